// Round 5
// baseline (847.539 us; speedup 1.0000x reference)
//
#include <hip/hip_runtime.h>

// ---------------- constants ----------------
#define LOG_DELTA (-5.2983174f)   // ln(0.005)

// ws layout (float offsets)
constexpr size_t OFF_C1G1  = 0;                       // [12][32][50]
constexpr size_t OFF_C1G2  = 19200;                   // [12][32][50]
constexpr size_t OFF_ACCS  = 38400;                   // [16]
constexpr size_t OFF_C0G   = 38416;                   // bzg [12][50][7000]
constexpr size_t OFF_BETA  = OFF_C0G  + 4200000;      // [600][7000]
constexpr size_t OFF_ALPHAT= OFF_BETA + 4200000;      // [600][300]
constexpr size_t OFF_INP   = OFF_ALPHAT + 180000;     // [384][400]
constexpr size_t OFF_X0    = OFF_INP  + 153600;       // [384][1600]
constexpr size_t OFF_OUT0  = OFF_X0   + 614400;       // [384][400]
constexpr size_t OFF_X1    = OFF_OUT0 + 153600;       // [384][1600]
constexpr size_t OFF_OUT1  = OFF_X1   + 614400;       // [384][400]
constexpr size_t OFF_CST   = OFF_OUT1 + 153600;       // [32][400]
constexpr size_t OFF_MUH   = OFF_CST  + 12800;        // [384][100] (mu|ls stacked)
constexpr size_t OFF_THETA = OFF_MUH  + 38400;        // [12][32][50]
constexpr size_t OFF_LTH   = OFF_THETA+ 19200;        // bsum0[1600]|bsum1[1600]|mlb[100]
constexpr size_t OFF_MUW4  = OFF_LTH  + 19200;        // [50][400]
constexpr size_t OFF_LSW4  = OFF_MUW4 + 20000;        // [50][400]
// whh transposed-packed buffers live in the (pre-pass1 dead) bzg region:
constexpr size_t OFF_W0T   = OFF_C0G;                 // [400][1600]
constexpr size_t OFF_W1T   = OFF_C0G + 640000;        // [400][1600]

// ---------------- helpers ----------------
__device__ __forceinline__ float wsum64(float x){
  #pragma unroll
  for (int o = 32; o; o >>= 1) x += __shfl_down(x, o);
  return x;
}
__device__ __forceinline__ float wmax64(float x){
  #pragma unroll
  for (int o = 32; o; o >>= 1) x = fmaxf(x, __shfl_down(x, o));
  return x;
}
// lowbias32 hash -> uniform (0,1)
__device__ __forceinline__ float u01(unsigned int x){
  x ^= x >> 16; x *= 0x7feb352dU;
  x ^= x >> 15; x *= 0x846ca68bU;
  x ^= x >> 16;
  return ((float)x + 0.5f) * (1.0f/4294967296.0f);
}

// ---------------- fused prep ----------------
__global__ void prep_misc(const float* __restrict__ muW, const float* __restrict__ lsW,
                          const float* __restrict__ qmu,
                          const float* __restrict__ bi0, const float* __restrict__ bh0,
                          const float* __restrict__ bi1, const float* __restrict__ bh1,
                          const float* __restrict__ mb,  const float* __restrict__ lb,
                          const float* __restrict__ qb,
                          float* __restrict__ zbase, float* __restrict__ muW4,
                          float* __restrict__ lsW4, float* __restrict__ alphT,
                          float* __restrict__ bsum0, float* __restrict__ bsum1,
                          float* __restrict__ mlb,   float* __restrict__ inp){
  for (int i = blockIdx.x*blockDim.x + threadIdx.x; i < 415316; i += gridDim.x*blockDim.x){
    if (i < 38416) zbase[i] = 0.f;
    else if (i < 58416){ int j = i - 38416; muW4[j] = muW[(j/400)*450 + (j%400)]; }
    else if (i < 78416){ int j = i - 58416; lsW4[j] = lsW[(j/400)*450 + (j%400)]; }
    else if (i < 258416){
      int j = i - 78416; int m = j/300, r = j%300; int t = m/50, k = m%50;
      alphT[j] = qmu[((size_t)k*12 + t)*300 + r];
    }
    else if (i < 260016){ int j = i - 258416; bsum0[j] = bi0[j] + bh0[j]; }
    else if (i < 261616){ int j = i - 260016; bsum1[j] = bi1[j] + bh1[j]; }
    else if (i < 261716){ int j = i - 261616; mlb[j] = (j < 50) ? mb[j] : lb[j-50]; }
    else { int j = i - 261716; inp[j] = qb[j % 400]; }
  }
}

// ---------------- whh transpose-pack: wT[r][u*4+g] = whh[g*400+u][r] ----------------
__global__ void prep_whT(const float* __restrict__ whh0, const float* __restrict__ whh1,
                         float* __restrict__ w0T, float* __restrict__ w1T){
  for (int i = blockIdx.x*blockDim.x + threadIdx.x; i < 1280000; i += gridDim.x*blockDim.x){
    int half = i / 640000, j = i % 640000;
    int r = j / 1600, col = j % 1600;
    int u = col >> 2, g = col & 3;
    float v = (half ? whh1 : whh0)[((size_t)(g*400 + u))*400 + r];
    (half ? w1T : w0T)[j] = v;
  }
}

// ---------------- GEMM: C (+)= A[M,K] * B[N,K]^T ----------------
__device__ __forceinline__ float4 g4(const float* __restrict__ base, int row, int nrows,
                                     int ld, int k, int kend){
  float4 v; v.x = v.y = v.z = v.w = 0.f;
  if (row < nrows){
    const float* q = base + (size_t)row*ld + k;
    if (k + 3 < kend) v = *(const float4*)q;
    else {
      if (k   < kend) v.x = q[0];
      if (k+1 < kend) v.y = q[1];
      if (k+2 < kend) v.z = q[2];
      if (k+3 < kend) v.w = q[3];
    }
  }
  return v;
}

__global__ __launch_bounds__(256) void gemm_f32(
    const float* __restrict__ A, int lda,
    const float* __restrict__ B, int ldb,
    float* __restrict__ C, int ldc,
    int M, int N, int K, int kchunk,
    const float* __restrict__ bias, int direct)
{
  __shared__ __align__(16) float As[16][68];
  __shared__ __align__(16) float Bs[16][68];
  const int tid = threadIdx.x;
  const int m0 = blockIdx.y * 64, n0 = blockIdx.x * 64;
  const int kbeg = blockIdx.z * kchunk;
  const int kend = min(K, kbeg + kchunk);
  const int lm  = tid >> 2;
  const int lkq = (tid & 3) << 2;
  const int ty = tid >> 4, tx = tid & 15;
  float acc[4][4];
  #pragma unroll
  for (int i=0;i<4;++i)
    #pragma unroll
    for (int j=0;j<4;++j) acc[i][j] = 0.f;

  for (int k0 = kbeg; k0 < kend; k0 += 16){
    float4 av = g4(A, m0+lm, M, lda, k0+lkq, kend);
    float4 bv = g4(B, n0+lm, N, ldb, k0+lkq, kend);
    As[lkq+0][lm]=av.x; As[lkq+1][lm]=av.y; As[lkq+2][lm]=av.z; As[lkq+3][lm]=av.w;
    Bs[lkq+0][lm]=bv.x; Bs[lkq+1][lm]=bv.y; Bs[lkq+2][lm]=bv.z; Bs[lkq+3][lm]=bv.w;
    __syncthreads();
    #pragma unroll
    for (int kk = 0; kk < 16; ++kk){
      const float4 a = *(const float4*)&As[kk][ty<<2];
      const float4 b = *(const float4*)&Bs[kk][tx<<2];
      float ar[4] = {a.x,a.y,a.z,a.w};
      float br[4] = {b.x,b.y,b.z,b.w};
      #pragma unroll
      for (int i=0;i<4;++i)
        #pragma unroll
        for (int j=0;j<4;++j) acc[i][j] = fmaf(ar[i], br[j], acc[i][j]);
    }
    __syncthreads();
  }
  const int om = m0 + (ty<<2), on = n0 + (tx<<2);
  if (direct){
    #pragma unroll
    for (int i=0;i<4;++i)
      #pragma unroll
      for (int j=0;j<4;++j)
        if (om+i < M && on+j < N)
          C[(size_t)(om+i)*ldc + (on+j)] = acc[i][j] + (bias ? bias[on+j] : 0.f);
  } else {
    #pragma unroll
    for (int i=0;i<4;++i)
      #pragma unroll
      for (int j=0;j<4;++j)
        if (om+i < M && on+j < N)
          atomicAdd(&C[(size_t)(om+i)*ldc + (on+j)], acc[i][j]);
  }
}

// ---------------- LSTM step v3: split-r, 512 threads ----------------
// 50 blocks x 512. Thread group rh=tid>>8 handles r in [rh*200, rh*200+200).
// Thread (rh, b=(tid&255)>>3, u=u0+(tid&7)) accumulates float4 (4 gates) over its
// r-half; rh==1 dumps partials to LDS; rh==0 combines + gate math.
__global__ __launch_bounds__(512) void lstm_step3(
    const float* __restrict__ X,     // [384][1600] gates input incl. biases, row b*12+t
    const float* __restrict__ wT,    // [400][1600] packed wT[r][u*4+g]
    float* __restrict__ hs,          // [384][400] row b*12+t
    float* __restrict__ cst,         // [32][400]
    int t)
{
  __shared__ __align__(16) float h_s[32][408];
  __shared__ __align__(16) float red[32][8][4];
  const int tid = threadIdx.x;
  const int u0 = blockIdx.x * 8;
  const int rh = tid >> 8;
  const int t2 = tid & 255;
  const int jq = t2 & 7;
  const int b  = t2 >> 3;
  const int u  = u0 + jq;

  float4 acc = {0.f, 0.f, 0.f, 0.f};
  if (t > 0){
    for (int i = tid; i < 3200; i += 512){
      int bb = i / 100, rq = i % 100;
      *(float4*)&h_s[bb][rq*4] =
        *(const float4*)&hs[((size_t)(bb*12 + (t-1)))*400 + rq*4];
    }
    __syncthreads();
    const float* wcol = wT + (size_t)u*4;
    const int rbase = rh * 200;
    #pragma unroll 2
    for (int rq = 0; rq < 50; ++rq){
      float4 h4 = *(const float4*)&h_s[b][rbase + rq*4];
      float hr[4] = {h4.x, h4.y, h4.z, h4.w};
      #pragma unroll
      for (int dr = 0; dr < 4; ++dr){
        float4 w4 = *(const float4*)&wcol[(size_t)(rbase + rq*4 + dr)*1600];
        acc.x = fmaf(hr[dr], w4.x, acc.x);
        acc.y = fmaf(hr[dr], w4.y, acc.y);
        acc.z = fmaf(hr[dr], w4.z, acc.z);
        acc.w = fmaf(hr[dr], w4.w, acc.w);
      }
    }
    if (rh == 1) *(float4*)&red[b][jq][0] = acc;
    __syncthreads();
  }
  if (rh == 0){
    if (t > 0){
      float4 r2 = *(const float4*)&red[b][jq][0];
      acc.x += r2.x; acc.y += r2.y; acc.z += r2.z; acc.w += r2.w;
    }
    const size_t xrow = ((size_t)b*12 + t)*1600;
    float gi = acc.x + X[xrow          + u];
    float gf = acc.y + X[xrow +  400   + u];
    float gg = acc.z + X[xrow +  800   + u];
    float go = acc.w + X[xrow + 1200   + u];
    float ii = 1.f/(1.f + expf(-gi));
    float ff = 1.f/(1.f + expf(-gf));
    float tg = tanhf(gg);
    float oo = 1.f/(1.f + expf(-go));
    float c = (t == 0) ? 0.f : cst[b*400 + u];
    c = ff*c + ii*tg;
    cst[b*400 + u] = c;
    hs[((size_t)b*12 + t)*400 + u] = oo * tanhf(c);
  }
}

// ---------------- theta head (4 blocks, 8 b's each) ----------------
__global__ __launch_bounds__(512) void theta_par(
    const float* __restrict__ muH2,   // [384][100] row b*12+t, cols 0..49 mu, 50..99 ls
    const float* __restrict__ muW, const float* __restrict__ lsW,  // [50][450]
    float* __restrict__ theta,        // [12][32][50]
    float* __restrict__ accs)
{
  __shared__ float zsall[12][8][50];
  __shared__ float wm[50][51], wl[50][51];
  __shared__ float ktot;
  const int tid = threadIdx.x;
  const int b0 = blockIdx.x * 8;
  for (int i = tid; i < 2500; i += 512){
    int k = i / 50, j = i % 50;
    wm[k][j] = muW[k*450 + 400 + j];
    wl[k][j] = lsW[k*450 + 400 + j];
  }
  if (tid == 0) ktot = 0.f;
  __syncthreads();
  const float dd = expf(LOG_DELTA) + 1e-6f;
  for (int t = 0; t < 12; ++t){
    float kpart = 0.f;
    if (tid < 400){
      int bl = tid / 50, k = tid % 50, b = b0 + bl;
      float m = muH2[((size_t)b*12 + t)*100 + k];
      float l = muH2[((size_t)b*12 + t)*100 + 50 + k];
      float zp = 0.f;
      if (t > 0){
        zp = zsall[t-1][bl][k];
        float sm = 0.f, sl = 0.f;
        #pragma unroll 5
        for (int j = 0; j < 50; ++j){
          float z = zsall[t-1][bl][j];
          sm = fmaf(z, wm[k][j], sm);
          sl = fmaf(z, wl[k][j], sl);
        }
        m += sm; l += sl;
      }
      zsall[t][bl][k] = m;
      float denom = (t > 0) ? dd : (1.f + 1e-6f);
      float pls = (t > 0) ? LOG_DELTA : 0.f;
      float d = m - zp;
      kpart += (expf(l) + d*d)/denom - 1.f + pls - l;
    }
    kpart = wsum64(kpart);
    if ((tid & 63) == 0) atomicAdd(&ktot, 0.5f * kpart / 32.f);
    __syncthreads();
  }
  for (int rr = tid; rr < 96; rr += 512){
    int t = rr >> 3, bl = rr & 7, b = b0 + bl;
    float m = -3.0e38f;
    for (int k = 0; k < 50; ++k) m = fmaxf(m, zsall[t][bl][k]);
    float S = 0.f;
    for (int k = 0; k < 50; ++k) S += expf(zsall[t][bl][k] - m);
    float inv = 1.f/S;
    for (int k = 0; k < 50; ++k)
      theta[((size_t)t*32 + b)*50 + k] = expf(zsall[t][bl][k] - m) * inv;
  }
  if (tid == 0) atomicAdd(&accs[6], ktot);
}

// ---------------- kld_alpha ----------------
__global__ void kld_alpha_k(const float* __restrict__ qmu, const float* __restrict__ qls,
                            float* __restrict__ accs){
  const int t = blockIdx.x / 50, k = blockIdx.x % 50;
  const size_t base  = ((size_t)k*12 + t)*300;
  const size_t pbase = ((size_t)k*12 + (t-1))*300;
  const float dd  = (t > 0) ? (expf(LOG_DELTA) + 1e-6f) : (1.f + 1e-6f);
  const float pls = (t > 0) ? LOG_DELTA : 0.f;
  float s = 0.f;
  for (int r = threadIdx.x; r < 300; r += 64){
    float qm = qmu[base + r], ql = qls[base + r];
    float pm = (t > 0) ? qmu[pbase + r] : 0.f;
    float d = qm - pm;
    s += (expf(ql) + d*d)/dd - 1.f + pls - ql;
  }
  s = wsum64(s);
  if (threadIdx.x == 0) atomicAdd(&accs[7], 0.5f * s / 50.f);
}

// ---------------- row softmax over vocab segment (in place) ----------------
__global__ __launch_bounds__(256) void softmax_seg(float* __restrict__ buf){
  const int row = blockIdx.x, part = blockIdx.y;
  float* p = buf + (size_t)row*7000 + (part ? 5000 : 0);
  const int n = part ? 2000 : 5000;
  __shared__ float sred[8];
  const int tid = threadIdx.x;
  float m = -3.0e38f;
  for (int i = tid; i < n; i += 256) m = fmaxf(m, p[i]);
  m = wmax64(m);
  if ((tid & 63) == 0) sred[tid >> 6] = m;
  __syncthreads();
  m = fmaxf(fmaxf(sred[0], sred[1]), fmaxf(sred[2], sred[3]));
  float s = 0.f;
  for (int i = tid; i < n; i += 256) s += __expf(p[i] - m);
  s = wsum64(s);
  if ((tid & 63) == 0) sred[4 + (tid >> 6)] = s;
  __syncthreads();
  s = sred[4] + sred[5] + sred[6] + sred[7];
  const float inv = 1.f/s;
  for (int i = tid; i < n; i += 256) p[i] = __expf(p[i] - m) * inv;
}

// ---------------- pass1: sample z, write bz = beta*c0/32, kld_z terms ----------------
// No per-thread array: 4 k-passes with exp recompute (scratch-free).
__global__ __launch_bounds__(256) void pass1(
    const float* __restrict__ beta,   // [600][7000]
    const float* __restrict__ theta,  // [12][32][50]
    float* __restrict__ bzg,          // [12][50][7000]  (k-major)
    float* __restrict__ c1g1, float* __restrict__ c1g2,  // [12][32][50]
    float* __restrict__ accs)
{
  const int t = blockIdx.y;
  const int v0 = blockIdx.x * 32;
  __shared__ float th[32][50];
  __shared__ float be[50][32];
  __shared__ float c0s[32][50];
  __shared__ float c1s[2][32][50];
  __shared__ float kred[4];
  const int tid = threadIdx.x;
  for (int i = tid; i < 1600; i += 256)
    th[i/50][i%50] = theta[(size_t)t*1600 + i];
  for (int i = tid; i < 1600; i += 256){
    int k = i >> 5, vl = i & 31, v = v0 + vl;
    be[k][vl] = (v < 7000) ? beta[((size_t)t*50 + k)*7000 + v] : 0.f;
  }
  for (int i = tid; i < 1600; i += 256) ((float*)c0s)[i] = 0.f;
  for (int i = tid; i < 3200; i += 256) ((float*)c1s)[i] = 0.f;
  if (tid < 4) kred[tid] = 0.f;
  __syncthreads();

  const int b = tid >> 3, sub = tid & 7;
  float kA1 = 0.f, kB1 = 0.f, kA2 = 0.f, kB2 = 0.f;

  // ---- pass A: row max ----
  float m1[4];
  #pragma unroll
  for (int i = 0; i < 4; ++i) m1[i] = -3.0e38f;
  for (int k = 0; k < 50; ++k){
    float tk = th[b][k];
    #pragma unroll
    for (int i = 0; i < 4; ++i)
      m1[i] = fmaxf(m1[i], tk * be[k][sub + 8*i]);
  }
  // ---- pass B: S1 ----
  float S1[4] = {0.f, 0.f, 0.f, 0.f};
  for (int k = 0; k < 50; ++k){
    float tk = th[b][k];
    #pragma unroll
    for (int i = 0; i < 4; ++i)
      S1[i] += __expf(tk * be[k][sub + 8*i] - m1[i]);
  }
  float inv[4];
  #pragma unroll
  for (int i = 0; i < 4; ++i) inv[i] = 1.f / S1[i];
  // ---- pass C: F = sum exp(pi) ----
  float Fv[4] = {0.f, 0.f, 0.f, 0.f};
  for (int k = 0; k < 50; ++k){
    float tk = th[b][k];
    #pragma unroll
    for (int i = 0; i < 4; ++i){
      float e = __expf(tk * be[k][sub + 8*i] - m1[i]);
      Fv[i] += __expf(e * inv[i]);
    }
  }
  float rthr[4];
  #pragma unroll
  for (int i = 0; i < 4; ++i){
    const unsigned int seed = (unsigned int)(((t*32) + b)*7000 + (v0 + sub + 8*i));
    rthr[i] = u01(seed) * Fv[i];
  }
  // ---- pass D: cumsum select (same op order as C -> csum_final == Fv bitwise) ----
  float csum[4] = {0.f, 0.f, 0.f, 0.f};
  float pis[4]  = {1.f, 1.f, 1.f, 1.f};
  int   ks[4]   = {49, 49, 49, 49};
  int   found[4]= {0, 0, 0, 0};
  for (int k = 0; k < 50; ++k){
    float tk = th[b][k];
    #pragma unroll
    for (int i = 0; i < 4; ++i){
      float e  = __expf(tk * be[k][sub + 8*i] - m1[i]);
      float pi = e * inv[i];
      csum[i] += __expf(pi);
      if (!found[i] && csum[i] >= rthr[i]){ ks[i] = k; pis[i] = pi; found[i] = 1; }
    }
  }
  // ---- side effects ----
  #pragma unroll
  for (int i = 0; i < 4; ++i){
    const int vl = sub + 8*i, v = v0 + vl;
    if (v < 7000){
      float lpis = __logf(pis[i]);
      float lt   = __logf(th[b][ks[i]]);
      if (v >= 5000){ kA2 += lt; kB2 += pis[i]*lpis; }
      else          { kA1 += lt; kB1 += pis[i]*lpis; }
      atomicAdd(&c0s[vl][ks[i]], 1.f);
      atomicAdd(&c1s[(v >= 5000) ? 1 : 0][b][ks[i]], 1.f);
    }
  }
  kA1 = wsum64(kA1); kB1 = wsum64(kB1); kA2 = wsum64(kA2); kB2 = wsum64(kB2);
  if ((tid & 63) == 0){
    atomicAdd(&kred[0], kA1); atomicAdd(&kred[1], kB1);
    atomicAdd(&kred[2], kA2); atomicAdd(&kred[3], kB2);
  }
  __syncthreads();
  // bz = beta * z.mean(0) = be * c0s/32, stored k-major (coalesced over v)
  for (int i = tid; i < 1600; i += 256){
    int k = i >> 5, vl = i & 31, v = v0 + vl;
    if (v < 7000)
      bzg[(size_t)t*350000 + (size_t)k*7000 + v] = be[k][vl] * c0s[vl][k] * (1.f/32.f);
  }
  for (int i = tid; i < 1600; i += 256){
    float x1 = ((float*)c1s)[i];
    float x2 = ((float*)c1s)[1600 + i];
    if (x1 != 0.f) atomicAdd(&c1g1[(size_t)t*1600 + i], x1);
    if (x2 != 0.f) atomicAdd(&c1g2[(size_t)t*1600 + i], x2);
  }
  if (tid < 4) atomicAdd(&accs[tid], kred[tid]);
}

// ---------------- pass2: log-likelihood (reads bzg, no beta re-read) ----------------
__global__ __launch_bounds__(256) void pass2(
    const float* __restrict__ bzg,    // [12][50][7000]
    const float* __restrict__ theta,
    const float* __restrict__ c1g1, const float* __restrict__ c1g2,
    const float* __restrict__ bows, float* __restrict__ accs)
{
  const int t = blockIdx.y, v0 = blockIdx.x * 32;
  __shared__ float tz[2][32][50];
  __shared__ float bzs[50][33];
  __shared__ float sr[2];
  const int tid = threadIdx.x;
  if (tid < 2) sr[tid] = 0.f;
  for (int i = tid; i < 1600; i += 256){
    int b = i / 50, k = i % 50;
    float th_ = theta[(size_t)t*1600 + i];
    tz[0][b][k] = th_ * c1g1[(size_t)t*1600 + i] * (1.f/5000.f);
    tz[1][b][k] = th_ * c1g2[(size_t)t*1600 + i] * (1.f/2000.f);
  }
  for (int i = tid; i < 1600; i += 256){
    int k = i >> 5, vl = i & 31, v = v0 + vl;
    bzs[k][vl] = (v < 7000) ? bzg[(size_t)t*350000 + (size_t)k*7000 + v] : 0.f;
  }
  __syncthreads();

  const int b = tid >> 3, sub = tid & 7;
  float s1 = 0.f, s2 = 0.f;
  #pragma unroll
  for (int it = 0; it < 4; ++it){
    const int vl = sub + (it << 3);
    const int v = v0 + vl;
    if (v < 7000){
      const int p = (v >= 5000);
      float dot = 0.f;
      #pragma unroll 2
      for (int k = 0; k < 50; ++k)
        dot = fmaf(tz[p][b][k], bzs[k][vl], dot);
      const float w = bows[((size_t)b*12 + t)*7000 + v];
      const float l = __logf(dot) * w;
      if (p) s2 += l; else s1 += l;
    }
  }
  s1 = wsum64(s1); s2 = wsum64(s2);
  if ((tid & 63) == 0){ atomicAdd(&sr[0], s1); atomicAdd(&sr[1], s2); }
  __syncthreads();
  if (tid < 2) atomicAdd(&accs[4 + tid], sr[tid]);
}

// ---------------- finalize ----------------
__global__ void finalize_k(const float* __restrict__ accs, float* __restrict__ out){
  if (threadIdx.x == 0 && blockIdx.x == 0){
    out[0] = -(accs[4] + accs[5]) * (1.f/32.f);           // recon_loss
    out[1] = accs[6];                                     // kld_theta
    out[2] = -accs[0]/(32.f*5000.f) - accs[1]/32.f;       // kld_z1
    out[3] = -accs[2]/(32.f*2000.f) - accs[3]/32.f;       // kld_z2
    out[4] = accs[7];                                     // kld_alpha
  }
}

// ---------------- host launcher ----------------
extern "C" void kernel_launch(void* const* d_in, const int* in_sizes, int n_in,
                              void* d_out, int out_size, void* d_ws, size_t ws_size,
                              hipStream_t stream)
{
  const float* bows   = (const float*)d_in[0];
  const float* nbows  = (const float*)d_in[1];
  const float* qmap_w = (const float*)d_in[2];
  const float* qmap_b = (const float*)d_in[3];
  const float* wih0   = (const float*)d_in[4];
  const float* whh0   = (const float*)d_in[5];
  const float* bih0   = (const float*)d_in[6];
  const float* bhh0   = (const float*)d_in[7];
  const float* wih1   = (const float*)d_in[8];
  const float* whh1   = (const float*)d_in[9];
  const float* bih1   = (const float*)d_in[10];
  const float* bhh1   = (const float*)d_in[11];
  const float* muW    = (const float*)d_in[12];
  const float* muB    = (const float*)d_in[13];
  const float* lsW    = (const float*)d_in[14];
  const float* lsB    = (const float*)d_in[15];
  const float* qmu    = (const float*)d_in[16];
  const float* qlsa   = (const float*)d_in[17];
  const float* rho1w  = (const float*)d_in[18];
  const float* rho1b  = (const float*)d_in[19];
  const float* rho2w  = (const float*)d_in[20];
  const float* rho2b  = (const float*)d_in[21];

  float* ws  = (float*)d_ws;
  float* out = (float*)d_out;

  float* c1g1  = ws + OFF_C1G1;
  float* c1g2  = ws + OFF_C1G2;
  float* accs  = ws + OFF_ACCS;
  float* bzg   = ws + OFF_C0G;
  float* beta  = ws + OFF_BETA;
  float* alphT = ws + OFF_ALPHAT;
  float* inp   = ws + OFF_INP;
  float* X0    = ws + OFF_X0;
  float* out0  = ws + OFF_OUT0;
  float* X1    = ws + OFF_X1;
  float* out1  = ws + OFF_OUT1;
  float* cst   = ws + OFF_CST;
  float* muH2  = ws + OFF_MUH;
  float* theta = ws + OFF_THETA;
  float* muW4  = ws + OFF_MUW4;
  float* w0T   = ws + OFF_W0T;
  float* w1T   = ws + OFF_W1T;
  float* bsum0 = ws + OFF_LTH;
  float* bsum1 = ws + OFF_LTH + 1600;
  float* mlb   = ws + OFF_LTH + 3200;

  prep_misc<<<1024, 256, 0, stream>>>(muW, lsW, qmu, bih0, bhh0, bih1, bhh1,
                                      muB, lsB, qmap_b,
                                      c1g1, muW4, ws + OFF_LSW4, alphT,
                                      bsum0, bsum1, mlb, inp);
  prep_whT<<<1280, 256, 0, stream>>>(whh0, whh1, w0T, w1T);
  kld_alpha_k<<<600, 64, 0, stream>>>(qmu, qlsa, accs);

  // inp += nbows @ qmap_w^T   [384,400], K=7000, 12-way split-K
  gemm_f32<<<dim3(7,6,12), 256, 0, stream>>>(nbows, 7000, qmap_w, 7000, inp, 400,
                                             384, 400, 7000, 592, nullptr, 0);
  // X0 = inp @ wih0^T + (bih0+bhh0)
  gemm_f32<<<dim3(25,6,1), 256, 0, stream>>>(inp, 400, wih0, 400, X0, 1600,
                                             384, 1600, 400, 400, bsum0, 1);
  for (int t = 0; t < 12; ++t)
    lstm_step3<<<50, 512, 0, stream>>>(X0, w0T, out0, cst, t);
  // X1 = out0 @ wih1^T + (bih1+bhh1)
  gemm_f32<<<dim3(25,6,1), 256, 0, stream>>>(out0, 400, wih1, 400, X1, 1600,
                                             384, 1600, 400, 400, bsum1, 1);
  for (int t = 0; t < 12; ++t)
    lstm_step3<<<50, 512, 0, stream>>>(X1, w1T, out1, cst, t);

  // muH2 = out1 @ [muW4;lsW4]^T + [muB;lsB]
  gemm_f32<<<dim3(2,6,1), 256, 0, stream>>>(out1, 400, muW4, 400, muH2, 100,
                                            384, 100, 400, 400, mlb, 1);
  theta_par<<<4, 512, 0, stream>>>(muH2, muW, lsW, theta, accs);

  // beta logits (direct store + bias), then row-softmax per segment
  gemm_f32<<<dim3(79,10,1), 256, 0, stream>>>(alphT, 300, rho1w, 300, beta, 7000,
                                              600, 5000, 300, 300, rho1b, 1);
  gemm_f32<<<dim3(32,10,1), 256, 0, stream>>>(alphT, 300, rho2w, 300, beta + 5000, 7000,
                                              600, 2000, 300, 300, rho2b, 1);
  softmax_seg<<<dim3(600,2), 256, 0, stream>>>(beta);

  // likelihood
  pass1<<<dim3(219,12), 256, 0, stream>>>(beta, theta, bzg, c1g1, c1g2, accs);
  pass2<<<dim3(219,12), 256, 0, stream>>>(bzg, theta, c1g1, c1g2, bows, accs);

  finalize_k<<<1, 64, 0, stream>>>(accs, out);
}

// Round 6
// 654.792 us; speedup vs baseline: 1.2944x; 1.2944x over previous
//
#include <hip/hip_runtime.h>

// ---------------- constants ----------------
#define LOG_DELTA (-5.2983174f)   // ln(0.005)
#define PIMAX     (0.0526f)       // provable bound: pi_k <= e/(49+e) = 0.05257

// ws layout (float offsets)
constexpr size_t OFF_C1G1  = 0;                       // [12][32][50]
constexpr size_t OFF_C1G2  = 19200;                   // [12][32][50]
constexpr size_t OFF_ACCS  = 38400;                   // [16]
constexpr size_t OFF_C0G   = 38416;                   // bzg [12][50][7000]
constexpr size_t OFF_BETA  = OFF_C0G  + 4200000;      // [600][7000]
constexpr size_t OFF_ALPHAT= OFF_BETA + 4200000;      // [600][300]
constexpr size_t OFF_INP   = OFF_ALPHAT + 180000;     // [384][400]
constexpr size_t OFF_X0    = OFF_INP  + 153600;       // [384][1600]
constexpr size_t OFF_OUT0  = OFF_X0   + 614400;       // [384][400]
constexpr size_t OFF_X1    = OFF_OUT0 + 153600;       // [384][1600]
constexpr size_t OFF_OUT1  = OFF_X1   + 614400;       // [384][400]
constexpr size_t OFF_CST   = OFF_OUT1 + 153600;       // [32][400]
constexpr size_t OFF_MUH   = OFF_CST  + 12800;        // [384][100] (mu|ls stacked)
constexpr size_t OFF_THETA = OFF_MUH  + 38400;        // [12][32][50]
constexpr size_t OFF_LTH   = OFF_THETA+ 19200;        // bsum0[1600]|bsum1[1600]|mlb[100]
constexpr size_t OFF_MUW4  = OFF_LTH  + 19200;        // [50][400]
constexpr size_t OFF_LSW4  = OFF_MUW4 + 20000;        // [50][400]
// whh transposed-packed buffers live in the (pre-pass1 dead) bzg region:
constexpr size_t OFF_W0T   = OFF_C0G;                 // [400][1600]
constexpr size_t OFF_W1T   = OFF_C0G + 640000;        // [400][1600]

// ---------------- helpers ----------------
__device__ __forceinline__ float wsum64(float x){
  #pragma unroll
  for (int o = 32; o; o >>= 1) x += __shfl_down(x, o);
  return x;
}
__device__ __forceinline__ float wmax64(float x){
  #pragma unroll
  for (int o = 32; o; o >>= 1) x = fmaxf(x, __shfl_down(x, o));
  return x;
}
// lowbias32 hash -> uniform (0,1)
__device__ __forceinline__ float u01(unsigned int x){
  x ^= x >> 16; x *= 0x7feb352dU;
  x ^= x >> 15; x *= 0x846ca68bU;
  x ^= x >> 16;
  return ((float)x + 0.5f) * (1.0f/4294967296.0f);
}

// ---------------- fused prep ----------------
__global__ void prep_misc(const float* __restrict__ muW, const float* __restrict__ lsW,
                          const float* __restrict__ qmu,
                          const float* __restrict__ bi0, const float* __restrict__ bh0,
                          const float* __restrict__ bi1, const float* __restrict__ bh1,
                          const float* __restrict__ mb,  const float* __restrict__ lb,
                          const float* __restrict__ qb,
                          float* __restrict__ zbase, float* __restrict__ muW4,
                          float* __restrict__ lsW4, float* __restrict__ alphT,
                          float* __restrict__ bsum0, float* __restrict__ bsum1,
                          float* __restrict__ mlb,   float* __restrict__ inp){
  for (int i = blockIdx.x*blockDim.x + threadIdx.x; i < 415316; i += gridDim.x*blockDim.x){
    if (i < 38416) zbase[i] = 0.f;
    else if (i < 58416){ int j = i - 38416; muW4[j] = muW[(j/400)*450 + (j%400)]; }
    else if (i < 78416){ int j = i - 58416; lsW4[j] = lsW[(j/400)*450 + (j%400)]; }
    else if (i < 258416){
      int j = i - 78416; int m = j/300, r = j%300; int t = m/50, k = m%50;
      alphT[j] = qmu[((size_t)k*12 + t)*300 + r];
    }
    else if (i < 260016){ int j = i - 258416; bsum0[j] = bi0[j] + bh0[j]; }
    else if (i < 261616){ int j = i - 260016; bsum1[j] = bi1[j] + bh1[j]; }
    else if (i < 261716){ int j = i - 261616; mlb[j] = (j < 50) ? mb[j] : lb[j-50]; }
    else { int j = i - 261716; inp[j] = qb[j % 400]; }
  }
}

// ---------------- whh transpose-pack: wT[r][u*4+g] = whh[g*400+u][r] ----------------
__global__ void prep_whT(const float* __restrict__ whh0, const float* __restrict__ whh1,
                         float* __restrict__ w0T, float* __restrict__ w1T){
  for (int i = blockIdx.x*blockDim.x + threadIdx.x; i < 1280000; i += gridDim.x*blockDim.x){
    int half = i / 640000, j = i % 640000;
    int r = j / 1600, col = j % 1600;
    int u = col >> 2, g = col & 3;
    float v = (half ? whh1 : whh0)[((size_t)(g*400 + u))*400 + r];
    (half ? w1T : w0T)[j] = v;
  }
}

// ---------------- GEMM: C (+)= A[M,K] * B[N,K]^T ----------------
__device__ __forceinline__ float4 g4(const float* __restrict__ base, int row, int nrows,
                                     int ld, int k, int kend){
  float4 v; v.x = v.y = v.z = v.w = 0.f;
  if (row < nrows){
    const float* q = base + (size_t)row*ld + k;
    if (k + 3 < kend) v = *(const float4*)q;
    else {
      if (k   < kend) v.x = q[0];
      if (k+1 < kend) v.y = q[1];
      if (k+2 < kend) v.z = q[2];
      if (k+3 < kend) v.w = q[3];
    }
  }
  return v;
}

__global__ __launch_bounds__(256) void gemm_f32(
    const float* __restrict__ A, int lda,
    const float* __restrict__ B, int ldb,
    float* __restrict__ C, int ldc,
    int M, int N, int K, int kchunk,
    const float* __restrict__ bias, int direct)
{
  __shared__ __align__(16) float As[16][68];
  __shared__ __align__(16) float Bs[16][68];
  const int tid = threadIdx.x;
  const int m0 = blockIdx.y * 64, n0 = blockIdx.x * 64;
  const int kbeg = blockIdx.z * kchunk;
  const int kend = min(K, kbeg + kchunk);
  const int lm  = tid >> 2;
  const int lkq = (tid & 3) << 2;
  const int ty = tid >> 4, tx = tid & 15;
  float acc[4][4];
  #pragma unroll
  for (int i=0;i<4;++i)
    #pragma unroll
    for (int j=0;j<4;++j) acc[i][j] = 0.f;

  for (int k0 = kbeg; k0 < kend; k0 += 16){
    float4 av = g4(A, m0+lm, M, lda, k0+lkq, kend);
    float4 bv = g4(B, n0+lm, N, ldb, k0+lkq, kend);
    As[lkq+0][lm]=av.x; As[lkq+1][lm]=av.y; As[lkq+2][lm]=av.z; As[lkq+3][lm]=av.w;
    Bs[lkq+0][lm]=bv.x; Bs[lkq+1][lm]=bv.y; Bs[lkq+2][lm]=bv.z; Bs[lkq+3][lm]=bv.w;
    __syncthreads();
    #pragma unroll
    for (int kk = 0; kk < 16; ++kk){
      const float4 a = *(const float4*)&As[kk][ty<<2];
      const float4 b = *(const float4*)&Bs[kk][tx<<2];
      float ar[4] = {a.x,a.y,a.z,a.w};
      float br[4] = {b.x,b.y,b.z,b.w};
      #pragma unroll
      for (int i=0;i<4;++i)
        #pragma unroll
        for (int j=0;j<4;++j) acc[i][j] = fmaf(ar[i], br[j], acc[i][j]);
    }
    __syncthreads();
  }
  const int om = m0 + (ty<<2), on = n0 + (tx<<2);
  if (direct){
    #pragma unroll
    for (int i=0;i<4;++i)
      #pragma unroll
      for (int j=0;j<4;++j)
        if (om+i < M && on+j < N)
          C[(size_t)(om+i)*ldc + (on+j)] = acc[i][j] + (bias ? bias[on+j] : 0.f);
  } else {
    #pragma unroll
    for (int i=0;i<4;++i)
      #pragma unroll
      for (int j=0;j<4;++j)
        if (om+i < M && on+j < N)
          atomicAdd(&C[(size_t)(om+i)*ldc + (on+j)], acc[i][j]);
  }
}

// ---------------- LSTM step v4: 200 blocks x 256, u-tile 2, 4-way r-split ----------
// Thread: rh = tid>>6 (r-quarter), b = (tid&63)>>1, ul = tid&1, u = bid*2+ul.
// h(t-1) staged in LDS as [rq][b] float4 (conflict-free b128 reads).
__global__ __launch_bounds__(256) void lstm_step4(
    const float* __restrict__ X,     // [384][1600] gates input incl. biases, row b*12+t
    const float* __restrict__ wT,    // [400][1600] packed wT[r][u*4+g]
    float* __restrict__ hs,          // [384][400] row b*12+t
    float* __restrict__ cst,         // [32][400]
    int t)
{
  __shared__ __align__(16) float4 hq4[100*32];   // [rq][b]
  __shared__ __align__(16) float4 red4[4][32][2];
  const int tid = threadIdx.x;
  const int U0 = blockIdx.x * 2;
  const int rh = tid >> 6;
  const int b  = (tid & 63) >> 1;
  const int ul = tid & 1;
  const int u  = U0 + ul;

  if (t > 0){
    for (int i = tid; i < 3200; i += 256){
      int bb = i & 31, rq = i >> 5;
      hq4[rq*32 + bb] = *(const float4*)&hs[((size_t)(bb*12 + (t-1)))*400 + rq*4];
    }
    __syncthreads();
    const float* wcol = wT + (size_t)u*4;
    float4 acc = {0.f, 0.f, 0.f, 0.f};
    const int rq0 = rh * 25;
    #pragma unroll 5
    for (int rq = rq0; rq < rq0 + 25; ++rq){
      float4 h4 = hq4[rq*32 + b];
      float hr[4] = {h4.x, h4.y, h4.z, h4.w};
      #pragma unroll
      for (int dr = 0; dr < 4; ++dr){
        float4 w4 = *(const float4*)&wcol[(size_t)(rq*4 + dr)*1600];
        acc.x = fmaf(hr[dr], w4.x, acc.x);
        acc.y = fmaf(hr[dr], w4.y, acc.y);
        acc.z = fmaf(hr[dr], w4.z, acc.z);
        acc.w = fmaf(hr[dr], w4.w, acc.w);
      }
    }
    red4[rh][b][ul] = acc;
  }
  __syncthreads();
  if (tid < 64){
    const int bb = tid >> 1, uu = U0 + (tid & 1);
    float4 a = {0.f, 0.f, 0.f, 0.f};
    if (t > 0){
      #pragma unroll
      for (int w = 0; w < 4; ++w){
        float4 r = red4[w][bb][tid & 1];
        a.x += r.x; a.y += r.y; a.z += r.z; a.w += r.w;
      }
    }
    const size_t xrow = ((size_t)bb*12 + t)*1600;
    float gi = a.x + X[xrow          + uu];
    float gf = a.y + X[xrow +  400   + uu];
    float gg = a.z + X[xrow +  800   + uu];
    float go = a.w + X[xrow + 1200   + uu];
    float ii = 1.f/(1.f + expf(-gi));
    float ff = 1.f/(1.f + expf(-gf));
    float tg = tanhf(gg);
    float oo = 1.f/(1.f + expf(-go));
    float c = (t == 0) ? 0.f : cst[bb*400 + uu];
    c = ff*c + ii*tg;
    cst[bb*400 + uu] = c;
    hs[((size_t)bb*12 + t)*400 + uu] = oo * tanhf(c);
  }
}

// ---------------- theta head (4 blocks, 8 b's each) ----------------
__global__ __launch_bounds__(512) void theta_par(
    const float* __restrict__ muH2,   // [384][100] row b*12+t, cols 0..49 mu, 50..99 ls
    const float* __restrict__ muW, const float* __restrict__ lsW,  // [50][450]
    float* __restrict__ theta,        // [12][32][50]
    float* __restrict__ accs)
{
  __shared__ float zsall[12][8][50];
  __shared__ float wm[50][51], wl[50][51];
  __shared__ float ktot;
  const int tid = threadIdx.x;
  const int b0 = blockIdx.x * 8;
  for (int i = tid; i < 2500; i += 512){
    int k = i / 50, j = i % 50;
    wm[k][j] = muW[k*450 + 400 + j];
    wl[k][j] = lsW[k*450 + 400 + j];
  }
  if (tid == 0) ktot = 0.f;
  __syncthreads();
  const float dd = expf(LOG_DELTA) + 1e-6f;
  for (int t = 0; t < 12; ++t){
    float kpart = 0.f;
    if (tid < 400){
      int bl = tid / 50, k = tid % 50, b = b0 + bl;
      float m = muH2[((size_t)b*12 + t)*100 + k];
      float l = muH2[((size_t)b*12 + t)*100 + 50 + k];
      float zp = 0.f;
      if (t > 0){
        zp = zsall[t-1][bl][k];
        float sm = 0.f, sl = 0.f;
        #pragma unroll 5
        for (int j = 0; j < 50; ++j){
          float z = zsall[t-1][bl][j];
          sm = fmaf(z, wm[k][j], sm);
          sl = fmaf(z, wl[k][j], sl);
        }
        m += sm; l += sl;
      }
      zsall[t][bl][k] = m;
      float denom = (t > 0) ? dd : (1.f + 1e-6f);
      float pls = (t > 0) ? LOG_DELTA : 0.f;
      float d = m - zp;
      kpart += (expf(l) + d*d)/denom - 1.f + pls - l;
    }
    kpart = wsum64(kpart);
    if ((tid & 63) == 0) atomicAdd(&ktot, 0.5f * kpart / 32.f);
    __syncthreads();
  }
  for (int rr = tid; rr < 96; rr += 512){
    int t = rr >> 3, bl = rr & 7, b = b0 + bl;
    float m = -3.0e38f;
    for (int k = 0; k < 50; ++k) m = fmaxf(m, zsall[t][bl][k]);
    float S = 0.f;
    for (int k = 0; k < 50; ++k) S += expf(zsall[t][bl][k] - m);
    float inv = 1.f/S;
    for (int k = 0; k < 50; ++k)
      theta[((size_t)t*32 + b)*50 + k] = expf(zsall[t][bl][k] - m) * inv;
  }
  if (tid == 0) atomicAdd(&accs[6], ktot);
}

// ---------------- kld_alpha ----------------
__global__ void kld_alpha_k(const float* __restrict__ qmu, const float* __restrict__ qls,
                            float* __restrict__ accs){
  const int t = blockIdx.x / 50, k = blockIdx.x % 50;
  const size_t base  = ((size_t)k*12 + t)*300;
  const size_t pbase = ((size_t)k*12 + (t-1))*300;
  const float dd  = (t > 0) ? (expf(LOG_DELTA) + 1e-6f) : (1.f + 1e-6f);
  const float pls = (t > 0) ? LOG_DELTA : 0.f;
  float s = 0.f;
  for (int r = threadIdx.x; r < 300; r += 64){
    float qm = qmu[base + r], ql = qls[base + r];
    float pm = (t > 0) ? qmu[pbase + r] : 0.f;
    float d = qm - pm;
    s += (expf(ql) + d*d)/dd - 1.f + pls - ql;
  }
  s = wsum64(s);
  if (threadIdx.x == 0) atomicAdd(&accs[7], 0.5f * s / 50.f);
}

// ---------------- row softmax over vocab segment (in place) ----------------
__global__ __launch_bounds__(256) void softmax_seg(float* __restrict__ buf){
  const int row = blockIdx.x, part = blockIdx.y;
  float* p = buf + (size_t)row*7000 + (part ? 5000 : 0);
  const int n = part ? 2000 : 5000;
  __shared__ float sred[8];
  const int tid = threadIdx.x;
  float m = -3.0e38f;
  for (int i = tid; i < n; i += 256) m = fmaxf(m, p[i]);
  m = wmax64(m);
  if ((tid & 63) == 0) sred[tid >> 6] = m;
  __syncthreads();
  m = fmaxf(fmaxf(sred[0], sred[1]), fmaxf(sred[2], sred[3]));
  float s = 0.f;
  for (int i = tid; i < n; i += 256) s += __expf(p[i] - m);
  s = wsum64(s);
  if ((tid & 63) == 0) sred[4 + (tid >> 6)] = s;
  __syncthreads();
  s = sred[4] + sred[5] + sred[6] + sred[7];
  const float inv = 1.f/s;
  for (int i = tid; i < n; i += 256) p[i] = __expf(p[i] - m) * inv;
}

// ---------------- pass1 v3: exact rejection sampling ----------------
// Per item: 50 exps for S1 (s = th*be in (0,1) -> no max needed), then propose
// k~U(50), accept iff u <= exp(pi_k - PIMAX); acceptance >= 0.949, exps/item ~56.
__global__ __launch_bounds__(256) void pass1(
    const float* __restrict__ beta,   // [600][7000]
    const float* __restrict__ theta,  // [12][32][50]
    float* __restrict__ bzg,          // [12][50][7000]  (k-major)
    float* __restrict__ c1g1, float* __restrict__ c1g2,  // [12][32][50]
    float* __restrict__ accs)
{
  const int t = blockIdx.y;
  const int v0 = blockIdx.x * 32;
  __shared__ float th[32][50];
  __shared__ float be[50][32];
  __shared__ float c0s[32][50];
  __shared__ float c1s[2][32][50];
  __shared__ float kred[4];
  const int tid = threadIdx.x;
  for (int i = tid; i < 1600; i += 256)
    th[i/50][i%50] = theta[(size_t)t*1600 + i];
  for (int i = tid; i < 1600; i += 256){
    int k = i >> 5, vl = i & 31, v = v0 + vl;
    be[k][vl] = (v < 7000) ? beta[((size_t)t*50 + k)*7000 + v] : 0.f;
  }
  for (int i = tid; i < 1600; i += 256) ((float*)c0s)[i] = 0.f;
  for (int i = tid; i < 3200; i += 256) ((float*)c1s)[i] = 0.f;
  if (tid < 4) kred[tid] = 0.f;
  __syncthreads();

  const int b = tid >> 3, sub = tid & 7;
  float kA1 = 0.f, kB1 = 0.f, kA2 = 0.f, kB2 = 0.f;

  for (int it = 0; it < 4; ++it){
    const int vl = sub + (it << 3);
    const int v  = v0 + vl;
    const bool valid = (v < 7000);
    // S1 = sum_k exp(th*be) — two partial chains for ILP
    float Sa = 0.f, Sb = 0.f;
    if (valid){
      #pragma unroll 5
      for (int k = 0; k < 50; k += 2){
        Sa += __expf(th[b][k  ] * be[k  ][vl]);
        Sb += __expf(th[b][k+1] * be[k+1][vl]);
      }
    }
    const float inv = 1.f / (Sa + Sb);
    // rejection sampling: wave-uniform rounds
    int   ks = 0;
    float pis = 1.f;
    bool  found = !valid;
    const unsigned base = (unsigned)(((t*32) + b)*7000 + v) * 2u;
    int round = 0;
    while (true){
      unsigned roff = (unsigned)round * 0x9E3779B9u;
      float u1 = u01(base + roff);
      float u2 = u01(base + 1u + roff);
      int kp = (int)(u1 * 50.f); kp = min(kp, 49);
      float pi = __expf(th[b][kp] * be[kp][vl]) * inv;
      bool acc = (!found) && (u2 <= __expf(pi - PIMAX));
      if (acc){ ks = kp; pis = pi; found = true; }
      ++round;
      if (round >= 8 && !found){ ks = kp; pis = pi; found = true; }
      if (__all((int)found)) break;
    }
    if (valid){
      float lpis = __logf(pis);
      float lt   = __logf(th[b][ks]);
      if (v >= 5000){ kA2 += lt; kB2 += pis*lpis; }
      else          { kA1 += lt; kB1 += pis*lpis; }
      atomicAdd(&c0s[vl][ks], 1.f);
      atomicAdd(&c1s[(v >= 5000) ? 1 : 0][b][ks], 1.f);
    }
  }
  kA1 = wsum64(kA1); kB1 = wsum64(kB1); kA2 = wsum64(kA2); kB2 = wsum64(kB2);
  if ((tid & 63) == 0){
    atomicAdd(&kred[0], kA1); atomicAdd(&kred[1], kB1);
    atomicAdd(&kred[2], kA2); atomicAdd(&kred[3], kB2);
  }
  __syncthreads();
  // bz = beta * z.mean(0) = be * c0s/32, stored k-major (coalesced over v)
  for (int i = tid; i < 1600; i += 256){
    int k = i >> 5, vl = i & 31, v = v0 + vl;
    if (v < 7000)
      bzg[(size_t)t*350000 + (size_t)k*7000 + v] = be[k][vl] * c0s[vl][k] * (1.f/32.f);
  }
  for (int i = tid; i < 1600; i += 256){
    float x1 = ((float*)c1s)[i];
    float x2 = ((float*)c1s)[1600 + i];
    if (x1 != 0.f) atomicAdd(&c1g1[(size_t)t*1600 + i], x1);
    if (x2 != 0.f) atomicAdd(&c1g2[(size_t)t*1600 + i], x2);
  }
  if (tid < 4) atomicAdd(&accs[tid], kred[tid]);
}

// ---------------- pass2: log-likelihood (reads bzg, no beta re-read) ----------------
__global__ __launch_bounds__(256) void pass2(
    const float* __restrict__ bzg,    // [12][50][7000]
    const float* __restrict__ theta,
    const float* __restrict__ c1g1, const float* __restrict__ c1g2,
    const float* __restrict__ bows, float* __restrict__ accs)
{
  const int t = blockIdx.y, v0 = blockIdx.x * 32;
  __shared__ float tz[2][32][50];
  __shared__ float bzs[50][33];
  __shared__ float sr[2];
  const int tid = threadIdx.x;
  if (tid < 2) sr[tid] = 0.f;
  for (int i = tid; i < 1600; i += 256){
    int b = i / 50, k = i % 50;
    float th_ = theta[(size_t)t*1600 + i];
    tz[0][b][k] = th_ * c1g1[(size_t)t*1600 + i] * (1.f/5000.f);
    tz[1][b][k] = th_ * c1g2[(size_t)t*1600 + i] * (1.f/2000.f);
  }
  for (int i = tid; i < 1600; i += 256){
    int k = i >> 5, vl = i & 31, v = v0 + vl;
    bzs[k][vl] = (v < 7000) ? bzg[(size_t)t*350000 + (size_t)k*7000 + v] : 0.f;
  }
  __syncthreads();

  const int b = tid >> 3, sub = tid & 7;
  float s1 = 0.f, s2 = 0.f;
  #pragma unroll
  for (int it = 0; it < 4; ++it){
    const int vl = sub + (it << 3);
    const int v = v0 + vl;
    if (v < 7000){
      const int p = (v >= 5000);
      float dot = 0.f;
      #pragma unroll 2
      for (int k = 0; k < 50; ++k)
        dot = fmaf(tz[p][b][k], bzs[k][vl], dot);
      const float w = bows[((size_t)b*12 + t)*7000 + v];
      const float l = __logf(dot) * w;
      if (p) s2 += l; else s1 += l;
    }
  }
  s1 = wsum64(s1); s2 = wsum64(s2);
  if ((tid & 63) == 0){ atomicAdd(&sr[0], s1); atomicAdd(&sr[1], s2); }
  __syncthreads();
  if (tid < 2) atomicAdd(&accs[4 + tid], sr[tid]);
}

// ---------------- finalize ----------------
__global__ void finalize_k(const float* __restrict__ accs, float* __restrict__ out){
  if (threadIdx.x == 0 && blockIdx.x == 0){
    out[0] = -(accs[4] + accs[5]) * (1.f/32.f);           // recon_loss
    out[1] = accs[6];                                     // kld_theta
    out[2] = -accs[0]/(32.f*5000.f) - accs[1]/32.f;       // kld_z1
    out[3] = -accs[2]/(32.f*2000.f) - accs[3]/32.f;       // kld_z2
    out[4] = accs[7];                                     // kld_alpha
  }
}

// ---------------- host launcher ----------------
extern "C" void kernel_launch(void* const* d_in, const int* in_sizes, int n_in,
                              void* d_out, int out_size, void* d_ws, size_t ws_size,
                              hipStream_t stream)
{
  const float* bows   = (const float*)d_in[0];
  const float* nbows  = (const float*)d_in[1];
  const float* qmap_w = (const float*)d_in[2];
  const float* qmap_b = (const float*)d_in[3];
  const float* wih0   = (const float*)d_in[4];
  const float* whh0   = (const float*)d_in[5];
  const float* bih0   = (const float*)d_in[6];
  const float* bhh0   = (const float*)d_in[7];
  const float* wih1   = (const float*)d_in[8];
  const float* whh1   = (const float*)d_in[9];
  const float* bih1   = (const float*)d_in[10];
  const float* bhh1   = (const float*)d_in[11];
  const float* muW    = (const float*)d_in[12];
  const float* muB    = (const float*)d_in[13];
  const float* lsW    = (const float*)d_in[14];
  const float* lsB    = (const float*)d_in[15];
  const float* qmu    = (const float*)d_in[16];
  const float* qlsa   = (const float*)d_in[17];
  const float* rho1w  = (const float*)d_in[18];
  const float* rho1b  = (const float*)d_in[19];
  const float* rho2w  = (const float*)d_in[20];
  const float* rho2b  = (const float*)d_in[21];

  float* ws  = (float*)d_ws;
  float* out = (float*)d_out;

  float* c1g1  = ws + OFF_C1G1;
  float* c1g2  = ws + OFF_C1G2;
  float* accs  = ws + OFF_ACCS;
  float* bzg   = ws + OFF_C0G;
  float* beta  = ws + OFF_BETA;
  float* alphT = ws + OFF_ALPHAT;
  float* inp   = ws + OFF_INP;
  float* X0    = ws + OFF_X0;
  float* out0  = ws + OFF_OUT0;
  float* X1    = ws + OFF_X1;
  float* out1  = ws + OFF_OUT1;
  float* cst   = ws + OFF_CST;
  float* muH2  = ws + OFF_MUH;
  float* theta = ws + OFF_THETA;
  float* muW4  = ws + OFF_MUW4;
  float* w0T   = ws + OFF_W0T;
  float* w1T   = ws + OFF_W1T;
  float* bsum0 = ws + OFF_LTH;
  float* bsum1 = ws + OFF_LTH + 1600;
  float* mlb   = ws + OFF_LTH + 3200;

  prep_misc<<<1024, 256, 0, stream>>>(muW, lsW, qmu, bih0, bhh0, bih1, bhh1,
                                      muB, lsB, qmap_b,
                                      c1g1, muW4, ws + OFF_LSW4, alphT,
                                      bsum0, bsum1, mlb, inp);
  prep_whT<<<1280, 256, 0, stream>>>(whh0, whh1, w0T, w1T);
  kld_alpha_k<<<600, 64, 0, stream>>>(qmu, qlsa, accs);

  // inp += nbows @ qmap_w^T   [384,400], K=7000, 12-way split-K
  gemm_f32<<<dim3(7,6,12), 256, 0, stream>>>(nbows, 7000, qmap_w, 7000, inp, 400,
                                             384, 400, 7000, 592, nullptr, 0);
  // X0 = inp @ wih0^T + (bih0+bhh0)
  gemm_f32<<<dim3(25,6,1), 256, 0, stream>>>(inp, 400, wih0, 400, X0, 1600,
                                             384, 1600, 400, 400, bsum0, 1);
  for (int t = 0; t < 12; ++t)
    lstm_step4<<<200, 256, 0, stream>>>(X0, w0T, out0, cst, t);
  // X1 = out0 @ wih1^T + (bih1+bhh1)
  gemm_f32<<<dim3(25,6,1), 256, 0, stream>>>(out0, 400, wih1, 400, X1, 1600,
                                             384, 1600, 400, 400, bsum1, 1);
  for (int t = 0; t < 12; ++t)
    lstm_step4<<<200, 256, 0, stream>>>(X1, w1T, out1, cst, t);

  // muH2 = out1 @ [muW4;lsW4]^T + [muB;lsB]
  gemm_f32<<<dim3(2,6,1), 256, 0, stream>>>(out1, 400, muW4, 400, muH2, 100,
                                            384, 100, 400, 400, mlb, 1);
  theta_par<<<4, 512, 0, stream>>>(muH2, muW, lsW, theta, accs);

  // beta logits (direct store + bias), then row-softmax per segment
  gemm_f32<<<dim3(79,10,1), 256, 0, stream>>>(alphT, 300, rho1w, 300, beta, 7000,
                                              600, 5000, 300, 300, rho1b, 1);
  gemm_f32<<<dim3(32,10,1), 256, 0, stream>>>(alphT, 300, rho2w, 300, beta + 5000, 7000,
                                              600, 2000, 300, 300, rho2b, 1);
  softmax_seg<<<dim3(600,2), 256, 0, stream>>>(beta);

  // likelihood
  pass1<<<dim3(219,12), 256, 0, stream>>>(beta, theta, bzg, c1g1, c1g2, accs);
  pass2<<<dim3(219,12), 256, 0, stream>>>(bzg, theta, c1g1, c1g2, bows, accs);

  finalize_k<<<1, 64, 0, stream>>>(accs, out);
}

// Round 7
// 620.714 us; speedup vs baseline: 1.3654x; 1.0549x over previous
//
#include <hip/hip_runtime.h>

// ---------------- constants ----------------
#define LOG_DELTA (-5.2983174f)   // ln(0.005)
#define PIMAX     (0.0526f)       // provable bound: pi_k <= e/(49+e) = 0.05257

// ws layout (float offsets)
constexpr size_t OFF_C1G1  = 0;                       // [12][32][50]
constexpr size_t OFF_C1G2  = 19200;                   // [12][32][50]
constexpr size_t OFF_ACCS  = 38400;                   // [16]
constexpr size_t OFF_C0G   = 38416;                   // bzg [12][50][7000]
constexpr size_t OFF_BETA  = OFF_C0G  + 4200000;      // [600][7000] (logits)
constexpr size_t OFF_ALPHAT= OFF_BETA + 4200000;      // [600][300]
constexpr size_t OFF_INP   = OFF_ALPHAT + 180000;     // [384][400]
constexpr size_t OFF_X0    = OFF_INP  + 153600;       // [384][1600]
constexpr size_t OFF_OUT0  = OFF_X0   + 614400;       // [384][400]
constexpr size_t OFF_X1    = OFF_OUT0 + 153600;       // [384][1600]
constexpr size_t OFF_OUT1  = OFF_X1   + 614400;       // [384][400]
constexpr size_t OFF_CST   = OFF_OUT1 + 153600;       // [32][400]
constexpr size_t OFF_MUH   = OFF_CST  + 12800;        // [384][100] (mu|ls stacked)
constexpr size_t OFF_THETA = OFF_MUH  + 38400;        // [12][32][50]
constexpr size_t OFF_LTH   = OFF_THETA+ 19200;        // bsum0|bsum1|mlb|rowsum
constexpr size_t OFF_MUW4  = OFF_LTH  + 19200;        // [50][400]
constexpr size_t OFF_LSW4  = OFF_MUW4 + 20000;        // [50][400]
constexpr size_t OFF_RS    = OFF_LTH  + 3300;         // rowsum [2][600]
// whh transposed-packed buffers live in the (pre-pass1 dead) bzg region:
constexpr size_t OFF_W0T   = OFF_C0G;                 // [400][1600]
constexpr size_t OFF_W1T   = OFF_C0G + 640000;        // [400][1600]

// ---------------- helpers ----------------
__device__ __forceinline__ float wsum64(float x){
  #pragma unroll
  for (int o = 32; o; o >>= 1) x += __shfl_down(x, o);
  return x;
}
// lowbias32 hash -> uniform (0,1)
__device__ __forceinline__ float u01(unsigned int x){
  x ^= x >> 16; x *= 0x7feb352dU;
  x ^= x >> 15; x *= 0x846ca68bU;
  x ^= x >> 16;
  return ((float)x + 0.5f) * (1.0f/4294967296.0f);
}

// ---------------- fused prep (all packing / zeroing / transposes, one launch) ----
__global__ void prep_misc(const float* __restrict__ muW, const float* __restrict__ lsW,
                          const float* __restrict__ qmu,
                          const float* __restrict__ bi0, const float* __restrict__ bh0,
                          const float* __restrict__ bi1, const float* __restrict__ bh1,
                          const float* __restrict__ mb,  const float* __restrict__ lb,
                          const float* __restrict__ qb,
                          const float* __restrict__ whh0, const float* __restrict__ whh1,
                          float* __restrict__ zbase, float* __restrict__ muW4,
                          float* __restrict__ lsW4, float* __restrict__ alphT,
                          float* __restrict__ bsum0, float* __restrict__ bsum1,
                          float* __restrict__ mlb,   float* __restrict__ rs,
                          float* __restrict__ inp,
                          float* __restrict__ w0T,   float* __restrict__ w1T){
  for (int i = blockIdx.x*blockDim.x + threadIdx.x; i < 1696516; i += gridDim.x*blockDim.x){
    if (i < 38416) zbase[i] = 0.f;
    else if (i < 58416){ int j = i - 38416; muW4[j] = muW[(j/400)*450 + (j%400)]; }
    else if (i < 78416){ int j = i - 58416; lsW4[j] = lsW[(j/400)*450 + (j%400)]; }
    else if (i < 258416){
      int j = i - 78416; int m = j/300, r = j%300; int t = m/50, k = m%50;
      alphT[j] = qmu[((size_t)k*12 + t)*300 + r];
    }
    else if (i < 260016){ int j = i - 258416; bsum0[j] = bi0[j] + bh0[j]; }
    else if (i < 261616){ int j = i - 260016; bsum1[j] = bi1[j] + bh1[j]; }
    else if (i < 261716){ int j = i - 261616; mlb[j] = (j < 50) ? mb[j] : lb[j-50]; }
    else if (i < 262916){ int j = i - 261716; rs[j] = 0.f; }
    else if (i < 416516){ int j = i - 262916; inp[j] = qb[j % 400]; }
    else {
      int j = i - 416516; int half = j / 640000, jj = j % 640000;
      int r = jj / 1600, col = jj % 1600;
      int u = col >> 2, g = col & 3;
      float v = (half ? whh1 : whh0)[((size_t)(g*400 + u))*400 + r];
      (half ? w1T : w0T)[jj] = v;
    }
  }
}

// ---------------- GEMM: C (+)= A[M,K] * B[N,K]^T ----------------
// direct: store acc+bias; rowsum!=nullptr: also atomicAdd per-row sum of exp(C).
__device__ __forceinline__ float4 g4(const float* __restrict__ base, int row, int nrows,
                                     int ld, int k, int kend){
  float4 v; v.x = v.y = v.z = v.w = 0.f;
  if (row < nrows){
    const float* q = base + (size_t)row*ld + k;
    if (k + 3 < kend) v = *(const float4*)q;
    else {
      if (k   < kend) v.x = q[0];
      if (k+1 < kend) v.y = q[1];
      if (k+2 < kend) v.z = q[2];
      if (k+3 < kend) v.w = q[3];
    }
  }
  return v;
}

__global__ __launch_bounds__(256) void gemm_f32(
    const float* __restrict__ A, int lda,
    const float* __restrict__ B, int ldb,
    float* __restrict__ C, int ldc,
    int M, int N, int K, int kchunk,
    const float* __restrict__ bias, int direct, float* __restrict__ rowsum)
{
  __shared__ __align__(16) float As[16][68];
  __shared__ __align__(16) float Bs[16][68];
  __shared__ float sexp[64];
  const int tid = threadIdx.x;
  const int m0 = blockIdx.y * 64, n0 = blockIdx.x * 64;
  const int kbeg = blockIdx.z * kchunk;
  const int kend = min(K, kbeg + kchunk);
  const int lm  = tid >> 2;
  const int lkq = (tid & 3) << 2;
  const int ty = tid >> 4, tx = tid & 15;
  if (rowsum && tid < 64) sexp[tid] = 0.f;
  float acc[4][4];
  #pragma unroll
  for (int i=0;i<4;++i)
    #pragma unroll
    for (int j=0;j<4;++j) acc[i][j] = 0.f;

  for (int k0 = kbeg; k0 < kend; k0 += 16){
    float4 av = g4(A, m0+lm, M, lda, k0+lkq, kend);
    float4 bv = g4(B, n0+lm, N, ldb, k0+lkq, kend);
    As[lkq+0][lm]=av.x; As[lkq+1][lm]=av.y; As[lkq+2][lm]=av.z; As[lkq+3][lm]=av.w;
    Bs[lkq+0][lm]=bv.x; Bs[lkq+1][lm]=bv.y; Bs[lkq+2][lm]=bv.z; Bs[lkq+3][lm]=bv.w;
    __syncthreads();
    #pragma unroll
    for (int kk = 0; kk < 16; ++kk){
      const float4 a = *(const float4*)&As[kk][ty<<2];
      const float4 b = *(const float4*)&Bs[kk][tx<<2];
      float ar[4] = {a.x,a.y,a.z,a.w};
      float br[4] = {b.x,b.y,b.z,b.w};
      #pragma unroll
      for (int i=0;i<4;++i)
        #pragma unroll
        for (int j=0;j<4;++j) acc[i][j] = fmaf(ar[i], br[j], acc[i][j]);
    }
    __syncthreads();
  }
  const int om = m0 + (ty<<2), on = n0 + (tx<<2);
  if (direct){
    #pragma unroll
    for (int i=0;i<4;++i)
      #pragma unroll
      for (int j=0;j<4;++j)
        if (om+i < M && on+j < N)
          C[(size_t)(om+i)*ldc + (on+j)] = acc[i][j] + (bias ? bias[on+j] : 0.f);
    if (rowsum){
      #pragma unroll
      for (int i=0;i<4;++i){
        float p = 0.f;
        #pragma unroll
        for (int j=0;j<4;++j)
          if (om+i < M && on+j < N) p += __expf(acc[i][j] + (bias ? bias[on+j] : 0.f));
        atomicAdd(&sexp[(ty<<2)+i], p);
      }
      __syncthreads();
      if (tid < 64 && m0 + tid < M) atomicAdd(&rowsum[m0 + tid], sexp[tid]);
    }
  } else {
    #pragma unroll
    for (int i=0;i<4;++i)
      #pragma unroll
      for (int j=0;j<4;++j)
        if (om+i < M && on+j < N)
          atomicAdd(&C[(size_t)(om+i)*ldc + (on+j)], acc[i][j]);
  }
}

// ---------------- LSTM step v4: 200 blocks x 256, u-tile 2, 4-way r-split ----------
__global__ __launch_bounds__(256) void lstm_step4(
    const float* __restrict__ X,     // [384][1600] gates input incl. biases, row b*12+t
    const float* __restrict__ wT,    // [400][1600] packed wT[r][u*4+g]
    float* __restrict__ hs,          // [384][400] row b*12+t
    float* __restrict__ cst,         // [32][400]
    int t)
{
  __shared__ __align__(16) float4 hq4[100*32];   // [rq][b]
  __shared__ __align__(16) float4 red4[4][32][2];
  const int tid = threadIdx.x;
  const int U0 = blockIdx.x * 2;
  const int rh = tid >> 6;
  const int b  = (tid & 63) >> 1;
  const int ul = tid & 1;
  const int u  = U0 + ul;

  if (t > 0){
    for (int i = tid; i < 3200; i += 256){
      int bb = i & 31, rq = i >> 5;
      hq4[rq*32 + bb] = *(const float4*)&hs[((size_t)(bb*12 + (t-1)))*400 + rq*4];
    }
    __syncthreads();
    const float* wcol = wT + (size_t)u*4;
    float4 acc = {0.f, 0.f, 0.f, 0.f};
    const int rq0 = rh * 25;
    #pragma unroll 5
    for (int rq = rq0; rq < rq0 + 25; ++rq){
      float4 h4 = hq4[rq*32 + b];
      float hr[4] = {h4.x, h4.y, h4.z, h4.w};
      #pragma unroll
      for (int dr = 0; dr < 4; ++dr){
        float4 w4 = *(const float4*)&wcol[(size_t)(rq*4 + dr)*1600];
        acc.x = fmaf(hr[dr], w4.x, acc.x);
        acc.y = fmaf(hr[dr], w4.y, acc.y);
        acc.z = fmaf(hr[dr], w4.z, acc.z);
        acc.w = fmaf(hr[dr], w4.w, acc.w);
      }
    }
    red4[rh][b][ul] = acc;
  }
  __syncthreads();
  if (tid < 64){
    const int bb = tid >> 1, uu = U0 + (tid & 1);
    float4 a = {0.f, 0.f, 0.f, 0.f};
    if (t > 0){
      #pragma unroll
      for (int w = 0; w < 4; ++w){
        float4 r = red4[w][bb][tid & 1];
        a.x += r.x; a.y += r.y; a.z += r.z; a.w += r.w;
      }
    }
    const size_t xrow = ((size_t)bb*12 + t)*1600;
    float gi = a.x + X[xrow          + uu];
    float gf = a.y + X[xrow +  400   + uu];
    float gg = a.z + X[xrow +  800   + uu];
    float go = a.w + X[xrow + 1200   + uu];
    float ii = 1.f/(1.f + expf(-gi));
    float ff = 1.f/(1.f + expf(-gf));
    float tg = tanhf(gg);
    float oo = 1.f/(1.f + expf(-go));
    float c = (t == 0) ? 0.f : cst[bb*400 + uu];
    c = ff*c + ii*tg;
    cst[bb*400 + uu] = c;
    hs[((size_t)bb*12 + t)*400 + uu] = oo * tanhf(c);
  }
}

// ---------------- theta head (4 blocks, 8 b's each) ----------------
__global__ __launch_bounds__(512) void theta_par(
    const float* __restrict__ muH2,   // [384][100] row b*12+t, cols 0..49 mu, 50..99 ls
    const float* __restrict__ muW, const float* __restrict__ lsW,  // [50][450]
    float* __restrict__ theta,        // [12][32][50]
    float* __restrict__ accs)
{
  __shared__ float zsall[12][8][50];
  __shared__ float wm[50][51], wl[50][51];
  __shared__ float ktot;
  const int tid = threadIdx.x;
  const int b0 = blockIdx.x * 8;
  for (int i = tid; i < 2500; i += 512){
    int k = i / 50, j = i % 50;
    wm[k][j] = muW[k*450 + 400 + j];
    wl[k][j] = lsW[k*450 + 400 + j];
  }
  if (tid == 0) ktot = 0.f;
  __syncthreads();
  const float dd = expf(LOG_DELTA) + 1e-6f;
  for (int t = 0; t < 12; ++t){
    float kpart = 0.f;
    if (tid < 400){
      int bl = tid / 50, k = tid % 50, b = b0 + bl;
      float m = muH2[((size_t)b*12 + t)*100 + k];
      float l = muH2[((size_t)b*12 + t)*100 + 50 + k];
      float zp = 0.f;
      if (t > 0){
        zp = zsall[t-1][bl][k];
        float sm = 0.f, sl = 0.f;
        #pragma unroll 5
        for (int j = 0; j < 50; ++j){
          float z = zsall[t-1][bl][j];
          sm = fmaf(z, wm[k][j], sm);
          sl = fmaf(z, wl[k][j], sl);
        }
        m += sm; l += sl;
      }
      zsall[t][bl][k] = m;
      float denom = (t > 0) ? dd : (1.f + 1e-6f);
      float pls = (t > 0) ? LOG_DELTA : 0.f;
      float d = m - zp;
      kpart += (expf(l) + d*d)/denom - 1.f + pls - l;
    }
    kpart = wsum64(kpart);
    if ((tid & 63) == 0) atomicAdd(&ktot, 0.5f * kpart / 32.f);
    __syncthreads();
  }
  for (int rr = tid; rr < 96; rr += 512){
    int t = rr >> 3, bl = rr & 7, b = b0 + bl;
    float m = -3.0e38f;
    for (int k = 0; k < 50; ++k) m = fmaxf(m, zsall[t][bl][k]);
    float S = 0.f;
    for (int k = 0; k < 50; ++k) S += expf(zsall[t][bl][k] - m);
    float inv = 1.f/S;
    for (int k = 0; k < 50; ++k)
      theta[((size_t)t*32 + b)*50 + k] = expf(zsall[t][bl][k] - m) * inv;
  }
  if (tid == 0) atomicAdd(&accs[6], ktot);
}

// ---------------- kld_alpha ----------------
__global__ void kld_alpha_k(const float* __restrict__ qmu, const float* __restrict__ qls,
                            float* __restrict__ accs){
  const int t = blockIdx.x / 50, k = blockIdx.x % 50;
  const size_t base  = ((size_t)k*12 + t)*300;
  const size_t pbase = ((size_t)k*12 + (t-1))*300;
  const float dd  = (t > 0) ? (expf(LOG_DELTA) + 1e-6f) : (1.f + 1e-6f);
  const float pls = (t > 0) ? LOG_DELTA : 0.f;
  float s = 0.f;
  for (int r = threadIdx.x; r < 300; r += 64){
    float qm = qmu[base + r], ql = qls[base + r];
    float pm = (t > 0) ? qmu[pbase + r] : 0.f;
    float d = qm - pm;
    s += (expf(ql) + d*d)/dd - 1.f + pls - ql;
  }
  s = wsum64(s);
  if (threadIdx.x == 0) atomicAdd(&accs[7], 0.5f * s / 50.f);
}

// ---------------- pass1 v4: 64-wide tile, 8-item ILP, rejection sampling ----------
// beta arrives as LOGITS; be = exp(logit)/rowsum (softmax fused into staging).
__global__ __launch_bounds__(256) void pass1(
    const float* __restrict__ blog,   // [600][7000] logits
    const float* __restrict__ rs,     // [2][600] row sums of exp(logit)
    const float* __restrict__ theta,  // [12][32][50]
    float* __restrict__ bzg,          // [12][50][7000]  (k-major)
    float* __restrict__ c1g1, float* __restrict__ c1g2,  // [12][32][50]
    float* __restrict__ accs)
{
  const int t = blockIdx.y;
  const int v0 = blockIdx.x * 64;
  __shared__ float th[32][50];
  __shared__ float be[50][64];
  __shared__ float c0s[64][50];
  __shared__ float c1s[2][32][50];
  __shared__ float kred[4];
  const int tid = threadIdx.x;
  for (int i = tid; i < 1600; i += 256)
    th[i/50][i%50] = theta[(size_t)t*1600 + i];
  for (int i = tid; i < 3200; i += 256){
    int k = i >> 6, vl = i & 63, v = v0 + vl;
    float e = 0.f;
    if (v < 7000){
      float lg = blog[((size_t)t*50 + k)*7000 + v];
      float r  = rs[((v >= 5000) ? 600 : 0) + t*50 + k];
      e = __expf(lg) / r;
    }
    be[k][vl] = e;
  }
  for (int i = tid; i < 3200; i += 256) ((float*)c0s)[i] = 0.f;
  for (int i = tid; i < 3200; i += 256) ((float*)c1s)[i] = 0.f;
  if (tid < 4) kred[tid] = 0.f;
  __syncthreads();

  const int b = tid >> 3, sub = tid & 7;

  // S1 with 8 independent exp chains
  float S[8];
  #pragma unroll
  for (int i=0;i<8;++i) S[i] = 0.f;
  for (int k = 0; k < 50; ++k){
    float tk = th[b][k];
    #pragma unroll
    for (int i=0;i<8;++i)
      S[i] += __expf(tk * be[k][sub + 8*i]);
  }
  float inv[8];
  #pragma unroll
  for (int i=0;i<8;++i) inv[i] = 1.f / S[i];

  // 8-way rejection sampling (exact, acceptance >= 0.949 per round)
  int ks[8]; float pis[8];
  unsigned fmask = 0;
  const int vbase = (t*32 + b)*7000 + v0 + sub;
  #pragma unroll
  for (int i=0;i<8;++i){
    ks[i] = 0; pis[i] = 1.f;
    if (v0 + sub + 8*i >= 7000) fmask |= 1u << i;
  }
  int round = 0;
  while (true){
    const unsigned roff = (unsigned)round * 0x9E3779B9u;
    #pragma unroll
    for (int i=0;i<8;++i){
      if (!((fmask >> i) & 1u)){
        const unsigned bse = (unsigned)(vbase + 8*i) * 2u;
        float u1 = u01(bse + roff);
        float u2 = u01(bse + 1u + roff);
        int kp = min((int)(u1 * 50.f), 49);
        float pi = __expf(th[b][kp] * be[kp][sub + 8*i]) * inv[i];
        if (u2 <= __expf(pi - PIMAX) || round >= 7){
          ks[i] = kp; pis[i] = pi; fmask |= 1u << i;
        }
      }
    }
    ++round;
    if (__all(fmask == 255u)) break;
  }

  // side effects
  float kA1 = 0.f, kB1 = 0.f, kA2 = 0.f, kB2 = 0.f;
  #pragma unroll
  for (int i=0;i<8;++i){
    const int vl = sub + 8*i, v = v0 + vl;
    if (v < 7000){
      float lpis = __logf(pis[i]);
      float lt   = __logf(th[b][ks[i]]);
      if (v >= 5000){ kA2 += lt; kB2 += pis[i]*lpis; }
      else          { kA1 += lt; kB1 += pis[i]*lpis; }
      atomicAdd(&c0s[vl][ks[i]], 1.f);
      atomicAdd(&c1s[(v >= 5000) ? 1 : 0][b][ks[i]], 1.f);
    }
  }
  kA1 = wsum64(kA1); kB1 = wsum64(kB1); kA2 = wsum64(kA2); kB2 = wsum64(kB2);
  if ((tid & 63) == 0){
    atomicAdd(&kred[0], kA1); atomicAdd(&kred[1], kB1);
    atomicAdd(&kred[2], kA2); atomicAdd(&kred[3], kB2);
  }
  __syncthreads();
  // bz = beta * z.mean(0) = be * c0s/32, k-major (coalesced over v)
  for (int i = tid; i < 3200; i += 256){
    int k = i >> 6, vl = i & 63, v = v0 + vl;
    if (v < 7000)
      bzg[(size_t)t*350000 + (size_t)k*7000 + v] = be[k][vl] * c0s[vl][k] * (1.f/32.f);
  }
  for (int i = tid; i < 1600; i += 256){
    float x1 = ((float*)c1s)[i];
    float x2 = ((float*)c1s)[1600 + i];
    if (x1 != 0.f) atomicAdd(&c1g1[(size_t)t*1600 + i], x1);
    if (x2 != 0.f) atomicAdd(&c1g2[(size_t)t*1600 + i], x2);
  }
  if (tid < 4) atomicAdd(&accs[tid], kred[tid]);
}

// ---------------- pass2: log-likelihood, 64-wide tile, 8-item dot ----------------
__global__ __launch_bounds__(256) void pass2(
    const float* __restrict__ bzg,    // [12][50][7000]
    const float* __restrict__ theta,
    const float* __restrict__ c1g1, const float* __restrict__ c1g2,
    const float* __restrict__ bows, float* __restrict__ accs)
{
  const int t = blockIdx.y, v0 = blockIdx.x * 64;
  __shared__ float tz[2][32][50];
  __shared__ float bzs[50][64];
  __shared__ float sr[2];
  const int tid = threadIdx.x;
  if (tid < 2) sr[tid] = 0.f;
  for (int i = tid; i < 1600; i += 256){
    int b = i / 50, k = i % 50;
    float th_ = theta[(size_t)t*1600 + i];
    tz[0][b][k] = th_ * c1g1[(size_t)t*1600 + i] * (1.f/5000.f);
    tz[1][b][k] = th_ * c1g2[(size_t)t*1600 + i] * (1.f/2000.f);
  }
  for (int i = tid; i < 3200; i += 256){
    int k = i >> 6, vl = i & 63, v = v0 + vl;
    bzs[k][vl] = (v < 7000) ? bzg[(size_t)t*350000 + (size_t)k*7000 + v] : 0.f;
  }
  __syncthreads();

  const int b = tid >> 3, sub = tid & 7;
  int part[8];
  #pragma unroll
  for (int i=0;i<8;++i) part[i] = (v0 + sub + 8*i >= 5000);
  float dot[8];
  #pragma unroll
  for (int i=0;i<8;++i) dot[i] = 0.f;
  for (int k = 0; k < 50; ++k){
    float t0 = tz[0][b][k], t1 = tz[1][b][k];
    #pragma unroll
    for (int i=0;i<8;++i)
      dot[i] = fmaf(part[i] ? t1 : t0, bzs[k][sub + 8*i], dot[i]);
  }
  float s1 = 0.f, s2 = 0.f;
  #pragma unroll
  for (int i=0;i<8;++i){
    const int v = v0 + sub + 8*i;
    if (v < 7000){
      const float w = bows[((size_t)b*12 + t)*7000 + v];
      const float l = __logf(dot[i]) * w;
      if (part[i]) s2 += l; else s1 += l;
    }
  }
  s1 = wsum64(s1); s2 = wsum64(s2);
  if ((tid & 63) == 0){ atomicAdd(&sr[0], s1); atomicAdd(&sr[1], s2); }
  __syncthreads();
  if (tid < 2) atomicAdd(&accs[4 + tid], sr[tid]);
}

// ---------------- finalize ----------------
__global__ void finalize_k(const float* __restrict__ accs, float* __restrict__ out){
  if (threadIdx.x == 0 && blockIdx.x == 0){
    out[0] = -(accs[4] + accs[5]) * (1.f/32.f);           // recon_loss
    out[1] = accs[6];                                     // kld_theta
    out[2] = -accs[0]/(32.f*5000.f) - accs[1]/32.f;       // kld_z1
    out[3] = -accs[2]/(32.f*2000.f) - accs[3]/32.f;       // kld_z2
    out[4] = accs[7];                                     // kld_alpha
  }
}

// ---------------- host launcher ----------------
extern "C" void kernel_launch(void* const* d_in, const int* in_sizes, int n_in,
                              void* d_out, int out_size, void* d_ws, size_t ws_size,
                              hipStream_t stream)
{
  const float* bows   = (const float*)d_in[0];
  const float* nbows  = (const float*)d_in[1];
  const float* qmap_w = (const float*)d_in[2];
  const float* qmap_b = (const float*)d_in[3];
  const float* wih0   = (const float*)d_in[4];
  const float* whh0   = (const float*)d_in[5];
  const float* bih0   = (const float*)d_in[6];
  const float* bhh0   = (const float*)d_in[7];
  const float* wih1   = (const float*)d_in[8];
  const float* whh1   = (const float*)d_in[9];
  const float* bih1   = (const float*)d_in[10];
  const float* bhh1   = (const float*)d_in[11];
  const float* muW    = (const float*)d_in[12];
  const float* muB    = (const float*)d_in[13];
  const float* lsW    = (const float*)d_in[14];
  const float* lsB    = (const float*)d_in[15];
  const float* qmu    = (const float*)d_in[16];
  const float* qlsa   = (const float*)d_in[17];
  const float* rho1w  = (const float*)d_in[18];
  const float* rho1b  = (const float*)d_in[19];
  const float* rho2w  = (const float*)d_in[20];
  const float* rho2b  = (const float*)d_in[21];

  float* ws  = (float*)d_ws;
  float* out = (float*)d_out;

  float* c1g1  = ws + OFF_C1G1;
  float* c1g2  = ws + OFF_C1G2;
  float* accs  = ws + OFF_ACCS;
  float* bzg   = ws + OFF_C0G;
  float* beta  = ws + OFF_BETA;
  float* alphT = ws + OFF_ALPHAT;
  float* inp   = ws + OFF_INP;
  float* X0    = ws + OFF_X0;
  float* out0  = ws + OFF_OUT0;
  float* X1    = ws + OFF_X1;
  float* out1  = ws + OFF_OUT1;
  float* cst   = ws + OFF_CST;
  float* muH2  = ws + OFF_MUH;
  float* theta = ws + OFF_THETA;
  float* muW4  = ws + OFF_MUW4;
  float* w0T   = ws + OFF_W0T;
  float* w1T   = ws + OFF_W1T;
  float* bsum0 = ws + OFF_LTH;
  float* bsum1 = ws + OFF_LTH + 1600;
  float* mlb   = ws + OFF_LTH + 3200;
  float* rs    = ws + OFF_RS;

  prep_misc<<<2048, 256, 0, stream>>>(muW, lsW, qmu, bih0, bhh0, bih1, bhh1,
                                      muB, lsB, qmap_b, whh0, whh1,
                                      c1g1, muW4, ws + OFF_LSW4, alphT,
                                      bsum0, bsum1, mlb, rs, inp, w0T, w1T);
  kld_alpha_k<<<600, 64, 0, stream>>>(qmu, qlsa, accs);

  // inp += nbows @ qmap_w^T   [384,400], K=7000, 12-way split-K
  gemm_f32<<<dim3(7,6,12), 256, 0, stream>>>(nbows, 7000, qmap_w, 7000, inp, 400,
                                             384, 400, 7000, 592, nullptr, 0, nullptr);
  // X0 = inp @ wih0^T + (bih0+bhh0)
  gemm_f32<<<dim3(25,6,1), 256, 0, stream>>>(inp, 400, wih0, 400, X0, 1600,
                                             384, 1600, 400, 400, bsum0, 1, nullptr);
  for (int t = 0; t < 12; ++t)
    lstm_step4<<<200, 256, 0, stream>>>(X0, w0T, out0, cst, t);
  // X1 = out0 @ wih1^T + (bih1+bhh1)
  gemm_f32<<<dim3(25,6,1), 256, 0, stream>>>(out0, 400, wih1, 400, X1, 1600,
                                             384, 1600, 400, 400, bsum1, 1, nullptr);
  for (int t = 0; t < 12; ++t)
    lstm_step4<<<200, 256, 0, stream>>>(X1, w1T, out1, cst, t);

  // muH2 = out1 @ [muW4;lsW4]^T + [muB;lsB]
  gemm_f32<<<dim3(2,6,1), 256, 0, stream>>>(out1, 400, muW4, 400, muH2, 100,
                                            384, 100, 400, 400, mlb, 1, nullptr);
  theta_par<<<4, 512, 0, stream>>>(muH2, muW, lsW, theta, accs);

  // beta LOGITS (direct store + bias) with fused per-row sum(exp) accumulation
  gemm_f32<<<dim3(79,10,1), 256, 0, stream>>>(alphT, 300, rho1w, 300, beta, 7000,
                                              600, 5000, 300, 300, rho1b, 1, rs);
  gemm_f32<<<dim3(32,10,1), 256, 0, stream>>>(alphT, 300, rho2w, 300, beta + 5000, 7000,
                                              600, 2000, 300, 300, rho2b, 1, rs + 600);

  // likelihood (softmax fused into pass1 staging)
  pass1<<<dim3(110,12), 256, 0, stream>>>(beta, rs, theta, bzg, c1g1, c1g2, accs);
  pass2<<<dim3(110,12), 256, 0, stream>>>(bzg, theta, c1g1, c1g2, bows, accs);

  finalize_k<<<1, 64, 0, stream>>>(accs, out);
}

// Round 8
// 529.704 us; speedup vs baseline: 1.6000x; 1.1718x over previous
//
#include <hip/hip_runtime.h>

// ---------------- constants ----------------
#define LOG_DELTA (-5.2983174f)   // ln(0.005)
#define PIMAX     (0.0526f)       // provable bound: pi_k <= e/(49+e)

typedef __attribute__((ext_vector_type(8))) short short8v;
typedef __attribute__((ext_vector_type(4))) float f32x4;

// ws layout (float offsets)
constexpr size_t OFF_C1G1  = 0;                       // [12][32][50]
constexpr size_t OFF_C1G2  = 19200;                   // [12][32][50]
constexpr size_t OFF_ACCS  = 38400;                   // [16]
constexpr size_t OFF_C0G   = 38416;                   // bzg [12][50][7000]
constexpr size_t OFF_BETA  = OFF_C0G  + 4200000;      // [600][7000] logits
constexpr size_t OFF_ALPHAT= OFF_BETA + 4200000;
constexpr size_t OFF_INP   = OFF_ALPHAT + 180000;     // inp_bf ushort[384][416]
constexpr size_t OFF_X0    = OFF_INP  + 153600;       // [384][1600]
constexpr size_t OFF_OUT0  = OFF_X0   + 614400;       // hs0 [384][400]
constexpr size_t OFF_X1    = OFF_OUT0 + 153600;       // cst1|albf|r2bf region
constexpr size_t OFF_OUT1  = OFF_X1   + 614400;       // hs1 [384][400]
constexpr size_t OFF_CST   = OFF_OUT1 + 153600;       // cst0 [32][400]
constexpr size_t OFF_MUH   = OFF_CST  + 12800;        // [384][100]
constexpr size_t OFF_THETA = OFF_MUH  + 38400;        // [12][32][50]
constexpr size_t OFF_LTH   = OFF_THETA+ 19200;        // bsum0|bsum1|mlb|rs
constexpr size_t OFF_MUW4  = OFF_LTH  + 19200;        // [50][400]
constexpr size_t OFF_LSW4  = OFF_MUW4 + 20000;        // [50][400]
constexpr size_t OFF_RS    = OFF_LTH  + 3300;         // rowsum [2][600]
// overlay in bzg region (dead before pass1):
constexpr size_t OFF_W0T   = OFF_C0G;                 // f32 [400][1600]
constexpr size_t OFF_W1T   = OFF_C0G + 640000;        // f32 [400][1600]
constexpr size_t OFF_WIH1T = OFF_C0G + 1280000;       // f32 [400][1600]
constexpr size_t OFF_NBBF  = OFF_C0G + 1920000;       // ushort[384][7040]
constexpr size_t OFF_R1BF  = OFF_C0G + 3271680;       // ushort[5000][320]
// overlay in beta region (dead before beta GEMMs):
constexpr size_t OFF_QWBF  = OFF_BETA;                // ushort[400][7040]
constexpr size_t OFF_W0BF  = OFF_BETA + 1408000;      // ushort[1600][416]
// overlay in X1 region (X1 eliminated):
constexpr size_t OFF_CST1  = OFF_X1;                  // f32 [32][400]
constexpr size_t OFF_ALBF  = OFF_X1 + 12800;          // ushort[600][320]
constexpr size_t OFF_R2BF  = OFF_X1 + 108800;         // ushort[2000][320]

// ---------------- helpers ----------------
__device__ __forceinline__ float wsum64(float x){
  #pragma unroll
  for (int o = 32; o; o >>= 1) x += __shfl_down(x, o);
  return x;
}
__device__ __forceinline__ float u01(unsigned int x){
  x ^= x >> 16; x *= 0x7feb352dU;
  x ^= x >> 15; x *= 0x846ca68bU;
  x ^= x >> 16;
  return ((float)x + 0.5f) * (1.0f/4294967296.0f);
}
__device__ __forceinline__ unsigned short f2bf(float x){
  unsigned int u = __float_as_uint(x);
  u += 0x7FFFu + ((u >> 16) & 1u);
  return (unsigned short)(u >> 16);
}

// ---------------- fused prep ----------------
__global__ void prep_misc(float* __restrict__ ws,
    const float* __restrict__ muW, const float* __restrict__ lsW,
    const float* __restrict__ qmu,
    const float* __restrict__ bi0, const float* __restrict__ bh0,
    const float* __restrict__ bi1, const float* __restrict__ bh1,
    const float* __restrict__ mb,  const float* __restrict__ lb,
    const float* __restrict__ qb,
    const float* __restrict__ whh0, const float* __restrict__ whh1,
    const float* __restrict__ wih1,
    const float* __restrict__ nbows, const float* __restrict__ qmap_w,
    const float* __restrict__ wih0,
    const float* __restrict__ rho1w, const float* __restrict__ rho2w)
{
  float* zbase = ws + OFF_C1G1;
  float* muW4  = ws + OFF_MUW4;
  float* lsW4  = ws + OFF_LSW4;
  unsigned short* albf = (unsigned short*)(ws + OFF_ALBF);
  float* bsum0 = ws + OFF_LTH;
  float* bsum1 = ws + OFF_LTH + 1600;
  float* mlb   = ws + OFF_LTH + 3200;
  float* rs    = ws + OFF_RS;
  unsigned int* inbz = (unsigned int*)(ws + OFF_INP);
  float* w0T   = ws + OFF_W0T;
  float* w1T   = ws + OFF_W1T;
  float* wi1T  = ws + OFF_WIH1T;
  unsigned short* nbbf = (unsigned short*)(ws + OFF_NBBF);
  unsigned short* qwbf = (unsigned short*)(ws + OFF_QWBF);
  unsigned short* w0bf = (unsigned short*)(ws + OFF_W0BF);
  unsigned short* r1bf = (unsigned short*)(ws + OFF_R1BF);
  unsigned short* r2bf = (unsigned short*)(ws + OFF_R2BF);

  for (long long i = blockIdx.x*blockDim.x + threadIdx.x; i < 10699748LL;
       i += (long long)gridDim.x*blockDim.x){
    if (i < 38416) zbase[i] = 0.f;
    else if (i < 58416){ int j = i - 38416; muW4[j] = muW[(j/400)*450 + (j%400)]; }
    else if (i < 78416){ int j = i - 58416; lsW4[j] = lsW[(j/400)*450 + (j%400)]; }
    else if (i < 270416){
      int j = i - 78416; int m = j/320, r = j%320; int t = m/50, k = m%50;
      albf[j] = (r < 300) ? f2bf(qmu[((size_t)k*12 + t)*300 + r]) : 0;
    }
    else if (i < 272016){ int j = i - 270416; bsum0[j] = bi0[j] + bh0[j]; }
    else if (i < 273616){ int j = i - 272016; bsum1[j] = bi1[j] + bh1[j]; }
    else if (i < 273716){ int j = i - 273616; mlb[j] = (j < 50) ? mb[j] : lb[j-50]; }
    else if (i < 274916){ int j = i - 273716; rs[j] = 0.f; }
    else if (i < 354788){ int j = i - 274916; inbz[j] = 0u; }
    else if (i < 994788){
      int j = i - 354788; int r = j/1600, col = j%1600;
      int u = col >> 2, g = col & 3;
      w0T[j] = whh0[((size_t)(g*400 + u))*400 + r];
    }
    else if (i < 1634788){
      int j = i - 994788; int r = j/1600, col = j%1600;
      int u = col >> 2, g = col & 3;
      w1T[j] = whh1[((size_t)(g*400 + u))*400 + r];
    }
    else if (i < 2274788){
      int j = i - 1634788; int r = j/1600, col = j%1600;
      int u = col >> 2, g = col & 3;
      wi1T[j] = wih1[((size_t)(g*400 + u))*400 + r];
    }
    else if (i < 4978148){
      int j = i - 2274788; int row = j/7040, v = j%7040;
      nbbf[j] = (v < 7000) ? f2bf(nbows[(size_t)row*7000 + v]) : 0;
    }
    else if (i < 7794148){
      int j = i - 4978148; int row = j/7040, v = j%7040;
      qwbf[j] = (v < 7000) ? f2bf(qmap_w[(size_t)row*7000 + v]) : 0;
    }
    else if (i < 8459748){
      int j = i - 7794148; int row = j/416, r = j%416;
      w0bf[j] = (r < 400) ? f2bf(wih0[(size_t)row*400 + r]) : 0;
    }
    else if (i < 10059748){
      int j = i - 8459748; int row = j/320, r = j%320;
      r1bf[j] = (r < 300) ? f2bf(rho1w[(size_t)row*300 + r]) : 0;
    }
    else {
      int j = i - 10059748; int row = j/320, r = j%320;
      r2bf[j] = (r < 300) ? f2bf(rho2w[(size_t)row*300 + r]) : 0;
    }
  }
}

// ---------------- MFMA bf16 GEMM: C[M][N] = A[M,Kp]bf * B[N,Kp]bf^T + bias ----
// Kp % 32 == 0. grid (ceil(N/64), ceil(M/64)), 256 threads (4 waves, 2x2).
// Cbf!=null -> bf16 store; else f32 store to Cf. rowsum: atomicAdd sum_n exp(val).
__global__ __launch_bounds__(256) void gemm_bf16(
    const unsigned short* __restrict__ A, int lda,
    const unsigned short* __restrict__ B, int ldb,
    float* __restrict__ Cf, unsigned short* __restrict__ Cbf, int ldc,
    int M, int N, int Kp,
    const float* __restrict__ bias, float* __restrict__ rowsum)
{
  __shared__ unsigned short As[64][40];
  __shared__ unsigned short Bs[64][40];
  __shared__ float sexp[64];
  const int tid = threadIdx.x;
  const int m0 = blockIdx.y * 64, n0 = blockIdx.x * 64;
  const int wave = tid >> 6, lane = tid & 63;
  const int wm = (wave >> 1) * 32, wn = (wave & 1) * 32;
  const int ra = tid >> 2, ck = (tid & 3) << 3;
  const int fr = lane & 15, fo = (lane >> 4) << 3;
  if (rowsum && tid < 64) sexp[tid] = 0.f;

  f32x4 acc00 = {0.f,0.f,0.f,0.f}, acc01 = {0.f,0.f,0.f,0.f};
  f32x4 acc10 = {0.f,0.f,0.f,0.f}, acc11 = {0.f,0.f,0.f,0.f};
  int4 pa, pb;
  {
    int rA = m0 + ra, rB = n0 + ra;
    pa = (rA < M) ? *(const int4*)&A[(size_t)rA*lda + ck] : make_int4(0,0,0,0);
    pb = (rB < N) ? *(const int4*)&B[(size_t)rB*ldb + ck] : make_int4(0,0,0,0);
  }
  const int nk = Kp >> 5;
  for (int kk = 0; kk < nk; ++kk){
    *(int4*)&As[ra][ck] = pa;
    *(int4*)&Bs[ra][ck] = pb;
    __syncthreads();
    if (kk + 1 < nk){
      int k0 = (kk + 1) << 5;
      int rA = m0 + ra, rB = n0 + ra;
      pa = (rA < M) ? *(const int4*)&A[(size_t)rA*lda + k0 + ck] : make_int4(0,0,0,0);
      pb = (rB < N) ? *(const int4*)&B[(size_t)rB*ldb + k0 + ck] : make_int4(0,0,0,0);
    }
    short8v a0 = *(const short8v*)&As[wm      + fr][fo];
    short8v a1 = *(const short8v*)&As[wm + 16 + fr][fo];
    short8v b0 = *(const short8v*)&Bs[wn      + fr][fo];
    short8v b1 = *(const short8v*)&Bs[wn + 16 + fr][fo];
    acc00 = __builtin_amdgcn_mfma_f32_16x16x32_bf16(a0, b0, acc00, 0, 0, 0);
    acc01 = __builtin_amdgcn_mfma_f32_16x16x32_bf16(a0, b1, acc01, 0, 0, 0);
    acc10 = __builtin_amdgcn_mfma_f32_16x16x32_bf16(a1, b0, acc10, 0, 0, 0);
    acc11 = __builtin_amdgcn_mfma_f32_16x16x32_bf16(a1, b1, acc11, 0, 0, 0);
    __syncthreads();
  }
  // epilogue: D col = lane&15, row = (lane>>4)*4 + reg  [guide §3, m89]
  const int rbase = (lane >> 4) << 2;
  auto epi = [&](f32x4 ac0, f32x4 ac1, int mi){
    #pragma unroll
    for (int reg = 0; reg < 4; ++reg){
      const int lr = wm + mi*16 + rbase + reg;
      const int gr = m0 + lr;
      float ex = 0.f;
      {
        int gc = n0 + wn + fr;
        if (gr < M && gc < N){
          float val = ac0[reg] + (bias ? bias[gc] : 0.f);
          if (Cbf) Cbf[(size_t)gr*ldc + gc] = f2bf(val);
          else     Cf [(size_t)gr*ldc + gc] = val;
          if (rowsum) ex += __expf(val);
        }
      }
      {
        int gc = n0 + wn + 16 + fr;
        if (gr < M && gc < N){
          float val = ac1[reg] + (bias ? bias[gc] : 0.f);
          if (Cbf) Cbf[(size_t)gr*ldc + gc] = f2bf(val);
          else     Cf [(size_t)gr*ldc + gc] = val;
          if (rowsum) ex += __expf(val);
        }
      }
      if (rowsum){
        ex += __shfl_xor(ex, 1); ex += __shfl_xor(ex, 2);
        ex += __shfl_xor(ex, 4); ex += __shfl_xor(ex, 8);
        if (fr == 0 && gr < M) atomicAdd(&sexp[lr], ex);
      }
    }
  };
  epi(acc00, acc01, 0);
  epi(acc10, acc11, 1);
  if (rowsum){
    __syncthreads();
    if (tid < 64 && m0 + tid < M) atomicAdd(&rowsum[m0 + tid], sexp[tid]);
  }
}

// ---------------- f32 GEMM (kept for tiny muH2) ----------------
__device__ __forceinline__ float4 g4(const float* __restrict__ base, int row, int nrows,
                                     int ld, int k, int kend){
  float4 v; v.x = v.y = v.z = v.w = 0.f;
  if (row < nrows){
    const float* q = base + (size_t)row*ld + k;
    if (k + 3 < kend) v = *(const float4*)q;
  }
  return v;
}
__global__ __launch_bounds__(256) void gemm_f32(
    const float* __restrict__ A, int lda,
    const float* __restrict__ B, int ldb,
    float* __restrict__ C, int ldc,
    int M, int N, int K,
    const float* __restrict__ bias)
{
  __shared__ __align__(16) float As[16][68];
  __shared__ __align__(16) float Bs[16][68];
  const int tid = threadIdx.x;
  const int m0 = blockIdx.y * 64, n0 = blockIdx.x * 64;
  const int lm  = tid >> 2;
  const int lkq = (tid & 3) << 2;
  const int ty = tid >> 4, tx = tid & 15;
  float acc[4][4];
  #pragma unroll
  for (int i=0;i<4;++i)
    #pragma unroll
    for (int j=0;j<4;++j) acc[i][j] = 0.f;
  for (int k0 = 0; k0 < K; k0 += 16){
    float4 av = g4(A, m0+lm, M, lda, k0+lkq, K);
    float4 bv = g4(B, n0+lm, N, ldb, k0+lkq, K);
    As[lkq+0][lm]=av.x; As[lkq+1][lm]=av.y; As[lkq+2][lm]=av.z; As[lkq+3][lm]=av.w;
    Bs[lkq+0][lm]=bv.x; Bs[lkq+1][lm]=bv.y; Bs[lkq+2][lm]=bv.z; Bs[lkq+3][lm]=bv.w;
    __syncthreads();
    #pragma unroll
    for (int kk = 0; kk < 16; ++kk){
      const float4 a = *(const float4*)&As[kk][ty<<2];
      const float4 b = *(const float4*)&Bs[kk][tx<<2];
      float ar[4] = {a.x,a.y,a.z,a.w};
      float br[4] = {b.x,b.y,b.z,b.w};
      #pragma unroll
      for (int i=0;i<4;++i)
        #pragma unroll
        for (int j=0;j<4;++j) acc[i][j] = fmaf(ar[i], br[j], acc[i][j]);
    }
    __syncthreads();
  }
  const int om = m0 + (ty<<2), on = n0 + (tx<<2);
  #pragma unroll
  for (int i=0;i<4;++i)
    #pragma unroll
    for (int j=0;j<4;++j)
      if (om+i < M && on+j < N)
        C[(size_t)(om+i)*ldc + (on+j)] = acc[i][j] + (bias ? bias[on+j] : 0.f);
}

// ---------------- pipelined LSTM: layer0 step t || layer1 step t-1 ----------------
// grid 400 x 256. blocks <200: layer0 (u-tile 2). blocks >=200: layer1 with wih1
// fused (two-phase staging: h0(t)@wih1T then h1(t-1)@w1T).
__global__ __launch_bounds__(256) void lstm_pipe(
    const float* __restrict__ X0,    const float* __restrict__ w0T,
    const float* __restrict__ wi1T,  const float* __restrict__ w1T,
    const float* __restrict__ bsum1,
    float* __restrict__ hs0, float* __restrict__ hs1,
    float* __restrict__ cst0, float* __restrict__ cst1, int step)
{
  __shared__ __align__(16) float4 hq4[100*32];
  __shared__ __align__(16) float4 red4[4][32][2];
  const int tid = threadIdx.x;
  const int rh = tid >> 6;
  const int b  = (tid & 63) >> 1;
  const int ul = tid & 1;
  const int rq0 = rh * 25;

  if (blockIdx.x < 200){
    const int t = step;
    if (t >= 12) return;
    const int U0 = blockIdx.x * 2;
    const int u = U0 + ul;
    if (t > 0){
      for (int i = tid; i < 3200; i += 256){
        int bb = i & 31, rq = i >> 5;
        hq4[rq*32 + bb] = *(const float4*)&hs0[((size_t)(bb*12 + (t-1)))*400 + rq*4];
      }
      __syncthreads();
      const float* wcol = w0T + (size_t)u*4;
      float4 acc = {0.f,0.f,0.f,0.f};
      #pragma unroll 5
      for (int rq = rq0; rq < rq0 + 25; ++rq){
        float4 h4 = hq4[rq*32 + b];
        float hr[4] = {h4.x, h4.y, h4.z, h4.w};
        #pragma unroll
        for (int dr = 0; dr < 4; ++dr){
          float4 w4 = *(const float4*)&wcol[(size_t)(rq*4 + dr)*1600];
          acc.x = fmaf(hr[dr], w4.x, acc.x);
          acc.y = fmaf(hr[dr], w4.y, acc.y);
          acc.z = fmaf(hr[dr], w4.z, acc.z);
          acc.w = fmaf(hr[dr], w4.w, acc.w);
        }
      }
      red4[rh][b][ul] = acc;
    }
    __syncthreads();
    if (tid < 64){
      const int bb = tid >> 1, uu = U0 + (tid & 1);
      float4 a = {0.f,0.f,0.f,0.f};
      if (t > 0){
        #pragma unroll
        for (int w = 0; w < 4; ++w){
          float4 r = red4[w][bb][tid & 1];
          a.x += r.x; a.y += r.y; a.z += r.z; a.w += r.w;
        }
      }
      const size_t xrow = ((size_t)bb*12 + t)*1600;
      float gi = a.x + X0[xrow          + uu];
      float gf = a.y + X0[xrow +  400   + uu];
      float gg = a.z + X0[xrow +  800   + uu];
      float go = a.w + X0[xrow + 1200   + uu];
      float ii = 1.f/(1.f + expf(-gi));
      float ff = 1.f/(1.f + expf(-gf));
      float tg = tanhf(gg);
      float oo = 1.f/(1.f + expf(-go));
      float c = (t == 0) ? 0.f : cst0[bb*400 + uu];
      c = ff*c + ii*tg;
      cst0[bb*400 + uu] = c;
      hs0[((size_t)bb*12 + t)*400 + uu] = oo * tanhf(c);
    }
  } else {
    const int t = step - 1;
    if (t < 0) return;
    const int U0 = (blockIdx.x - 200) * 2;
    const int u = U0 + ul;
    float4 acc = {0.f,0.f,0.f,0.f};
    // phase A: h0(t) @ wih1T
    for (int i = tid; i < 3200; i += 256){
      int bb = i & 31, rq = i >> 5;
      hq4[rq*32 + bb] = *(const float4*)&hs0[((size_t)(bb*12 + t))*400 + rq*4];
    }
    __syncthreads();
    {
      const float* wcol = wi1T + (size_t)u*4;
      #pragma unroll 5
      for (int rq = rq0; rq < rq0 + 25; ++rq){
        float4 h4 = hq4[rq*32 + b];
        float hr[4] = {h4.x, h4.y, h4.z, h4.w};
        #pragma unroll
        for (int dr = 0; dr < 4; ++dr){
          float4 w4 = *(const float4*)&wcol[(size_t)(rq*4 + dr)*1600];
          acc.x = fmaf(hr[dr], w4.x, acc.x);
          acc.y = fmaf(hr[dr], w4.y, acc.y);
          acc.z = fmaf(hr[dr], w4.z, acc.z);
          acc.w = fmaf(hr[dr], w4.w, acc.w);
        }
      }
    }
    __syncthreads();
    // phase B: h1(t-1) @ w1T
    if (t > 0){
      for (int i = tid; i < 3200; i += 256){
        int bb = i & 31, rq = i >> 5;
        hq4[rq*32 + bb] = *(const float4*)&hs1[((size_t)(bb*12 + (t-1)))*400 + rq*4];
      }
    }
    __syncthreads();
    if (t > 0){
      const float* wcol = w1T + (size_t)u*4;
      #pragma unroll 5
      for (int rq = rq0; rq < rq0 + 25; ++rq){
        float4 h4 = hq4[rq*32 + b];
        float hr[4] = {h4.x, h4.y, h4.z, h4.w};
        #pragma unroll
        for (int dr = 0; dr < 4; ++dr){
          float4 w4 = *(const float4*)&wcol[(size_t)(rq*4 + dr)*1600];
          acc.x = fmaf(hr[dr], w4.x, acc.x);
          acc.y = fmaf(hr[dr], w4.y, acc.y);
          acc.z = fmaf(hr[dr], w4.z, acc.z);
          acc.w = fmaf(hr[dr], w4.w, acc.w);
        }
      }
    }
    red4[rh][b][ul] = acc;
    __syncthreads();
    if (tid < 64){
      const int bb = tid >> 1, uu = U0 + (tid & 1);
      float4 a = {0.f,0.f,0.f,0.f};
      #pragma unroll
      for (int w = 0; w < 4; ++w){
        float4 r = red4[w][bb][tid & 1];
        a.x += r.x; a.y += r.y; a.z += r.z; a.w += r.w;
      }
      float gi = a.x + bsum1[        uu];
      float gf = a.y + bsum1[ 400 + uu];
      float gg = a.z + bsum1[ 800 + uu];
      float go = a.w + bsum1[1200 + uu];
      float ii = 1.f/(1.f + expf(-gi));
      float ff = 1.f/(1.f + expf(-gf));
      float tg = tanhf(gg);
      float oo = 1.f/(1.f + expf(-go));
      float c = (t == 0) ? 0.f : cst1[bb*400 + uu];
      c = ff*c + ii*tg;
      cst1[bb*400 + uu] = c;
      hs1[((size_t)bb*12 + t)*400 + uu] = oo * tanhf(c);
    }
  }
}

// ---------------- theta head (4 blocks, 8 b's each) ----------------
__global__ __launch_bounds__(512) void theta_par(
    const float* __restrict__ muH2,
    const float* __restrict__ muW, const float* __restrict__ lsW,
    float* __restrict__ theta, float* __restrict__ accs)
{
  __shared__ float zsall[12][8][50];
  __shared__ float wm[50][51], wl[50][51];
  __shared__ float ktot;
  const int tid = threadIdx.x;
  const int b0 = blockIdx.x * 8;
  for (int i = tid; i < 2500; i += 512){
    int k = i / 50, j = i % 50;
    wm[k][j] = muW[k*450 + 400 + j];
    wl[k][j] = lsW[k*450 + 400 + j];
  }
  if (tid == 0) ktot = 0.f;
  __syncthreads();
  const float dd = expf(LOG_DELTA) + 1e-6f;
  for (int t = 0; t < 12; ++t){
    float kpart = 0.f;
    if (tid < 400){
      int bl = tid / 50, k = tid % 50, b = b0 + bl;
      float m = muH2[((size_t)b*12 + t)*100 + k];
      float l = muH2[((size_t)b*12 + t)*100 + 50 + k];
      float zp = 0.f;
      if (t > 0){
        zp = zsall[t-1][bl][k];
        float sm = 0.f, sl = 0.f;
        #pragma unroll 5
        for (int j = 0; j < 50; ++j){
          float z = zsall[t-1][bl][j];
          sm = fmaf(z, wm[k][j], sm);
          sl = fmaf(z, wl[k][j], sl);
        }
        m += sm; l += sl;
      }
      zsall[t][bl][k] = m;
      float denom = (t > 0) ? dd : (1.f + 1e-6f);
      float pls = (t > 0) ? LOG_DELTA : 0.f;
      float d = m - zp;
      kpart += (expf(l) + d*d)/denom - 1.f + pls - l;
    }
    kpart = wsum64(kpart);
    if ((tid & 63) == 0) atomicAdd(&ktot, 0.5f * kpart / 32.f);
    __syncthreads();
  }
  for (int rr = tid; rr < 96; rr += 512){
    int t = rr >> 3, bl = rr & 7, b = b0 + bl;
    float m = -3.0e38f;
    for (int k = 0; k < 50; ++k) m = fmaxf(m, zsall[t][bl][k]);
    float S = 0.f;
    for (int k = 0; k < 50; ++k) S += expf(zsall[t][bl][k] - m);
    float inv = 1.f/S;
    for (int k = 0; k < 50; ++k)
      theta[((size_t)t*32 + b)*50 + k] = expf(zsall[t][bl][k] - m) * inv;
  }
  if (tid == 0) atomicAdd(&accs[6], ktot);
}

// ---------------- kld_alpha ----------------
__global__ void kld_alpha_k(const float* __restrict__ qmu, const float* __restrict__ qls,
                            float* __restrict__ accs){
  const int t = blockIdx.x / 50, k = blockIdx.x % 50;
  const size_t base  = ((size_t)k*12 + t)*300;
  const size_t pbase = ((size_t)k*12 + (t-1))*300;
  const float dd  = (t > 0) ? (expf(LOG_DELTA) + 1e-6f) : (1.f + 1e-6f);
  const float pls = (t > 0) ? LOG_DELTA : 0.f;
  float s = 0.f;
  for (int r = threadIdx.x; r < 300; r += 64){
    float qm = qmu[base + r], ql = qls[base + r];
    float pm = (t > 0) ? qmu[pbase + r] : 0.f;
    float d = qm - pm;
    s += (expf(ql) + d*d)/dd - 1.f + pls - ql;
  }
  s = wsum64(s);
  if (threadIdx.x == 0) atomicAdd(&accs[7], 0.5f * s / 50.f);
}

// ---------------- pass1: rejection sampling, packed counters ----------------
__global__ __launch_bounds__(256) void pass1(
    const float* __restrict__ blog, const float* __restrict__ rs,
    const float* __restrict__ theta,
    float* __restrict__ bzg,
    float* __restrict__ c1g1, float* __restrict__ c1g2,
    float* __restrict__ accs)
{
  const int t = blockIdx.y;
  const int v0 = blockIdx.x * 64;
  __shared__ float th[32][50];
  __shared__ float be[50][64];
  __shared__ float c0s[64][50];
  __shared__ unsigned int c1p[2][32][25];
  __shared__ float rlog[2][50];
  __shared__ float kred[4];
  const int tid = threadIdx.x;

  if (tid < 100){
    int p = tid / 50, k = tid % 50;
    rlog[p][k] = __logf(rs[p*600 + t*50 + k]);
  }
  float lg[13];
  #pragma unroll
  for (int j = 0; j < 13; ++j){
    int i = tid + j*256;
    lg[j] = -40.f;
    if (i < 3200){
      int k = i >> 6, vl = i & 63, v = v0 + vl;
      if (v < 7000) lg[j] = blog[((size_t)t*50 + k)*7000 + v];
    }
  }
  #pragma unroll
  for (int j = 0; j < 7; ++j){
    int i = tid + j*256;
    if (i < 1600) th[i/50][i%50] = theta[(size_t)t*1600 + i];
  }
  #pragma unroll
  for (int j = 0; j < 13; ++j){
    int i = tid + j*256;
    if (i < 3200) ((float*)c0s)[i] = 0.f;
  }
  #pragma unroll
  for (int j = 0; j < 7; ++j){
    int i = tid + j*256;
    if (i < 1600) ((unsigned int*)c1p)[i] = 0u;
  }
  if (tid < 4) kred[tid] = 0.f;
  __syncthreads();
  #pragma unroll
  for (int j = 0; j < 13; ++j){
    int i = tid + j*256;
    if (i < 3200){
      int k = i >> 6, vl = i & 63, v = v0 + vl;
      int p = (v >= 5000);
      be[k][vl] = __expf(lg[j] - rlog[p][k]);
    }
  }
  __syncthreads();

  const int b = tid >> 3, sub = tid & 7;
  float S[8];
  #pragma unroll
  for (int i = 0; i < 8; ++i) S[i] = 0.f;
  for (int k = 0; k < 50; ++k){
    float tk = th[b][k];
    #pragma unroll
    for (int i = 0; i < 8; ++i)
      S[i] += __expf(tk * be[k][sub + 8*i]);
  }
  float inv[8];
  #pragma unroll
  for (int i = 0; i < 8; ++i) inv[i] = 1.f / S[i];

  int ks[8]; float pis[8];
  unsigned fmask = 0;
  const int vbase = (t*32 + b)*7000 + v0 + sub;
  #pragma unroll
  for (int i = 0; i < 8; ++i){
    ks[i] = 0; pis[i] = 1.f;
    if (v0 + sub + 8*i >= 7000) fmask |= 1u << i;
  }
  int round = 0;
  while (true){
    const unsigned roff = (unsigned)round * 0x9E3779B9u;
    #pragma unroll
    for (int i = 0; i < 8; ++i){
      if (!((fmask >> i) & 1u)){
        const unsigned bse = (unsigned)(vbase + 8*i) * 2u;
        float u1 = u01(bse + roff);
        float u2 = u01(bse + 1u + roff);
        int kp = min((int)(u1 * 50.f), 49);
        float pi = __expf(th[b][kp] * be[kp][sub + 8*i]) * inv[i];
        if (u2 <= __expf(pi - PIMAX) || round >= 7){
          ks[i] = kp; pis[i] = pi; fmask |= 1u << i;
        }
      }
    }
    ++round;
    if (__all(fmask == 255u)) break;
  }

  float kA1 = 0.f, kB1 = 0.f, kA2 = 0.f, kB2 = 0.f;
  #pragma unroll
  for (int i = 0; i < 8; ++i){
    const int vl = sub + 8*i, v = v0 + vl;
    if (v < 7000){
      float lpis = __logf(pis[i]);
      float lt   = __logf(th[b][ks[i]]);
      if (v >= 5000){ kA2 += lt; kB2 += pis[i]*lpis; }
      else          { kA1 += lt; kB1 += pis[i]*lpis; }
      atomicAdd(&c0s[vl][ks[i]], 1.f);
      atomicAdd(&c1p[(v >= 5000) ? 1 : 0][b][ks[i] >> 1],
                (ks[i] & 1) ? 65536u : 1u);
    }
  }
  kA1 = wsum64(kA1); kB1 = wsum64(kB1); kA2 = wsum64(kA2); kB2 = wsum64(kB2);
  if ((tid & 63) == 0){
    atomicAdd(&kred[0], kA1); atomicAdd(&kred[1], kB1);
    atomicAdd(&kred[2], kA2); atomicAdd(&kred[3], kB2);
  }
  __syncthreads();
  #pragma unroll
  for (int j = 0; j < 13; ++j){
    int i = tid + j*256;
    if (i < 3200){
      int k = i >> 6, vl = i & 63, v = v0 + vl;
      if (v < 7000)
        bzg[(size_t)t*350000 + (size_t)k*7000 + v] = be[k][vl] * c0s[vl][k] * (1.f/32.f);
    }
  }
  for (int i = tid; i < 1600; i += 256){
    int b2 = i / 50, k2 = i % 50;
    unsigned w1 = c1p[0][b2][k2 >> 1];
    unsigned w2 = c1p[1][b2][k2 >> 1];
    unsigned cnt1 = (k2 & 1) ? (w1 >> 16) : (w1 & 0xFFFFu);
    unsigned cnt2 = (k2 & 1) ? (w2 >> 16) : (w2 & 0xFFFFu);
    if (cnt1) atomicAdd(&c1g1[(size_t)t*1600 + i], (float)cnt1);
    if (cnt2) atomicAdd(&c1g2[(size_t)t*1600 + i], (float)cnt2);
  }
  if (tid < 4) atomicAdd(&accs[tid], kred[tid]);
}

// ---------------- pass2: log-likelihood ----------------
__global__ __launch_bounds__(256) void pass2(
    const float* __restrict__ bzg, const float* __restrict__ theta,
    const float* __restrict__ c1g1, const float* __restrict__ c1g2,
    const float* __restrict__ bows, float* __restrict__ accs)
{
  const int t = blockIdx.y, v0 = blockIdx.x * 64;
  __shared__ float tz[2][32][50];
  __shared__ float bzs[50][64];
  __shared__ float sr[2];
  const int tid = threadIdx.x;
  if (tid < 2) sr[tid] = 0.f;
  for (int i = tid; i < 1600; i += 256){
    int b = i / 50, k = i % 50;
    float th_ = theta[(size_t)t*1600 + i];
    tz[0][b][k] = th_ * c1g1[(size_t)t*1600 + i] * (1.f/5000.f);
    tz[1][b][k] = th_ * c1g2[(size_t)t*1600 + i] * (1.f/2000.f);
  }
  for (int i = tid; i < 3200; i += 256){
    int k = i >> 6, vl = i & 63, v = v0 + vl;
    bzs[k][vl] = (v < 7000) ? bzg[(size_t)t*350000 + (size_t)k*7000 + v] : 0.f;
  }
  __syncthreads();

  const int b = tid >> 3, sub = tid & 7;
  int part[8];
  #pragma unroll
  for (int i = 0; i < 8; ++i) part[i] = (v0 + sub + 8*i >= 5000);
  float dot[8];
  #pragma unroll
  for (int i = 0; i < 8; ++i) dot[i] = 0.f;
  for (int k = 0; k < 50; ++k){
    float t0 = tz[0][b][k], t1 = tz[1][b][k];
    #pragma unroll
    for (int i = 0; i < 8; ++i)
      dot[i] = fmaf(part[i] ? t1 : t0, bzs[k][sub + 8*i], dot[i]);
  }
  float s1 = 0.f, s2 = 0.f;
  #pragma unroll
  for (int i = 0; i < 8; ++i){
    const int v = v0 + sub + 8*i;
    if (v < 7000){
      const float w = bows[((size_t)b*12 + t)*7000 + v];
      const float l = __logf(dot[i]) * w;
      if (part[i]) s2 += l; else s1 += l;
    }
  }
  s1 = wsum64(s1); s2 = wsum64(s2);
  if ((tid & 63) == 0){ atomicAdd(&sr[0], s1); atomicAdd(&sr[1], s2); }
  __syncthreads();
  if (tid < 2) atomicAdd(&accs[4 + tid], sr[tid]);
}

// ---------------- finalize ----------------
__global__ void finalize_k(const float* __restrict__ accs, float* __restrict__ out){
  if (threadIdx.x == 0 && blockIdx.x == 0){
    out[0] = -(accs[4] + accs[5]) * (1.f/32.f);
    out[1] = accs[6];
    out[2] = -accs[0]/(32.f*5000.f) - accs[1]/32.f;
    out[3] = -accs[2]/(32.f*2000.f) - accs[3]/32.f;
    out[4] = accs[7];
  }
}

// ---------------- host launcher ----------------
extern "C" void kernel_launch(void* const* d_in, const int* in_sizes, int n_in,
                              void* d_out, int out_size, void* d_ws, size_t ws_size,
                              hipStream_t stream)
{
  const float* bows   = (const float*)d_in[0];
  const float* nbows  = (const float*)d_in[1];
  const float* qmap_w = (const float*)d_in[2];
  const float* qmap_b = (const float*)d_in[3];
  const float* wih0   = (const float*)d_in[4];
  const float* whh0   = (const float*)d_in[5];
  const float* wih1   = (const float*)d_in[8];
  const float* whh1   = (const float*)d_in[9];
  const float* bih0   = (const float*)d_in[6];
  const float* bhh0   = (const float*)d_in[7];
  const float* bih1   = (const float*)d_in[10];
  const float* bhh1   = (const float*)d_in[11];
  const float* muW    = (const float*)d_in[12];
  const float* muB    = (const float*)d_in[13];
  const float* lsW    = (const float*)d_in[14];
  const float* lsB    = (const float*)d_in[15];
  const float* qmu    = (const float*)d_in[16];
  const float* qlsa   = (const float*)d_in[17];
  const float* rho1w  = (const float*)d_in[18];
  const float* rho1b  = (const float*)d_in[19];
  const float* rho2w  = (const float*)d_in[20];
  const float* rho2b  = (const float*)d_in[21];

  float* ws  = (float*)d_ws;
  float* out = (float*)d_out;

  float* c1g1  = ws + OFF_C1G1;
  float* c1g2  = ws + OFF_C1G2;
  float* accs  = ws + OFF_ACCS;
  float* bzg   = ws + OFF_C0G;
  float* beta  = ws + OFF_BETA;
  float* X0    = ws + OFF_X0;
  float* hs0   = ws + OFF_OUT0;
  float* hs1   = ws + OFF_OUT1;
  float* cst0  = ws + OFF_CST;
  float* cst1  = ws + OFF_CST1;
  float* muH2  = ws + OFF_MUH;
  float* theta = ws + OFF_THETA;
  float* muW4  = ws + OFF_MUW4;
  float* bsum0 = ws + OFF_LTH;
  float* bsum1 = ws + OFF_LTH + 1600;
  float* mlb   = ws + OFF_LTH + 3200;
  float* rs    = ws + OFF_RS;
  unsigned short* nbbf  = (unsigned short*)(ws + OFF_NBBF);
  unsigned short* qwbf  = (unsigned short*)(ws + OFF_QWBF);
  unsigned short* inpbf = (unsigned short*)(ws + OFF_INP);
  unsigned short* w0bf  = (unsigned short*)(ws + OFF_W0BF);
  unsigned short* albf  = (unsigned short*)(ws + OFF_ALBF);
  unsigned short* r1bf  = (unsigned short*)(ws + OFF_R1BF);
  unsigned short* r2bf  = (unsigned short*)(ws + OFF_R2BF);
  float* w0T  = ws + OFF_W0T;
  float* w1T  = ws + OFF_W1T;
  float* wi1T = ws + OFF_WIH1T;

  prep_misc<<<4096, 256, 0, stream>>>(ws, muW, lsW, qmu, bih0, bhh0, bih1, bhh1,
                                      muB, lsB, qmap_b, whh0, whh1, wih1,
                                      nbows, qmap_w, wih0, rho1w, rho2w);
  kld_alpha_k<<<600, 64, 0, stream>>>(qmu, qlsa, accs);

  // inp_bf = bf16(nbows @ qmap_w^T + qb)   M=384 N=400 Kp=7040
  gemm_bf16<<<dim3(7,6), 256, 0, stream>>>(nbbf, 7040, qwbf, 7040,
                                           nullptr, inpbf, 416,
                                           384, 400, 7040, qmap_b, nullptr);
  // X0 = inp_bf @ wih0^T + (bih0+bhh0)     M=384 N=1600 Kp=416
  gemm_bf16<<<dim3(25,6), 256, 0, stream>>>(inpbf, 416, w0bf, 416,
                                            X0, nullptr, 1600,
                                            384, 1600, 416, bsum0, nullptr);
  // pipelined double-layer LSTM: 13 launches
  for (int i = 0; i < 13; ++i)
    lstm_pipe<<<400, 256, 0, stream>>>(X0, w0T, wi1T, w1T, bsum1,
                                       hs0, hs1, cst0, cst1, i);

  // muH2 = hs1 @ [muW4;lsW4]^T + [muB;lsB]
  gemm_f32<<<dim3(2,6), 256, 0, stream>>>(hs1, 400, muW4, 400, muH2, 100,
                                          384, 100, 400, mlb);
  theta_par<<<4, 512, 0, stream>>>(muH2, muW, lsW, theta, accs);

  // beta logits via MFMA + fused row sum(exp)
  gemm_bf16<<<dim3(79,10), 256, 0, stream>>>(albf, 320, r1bf, 320,
                                             beta, nullptr, 7000,
                                             600, 5000, 320, rho1b, rs);
  gemm_bf16<<<dim3(32,10), 256, 0, stream>>>(albf, 320, r2bf, 320,
                                             beta + 5000, nullptr, 7000,
                                             600, 2000, 320, rho2b, rs + 600);

  pass1<<<dim3(110,12), 256, 0, stream>>>(beta, rs, theta, bzg, c1g1, c1g2, accs);
  pass2<<<dim3(110,12), 256, 0, stream>>>(bzg, theta, c1g1, c1g2, bows, accs);

  finalize_k<<<1, 64, 0, stream>>>(accs, out);
}

// Round 9
// 466.662 us; speedup vs baseline: 1.8162x; 1.1351x over previous
//
#include <hip/hip_runtime.h>

// ---------------- constants ----------------
#define LOG_DELTA (-5.2983174f)   // ln(0.005)
#define PIMAX     (0.0526f)       // provable bound: pi_k <= e/(49+e)

typedef __attribute__((ext_vector_type(8))) short short8v;
typedef __attribute__((ext_vector_type(4))) float f32x4;

// ws layout (float offsets)
constexpr size_t OFF_C1G1  = 0;                       // [12][32][50]
constexpr size_t OFF_C1G2  = 19200;                   // [12][32][50]
constexpr size_t OFF_ACCS  = 38400;                   // [16]
constexpr size_t OFF_C0G   = 38416;                   // bzg [12][50][7000]
constexpr size_t OFF_BETA  = OFF_C0G  + 4200000;      // [600][7000] logits
constexpr size_t OFF_ALPHAT= OFF_BETA + 4200000;      // inp_f32 [384][400]
constexpr size_t OFF_INP   = OFF_ALPHAT + 180000;     // inp_bf ushort[384][416]
constexpr size_t OFF_X0    = OFF_INP  + 153600;       // [384][1600]
constexpr size_t OFF_OUT0  = OFF_X0   + 614400;       // hs0 [384][400]
constexpr size_t OFF_X1    = OFF_OUT0 + 153600;       // cst1|albf|r2bf region
constexpr size_t OFF_OUT1  = OFF_X1   + 614400;       // hs1 [384][400]
constexpr size_t OFF_CST   = OFF_OUT1 + 153600;       // cst0 [32][400]
constexpr size_t OFF_MUH   = OFF_CST  + 12800;        // [384][100]
constexpr size_t OFF_THETA = OFF_MUH  + 38400;        // [12][32][50]
constexpr size_t OFF_LTH   = OFF_THETA+ 19200;        // bsum0|bsum1|mlb|rs
constexpr size_t OFF_MUW4  = OFF_LTH  + 19200;        // [50][400]
constexpr size_t OFF_LSW4  = OFF_MUW4 + 20000;        // [50][400]
constexpr size_t OFF_RS    = OFF_LTH  + 3300;         // rowsum [2][600]
// overlay in bzg region (dead before pass1):
constexpr size_t OFF_W0T   = OFF_C0G;                 // f32 [400][1600]
constexpr size_t OFF_W1T   = OFF_C0G + 640000;        // f32 [400][1600]
constexpr size_t OFF_WIH1T = OFF_C0G + 1280000;       // f32 [400][1600]
constexpr size_t OFF_NBBF  = OFF_C0G + 1920000;       // ushort[384][7040]
constexpr size_t OFF_R1BF  = OFF_C0G + 3271680;       // ushort[5000][320]
// overlay in beta region (dead before beta GEMMs):
constexpr size_t OFF_QWBF  = OFF_BETA;                // ushort[400][7040]
constexpr size_t OFF_W0BF  = OFF_BETA + 1408000;      // ushort[1600][416]
// overlay in X1 region (X1 eliminated):
constexpr size_t OFF_CST1  = OFF_X1;                  // f32 [32][400]
constexpr size_t OFF_ALBF  = OFF_X1 + 12800;          // ushort[600][320]
constexpr size_t OFF_R2BF  = OFF_X1 + 108800;         // ushort[2000][320]

// ---------------- helpers ----------------
__device__ __forceinline__ float wsum64(float x){
  #pragma unroll
  for (int o = 32; o; o >>= 1) x += __shfl_down(x, o);
  return x;
}
__device__ __forceinline__ float u01(unsigned int x){
  x ^= x >> 16; x *= 0x7feb352dU;
  x ^= x >> 15; x *= 0x846ca68bU;
  x ^= x >> 16;
  return ((float)x + 0.5f) * (1.0f/4294967296.0f);
}
__device__ __forceinline__ unsigned short f2bf(float x){
  unsigned int u = __float_as_uint(x);
  u += 0x7FFFu + ((u >> 16) & 1u);
  return (unsigned short)(u >> 16);
}

// ---------------- fused prep ----------------
__global__ void prep_misc(float* __restrict__ ws,
    const float* __restrict__ muW, const float* __restrict__ lsW,
    const float* __restrict__ qmu,
    const float* __restrict__ bi0, const float* __restrict__ bh0,
    const float* __restrict__ bi1, const float* __restrict__ bh1,
    const float* __restrict__ mb,  const float* __restrict__ lb,
    const float* __restrict__ qb,
    const float* __restrict__ whh0, const float* __restrict__ whh1,
    const float* __restrict__ wih1,
    const float* __restrict__ nbows, const float* __restrict__ qmap_w,
    const float* __restrict__ wih0,
    const float* __restrict__ rho1w, const float* __restrict__ rho2w)
{
  float* zbase = ws + OFF_C1G1;
  float* muW4  = ws + OFF_MUW4;
  float* lsW4  = ws + OFF_LSW4;
  unsigned short* albf = (unsigned short*)(ws + OFF_ALBF);
  float* bsum0 = ws + OFF_LTH;
  float* bsum1 = ws + OFF_LTH + 1600;
  float* mlb   = ws + OFF_LTH + 3200;
  float* rs    = ws + OFF_RS;
  unsigned int* inbz = (unsigned int*)(ws + OFF_INP);
  float* inpf  = ws + OFF_ALPHAT;
  float* w0T   = ws + OFF_W0T;
  float* w1T   = ws + OFF_W1T;
  float* wi1T  = ws + OFF_WIH1T;
  unsigned short* nbbf = (unsigned short*)(ws + OFF_NBBF);
  unsigned short* qwbf = (unsigned short*)(ws + OFF_QWBF);
  unsigned short* w0bf = (unsigned short*)(ws + OFF_W0BF);
  unsigned short* r1bf = (unsigned short*)(ws + OFF_R1BF);
  unsigned short* r2bf = (unsigned short*)(ws + OFF_R2BF);

  for (long long i = blockIdx.x*blockDim.x + threadIdx.x; i < 10853348LL;
       i += (long long)gridDim.x*blockDim.x){
    if (i < 38416) zbase[i] = 0.f;
    else if (i < 58416){ int j = i - 38416; muW4[j] = muW[(j/400)*450 + (j%400)]; }
    else if (i < 78416){ int j = i - 58416; lsW4[j] = lsW[(j/400)*450 + (j%400)]; }
    else if (i < 270416){
      int j = i - 78416; int m = j/320, r = j%320; int t = m/50, k = m%50;
      albf[j] = (r < 300) ? f2bf(qmu[((size_t)k*12 + t)*300 + r]) : 0;
    }
    else if (i < 272016){ int j = i - 270416; bsum0[j] = bi0[j] + bh0[j]; }
    else if (i < 273616){ int j = i - 272016; bsum1[j] = bi1[j] + bh1[j]; }
    else if (i < 273716){ int j = i - 273616; mlb[j] = (j < 50) ? mb[j] : lb[j-50]; }
    else if (i < 274916){ int j = i - 273716; rs[j] = 0.f; }
    else if (i < 354788){ int j = i - 274916; inbz[j] = 0u; }
    else if (i < 994788){
      int j = i - 354788; int r = j/1600, col = j%1600;
      int u = col >> 2, g = col & 3;
      w0T[j] = whh0[((size_t)(g*400 + u))*400 + r];
    }
    else if (i < 1634788){
      int j = i - 994788; int r = j/1600, col = j%1600;
      int u = col >> 2, g = col & 3;
      w1T[j] = whh1[((size_t)(g*400 + u))*400 + r];
    }
    else if (i < 2274788){
      int j = i - 1634788; int r = j/1600, col = j%1600;
      int u = col >> 2, g = col & 3;
      wi1T[j] = wih1[((size_t)(g*400 + u))*400 + r];
    }
    else if (i < 4978148){
      int j = i - 2274788; int row = j/7040, v = j%7040;
      nbbf[j] = (v < 7000) ? f2bf(nbows[(size_t)row*7000 + v]) : 0;
    }
    else if (i < 7794148){
      int j = i - 4978148; int row = j/7040, v = j%7040;
      qwbf[j] = (v < 7000) ? f2bf(qmap_w[(size_t)row*7000 + v]) : 0;
    }
    else if (i < 8459748){
      int j = i - 7794148; int row = j/416, r = j%416;
      w0bf[j] = (r < 400) ? f2bf(wih0[(size_t)row*400 + r]) : 0;
    }
    else if (i < 10059748){
      int j = i - 8459748; int row = j/320, r = j%320;
      r1bf[j] = (r < 300) ? f2bf(rho1w[(size_t)row*300 + r]) : 0;
    }
    else if (i < 10699748){
      int j = i - 10059748; int row = j/320, r = j%320;
      r2bf[j] = (r < 300) ? f2bf(rho2w[(size_t)row*300 + r]) : 0;
    }
    else { int j = i - 10699748; inpf[j] = qb[j % 400]; }   // inp_f32 = bias
  }
}

// ---------------- MFMA bf16 GEMM ----------------
// Kp % 32 == 0, kchunk % 32 == 0. grid (ceil(N/64), ceil(M/64), splitK).
// Cacc!=null: atomicAdd f32 (split-K; bias pre-initialized). Else direct store:
// Cbf!=null -> bf16; else f32 to Cf; rowsum: atomicAdd per-row sum of exp.
__global__ __launch_bounds__(256) void gemm_bf16(
    const unsigned short* __restrict__ A, int lda,
    const unsigned short* __restrict__ B, int ldb,
    float* __restrict__ Cf, unsigned short* __restrict__ Cbf,
    float* __restrict__ Cacc, int ldc,
    int M, int N, int Kp, int kchunk,
    const float* __restrict__ bias, float* __restrict__ rowsum)
{
  __shared__ unsigned short As[64][40];
  __shared__ unsigned short Bs[64][40];
  __shared__ float sexp[64];
  const int tid = threadIdx.x;
  const int m0 = blockIdx.y * 64, n0 = blockIdx.x * 64;
  const int kbeg = blockIdx.z * kchunk;
  const int kend = min(Kp, kbeg + kchunk);
  const int wave = tid >> 6, lane = tid & 63;
  const int wm = (wave >> 1) * 32, wn = (wave & 1) * 32;
  const int ra = tid >> 2, ck = (tid & 3) << 3;
  const int fr = lane & 15, fo = (lane >> 4) << 3;
  if (rowsum && tid < 64) sexp[tid] = 0.f;

  f32x4 acc00 = {0.f,0.f,0.f,0.f}, acc01 = {0.f,0.f,0.f,0.f};
  f32x4 acc10 = {0.f,0.f,0.f,0.f}, acc11 = {0.f,0.f,0.f,0.f};
  int4 pa, pb;
  {
    int rA = m0 + ra, rB = n0 + ra;
    pa = (rA < M) ? *(const int4*)&A[(size_t)rA*lda + kbeg + ck] : make_int4(0,0,0,0);
    pb = (rB < N) ? *(const int4*)&B[(size_t)rB*ldb + kbeg + ck] : make_int4(0,0,0,0);
  }
  for (int k0 = kbeg; k0 < kend; k0 += 32){
    *(int4*)&As[ra][ck] = pa;
    *(int4*)&Bs[ra][ck] = pb;
    __syncthreads();
    if (k0 + 32 < kend){
      int rA = m0 + ra, rB = n0 + ra;
      pa = (rA < M) ? *(const int4*)&A[(size_t)rA*lda + k0 + 32 + ck] : make_int4(0,0,0,0);
      pb = (rB < N) ? *(const int4*)&B[(size_t)rB*ldb + k0 + 32 + ck] : make_int4(0,0,0,0);
    }
    short8v a0 = *(const short8v*)&As[wm      + fr][fo];
    short8v a1 = *(const short8v*)&As[wm + 16 + fr][fo];
    short8v b0 = *(const short8v*)&Bs[wn      + fr][fo];
    short8v b1 = *(const short8v*)&Bs[wn + 16 + fr][fo];
    acc00 = __builtin_amdgcn_mfma_f32_16x16x32_bf16(a0, b0, acc00, 0, 0, 0);
    acc01 = __builtin_amdgcn_mfma_f32_16x16x32_bf16(a0, b1, acc01, 0, 0, 0);
    acc10 = __builtin_amdgcn_mfma_f32_16x16x32_bf16(a1, b0, acc10, 0, 0, 0);
    acc11 = __builtin_amdgcn_mfma_f32_16x16x32_bf16(a1, b1, acc11, 0, 0, 0);
    __syncthreads();
  }
  // epilogue: D col = lane&15, row = (lane>>4)*4 + reg  [guide §3, m89]
  const int rbase = (lane >> 4) << 2;
  auto epi = [&](f32x4 ac0, f32x4 ac1, int mi){
    #pragma unroll
    for (int reg = 0; reg < 4; ++reg){
      const int lr = wm + mi*16 + rbase + reg;
      const int gr = m0 + lr;
      float ex = 0.f;
      {
        int gc = n0 + wn + fr;
        if (gr < M && gc < N){
          if (Cacc) atomicAdd(&Cacc[(size_t)gr*ldc + gc], ac0[reg]);
          else {
            float val = ac0[reg] + (bias ? bias[gc] : 0.f);
            if (Cbf) Cbf[(size_t)gr*ldc + gc] = f2bf(val);
            else     Cf [(size_t)gr*ldc + gc] = val;
            if (rowsum) ex += __expf(val);
          }
        }
      }
      {
        int gc = n0 + wn + 16 + fr;
        if (gr < M && gc < N){
          if (Cacc) atomicAdd(&Cacc[(size_t)gr*ldc + gc], ac1[reg]);
          else {
            float val = ac1[reg] + (bias ? bias[gc] : 0.f);
            if (Cbf) Cbf[(size_t)gr*ldc + gc] = f2bf(val);
            else     Cf [(size_t)gr*ldc + gc] = val;
            if (rowsum) ex += __expf(val);
          }
        }
      }
      if (rowsum){
        ex += __shfl_xor(ex, 1); ex += __shfl_xor(ex, 2);
        ex += __shfl_xor(ex, 4); ex += __shfl_xor(ex, 8);
        if (fr == 0 && gr < M) atomicAdd(&sexp[lr], ex);
      }
    }
  };
  epi(acc00, acc01, 0);
  epi(acc10, acc11, 1);
  if (rowsum){
    __syncthreads();
    if (tid < 64 && m0 + tid < M) atomicAdd(&rowsum[m0 + tid], sexp[tid]);
  }
}

// ---------------- convert inp_f32 -> bf16 ----------------
__global__ void cvt_inp(const float* __restrict__ inpf, unsigned short* __restrict__ inpbf){
  int i = blockIdx.x*blockDim.x + threadIdx.x;
  if (i < 153600){
    int r = i / 400, c = i % 400;
    inpbf[r*416 + c] = f2bf(inpf[i]);
  }
}

// ---------------- f32 GEMM (kept for tiny muH2) ----------------
__device__ __forceinline__ float4 g4(const float* __restrict__ base, int row, int nrows,
                                     int ld, int k, int kend){
  float4 v; v.x = v.y = v.z = v.w = 0.f;
  if (row < nrows){
    const float* q = base + (size_t)row*ld + k;
    if (k + 3 < kend) v = *(const float4*)q;
  }
  return v;
}
__global__ __launch_bounds__(256) void gemm_f32(
    const float* __restrict__ A, int lda,
    const float* __restrict__ B, int ldb,
    float* __restrict__ C, int ldc,
    int M, int N, int K,
    const float* __restrict__ bias)
{
  __shared__ __align__(16) float As[16][68];
  __shared__ __align__(16) float Bs[16][68];
  const int tid = threadIdx.x;
  const int m0 = blockIdx.y * 64, n0 = blockIdx.x * 64;
  const int lm  = tid >> 2;
  const int lkq = (tid & 3) << 2;
  const int ty = tid >> 4, tx = tid & 15;
  float acc[4][4];
  #pragma unroll
  for (int i=0;i<4;++i)
    #pragma unroll
    for (int j=0;j<4;++j) acc[i][j] = 0.f;
  for (int k0 = 0; k0 < K; k0 += 16){
    float4 av = g4(A, m0+lm, M, lda, k0+lkq, K);
    float4 bv = g4(B, n0+lm, N, ldb, k0+lkq, K);
    As[lkq+0][lm]=av.x; As[lkq+1][lm]=av.y; As[lkq+2][lm]=av.z; As[lkq+3][lm]=av.w;
    Bs[lkq+0][lm]=bv.x; Bs[lkq+1][lm]=bv.y; Bs[lkq+2][lm]=bv.z; Bs[lkq+3][lm]=bv.w;
    __syncthreads();
    #pragma unroll
    for (int kk = 0; kk < 16; ++kk){
      const float4 a = *(const float4*)&As[kk][ty<<2];
      const float4 b = *(const float4*)&Bs[kk][tx<<2];
      float ar[4] = {a.x,a.y,a.z,a.w};
      float br[4] = {b.x,b.y,b.z,b.w};
      #pragma unroll
      for (int i=0;i<4;++i)
        #pragma unroll
        for (int j=0;j<4;++j) acc[i][j] = fmaf(ar[i], br[j], acc[i][j]);
    }
    __syncthreads();
  }
  const int om = m0 + (ty<<2), on = n0 + (tx<<2);
  #pragma unroll
  for (int i=0;i<4;++i)
    #pragma unroll
    for (int j=0;j<4;++j)
      if (om+i < M && on+j < N)
        C[(size_t)(om+i)*ldc + (on+j)] = acc[i][j] + (bias ? bias[on+j] : 0.f);
}

// ---------------- pipelined LSTM: layer0 step t || layer1 step t-1 ----------------
__global__ __launch_bounds__(256) void lstm_pipe(
    const float* __restrict__ X0,    const float* __restrict__ w0T,
    const float* __restrict__ wi1T,  const float* __restrict__ w1T,
    const float* __restrict__ bsum1,
    float* __restrict__ hs0, float* __restrict__ hs1,
    float* __restrict__ cst0, float* __restrict__ cst1, int step)
{
  __shared__ __align__(16) float4 hq4[100*32];
  __shared__ __align__(16) float4 red4[4][32][2];
  const int tid = threadIdx.x;
  const int rh = tid >> 6;
  const int b  = (tid & 63) >> 1;
  const int ul = tid & 1;
  const int rq0 = rh * 25;

  if (blockIdx.x < 200){
    const int t = step;
    if (t >= 12) return;
    const int U0 = blockIdx.x * 2;
    const int u = U0 + ul;
    if (t > 0){
      for (int i = tid; i < 3200; i += 256){
        int bb = i & 31, rq = i >> 5;
        hq4[rq*32 + bb] = *(const float4*)&hs0[((size_t)(bb*12 + (t-1)))*400 + rq*4];
      }
      __syncthreads();
      const float* wcol = w0T + (size_t)u*4;
      float4 acc = {0.f,0.f,0.f,0.f};
      #pragma unroll 5
      for (int rq = rq0; rq < rq0 + 25; ++rq){
        float4 h4 = hq4[rq*32 + b];
        float hr[4] = {h4.x, h4.y, h4.z, h4.w};
        #pragma unroll
        for (int dr = 0; dr < 4; ++dr){
          float4 w4 = *(const float4*)&wcol[(size_t)(rq*4 + dr)*1600];
          acc.x = fmaf(hr[dr], w4.x, acc.x);
          acc.y = fmaf(hr[dr], w4.y, acc.y);
          acc.z = fmaf(hr[dr], w4.z, acc.z);
          acc.w = fmaf(hr[dr], w4.w, acc.w);
        }
      }
      red4[rh][b][ul] = acc;
    }
    __syncthreads();
    if (tid < 64){
      const int bb = tid >> 1, uu = U0 + (tid & 1);
      float4 a = {0.f,0.f,0.f,0.f};
      if (t > 0){
        #pragma unroll
        for (int w = 0; w < 4; ++w){
          float4 r = red4[w][bb][tid & 1];
          a.x += r.x; a.y += r.y; a.z += r.z; a.w += r.w;
        }
      }
      const size_t xrow = ((size_t)bb*12 + t)*1600;
      float gi = a.x + X0[xrow          + uu];
      float gf = a.y + X0[xrow +  400   + uu];
      float gg = a.z + X0[xrow +  800   + uu];
      float go = a.w + X0[xrow + 1200   + uu];
      float ii = 1.f/(1.f + expf(-gi));
      float ff = 1.f/(1.f + expf(-gf));
      float tg = tanhf(gg);
      float oo = 1.f/(1.f + expf(-go));
      float c = (t == 0) ? 0.f : cst0[bb*400 + uu];
      c = ff*c + ii*tg;
      cst0[bb*400 + uu] = c;
      hs0[((size_t)bb*12 + t)*400 + uu] = oo * tanhf(c);
    }
  } else {
    const int t = step - 1;
    if (t < 0) return;
    const int U0 = (blockIdx.x - 200) * 2;
    const int u = U0 + ul;
    float4 acc = {0.f,0.f,0.f,0.f};
    // phase A: h0(t) @ wih1T
    for (int i = tid; i < 3200; i += 256){
      int bb = i & 31, rq = i >> 5;
      hq4[rq*32 + bb] = *(const float4*)&hs0[((size_t)(bb*12 + t))*400 + rq*4];
    }
    __syncthreads();
    {
      const float* wcol = wi1T + (size_t)u*4;
      #pragma unroll 5
      for (int rq = rq0; rq < rq0 + 25; ++rq){
        float4 h4 = hq4[rq*32 + b];
        float hr[4] = {h4.x, h4.y, h4.z, h4.w};
        #pragma unroll
        for (int dr = 0; dr < 4; ++dr){
          float4 w4 = *(const float4*)&wcol[(size_t)(rq*4 + dr)*1600];
          acc.x = fmaf(hr[dr], w4.x, acc.x);
          acc.y = fmaf(hr[dr], w4.y, acc.y);
          acc.z = fmaf(hr[dr], w4.z, acc.z);
          acc.w = fmaf(hr[dr], w4.w, acc.w);
        }
      }
    }
    __syncthreads();
    // phase B: h1(t-1) @ w1T
    if (t > 0){
      for (int i = tid; i < 3200; i += 256){
        int bb = i & 31, rq = i >> 5;
        hq4[rq*32 + bb] = *(const float4*)&hs1[((size_t)(bb*12 + (t-1)))*400 + rq*4];
      }
    }
    __syncthreads();
    if (t > 0){
      const float* wcol = w1T + (size_t)u*4;
      #pragma unroll 5
      for (int rq = rq0; rq < rq0 + 25; ++rq){
        float4 h4 = hq4[rq*32 + b];
        float hr[4] = {h4.x, h4.y, h4.z, h4.w};
        #pragma unroll
        for (int dr = 0; dr < 4; ++dr){
          float4 w4 = *(const float4*)&wcol[(size_t)(rq*4 + dr)*1600];
          acc.x = fmaf(hr[dr], w4.x, acc.x);
          acc.y = fmaf(hr[dr], w4.y, acc.y);
          acc.z = fmaf(hr[dr], w4.z, acc.z);
          acc.w = fmaf(hr[dr], w4.w, acc.w);
        }
      }
    }
    red4[rh][b][ul] = acc;
    __syncthreads();
    if (tid < 64){
      const int bb = tid >> 1, uu = U0 + (tid & 1);
      float4 a = {0.f,0.f,0.f,0.f};
      #pragma unroll
      for (int w = 0; w < 4; ++w){
        float4 r = red4[w][bb][tid & 1];
        a.x += r.x; a.y += r.y; a.z += r.z; a.w += r.w;
      }
      float gi = a.x + bsum1[        uu];
      float gf = a.y + bsum1[ 400 + uu];
      float gg = a.z + bsum1[ 800 + uu];
      float go = a.w + bsum1[1200 + uu];
      float ii = 1.f/(1.f + expf(-gi));
      float ff = 1.f/(1.f + expf(-gf));
      float tg = tanhf(gg);
      float oo = 1.f/(1.f + expf(-go));
      float c = (t == 0) ? 0.f : cst1[bb*400 + uu];
      c = ff*c + ii*tg;
      cst1[bb*400 + uu] = c;
      hs1[((size_t)bb*12 + t)*400 + uu] = oo * tanhf(c);
    }
  }
}

// ---------------- theta head (4 blocks, 8 b's each) ----------------
__global__ __launch_bounds__(512) void theta_par(
    const float* __restrict__ muH2,
    const float* __restrict__ muW, const float* __restrict__ lsW,
    float* __restrict__ theta, float* __restrict__ accs)
{
  __shared__ float zsall[12][8][50];
  __shared__ float wm[50][51], wl[50][51];
  __shared__ float ktot;
  const int tid = threadIdx.x;
  const int b0 = blockIdx.x * 8;
  for (int i = tid; i < 2500; i += 512){
    int k = i / 50, j = i % 50;
    wm[k][j] = muW[k*450 + 400 + j];
    wl[k][j] = lsW[k*450 + 400 + j];
  }
  if (tid == 0) ktot = 0.f;
  __syncthreads();
  const float dd = expf(LOG_DELTA) + 1e-6f;
  for (int t = 0; t < 12; ++t){
    float kpart = 0.f;
    if (tid < 400){
      int bl = tid / 50, k = tid % 50, b = b0 + bl;
      float m = muH2[((size_t)b*12 + t)*100 + k];
      float l = muH2[((size_t)b*12 + t)*100 + 50 + k];
      float zp = 0.f;
      if (t > 0){
        zp = zsall[t-1][bl][k];
        float sm = 0.f, sl = 0.f;
        #pragma unroll 5
        for (int j = 0; j < 50; ++j){
          float z = zsall[t-1][bl][j];
          sm = fmaf(z, wm[k][j], sm);
          sl = fmaf(z, wl[k][j], sl);
        }
        m += sm; l += sl;
      }
      zsall[t][bl][k] = m;
      float denom = (t > 0) ? dd : (1.f + 1e-6f);
      float pls = (t > 0) ? LOG_DELTA : 0.f;
      float d = m - zp;
      kpart += (expf(l) + d*d)/denom - 1.f + pls - l;
    }
    kpart = wsum64(kpart);
    if ((tid & 63) == 0) atomicAdd(&ktot, 0.5f * kpart / 32.f);
    __syncthreads();
  }
  for (int rr = tid; rr < 96; rr += 512){
    int t = rr >> 3, bl = rr & 7, b = b0 + bl;
    float m = -3.0e38f;
    for (int k = 0; k < 50; ++k) m = fmaxf(m, zsall[t][bl][k]);
    float S = 0.f;
    for (int k = 0; k < 50; ++k) S += expf(zsall[t][bl][k] - m);
    float inv = 1.f/S;
    for (int k = 0; k < 50; ++k)
      theta[((size_t)t*32 + b)*50 + k] = expf(zsall[t][bl][k] - m) * inv;
  }
  if (tid == 0) atomicAdd(&accs[6], ktot);
}

// ---------------- kld_alpha ----------------
__global__ void kld_alpha_k(const float* __restrict__ qmu, const float* __restrict__ qls,
                            float* __restrict__ accs){
  const int t = blockIdx.x / 50, k = blockIdx.x % 50;
  const size_t base  = ((size_t)k*12 + t)*300;
  const size_t pbase = ((size_t)k*12 + (t-1))*300;
  const float dd  = (t > 0) ? (expf(LOG_DELTA) + 1e-6f) : (1.f + 1e-6f);
  const float pls = (t > 0) ? LOG_DELTA : 0.f;
  float s = 0.f;
  for (int r = threadIdx.x; r < 300; r += 64){
    float qm = qmu[base + r], ql = qls[base + r];
    float pm = (t > 0) ? qmu[pbase + r] : 0.f;
    float d = qm - pm;
    s += (expf(ql) + d*d)/dd - 1.f + pls - ql;
  }
  s = wsum64(s);
  if (threadIdx.x == 0) atomicAdd(&accs[7], 0.5f * s / 50.f);
}

// ---------------- pass1: rejection sampling, packed counters ----------------
__global__ __launch_bounds__(256) void pass1(
    const float* __restrict__ blog, const float* __restrict__ rs,
    const float* __restrict__ theta,
    float* __restrict__ bzg,
    float* __restrict__ c1g1, float* __restrict__ c1g2,
    float* __restrict__ accs)
{
  const int t = blockIdx.y;
  const int v0 = blockIdx.x * 64;
  __shared__ float th[32][50];
  __shared__ float be[50][64];
  __shared__ float c0s[64][50];
  __shared__ unsigned int c1p[2][32][25];
  __shared__ float rlog[2][50];
  __shared__ float kred[4];
  const int tid = threadIdx.x;

  if (tid < 100){
    int p = tid / 50, k = tid % 50;
    rlog[p][k] = __logf(rs[p*600 + t*50 + k]);
  }
  float lg[13];
  #pragma unroll
  for (int j = 0; j < 13; ++j){
    int i = tid + j*256;
    lg[j] = -40.f;
    if (i < 3200){
      int k = i >> 6, vl = i & 63, v = v0 + vl;
      if (v < 7000) lg[j] = blog[((size_t)t*50 + k)*7000 + v];
    }
  }
  #pragma unroll
  for (int j = 0; j < 7; ++j){
    int i = tid + j*256;
    if (i < 1600) th[i/50][i%50] = theta[(size_t)t*1600 + i];
  }
  #pragma unroll
  for (int j = 0; j < 13; ++j){
    int i = tid + j*256;
    if (i < 3200) ((float*)c0s)[i] = 0.f;
  }
  #pragma unroll
  for (int j = 0; j < 7; ++j){
    int i = tid + j*256;
    if (i < 1600) ((unsigned int*)c1p)[i] = 0u;
  }
  if (tid < 4) kred[tid] = 0.f;
  __syncthreads();
  #pragma unroll
  for (int j = 0; j < 13; ++j){
    int i = tid + j*256;
    if (i < 3200){
      int k = i >> 6, vl = i & 63, v = v0 + vl;
      int p = (v >= 5000);
      be[k][vl] = __expf(lg[j] - rlog[p][k]);
    }
  }
  __syncthreads();

  const int b = tid >> 3, sub = tid & 7;
  float S[8];
  #pragma unroll
  for (int i = 0; i < 8; ++i) S[i] = 0.f;
  for (int k = 0; k < 50; ++k){
    float tk = th[b][k];
    #pragma unroll
    for (int i = 0; i < 8; ++i)
      S[i] += __expf(tk * be[k][sub + 8*i]);
  }
  float inv[8];
  #pragma unroll
  for (int i = 0; i < 8; ++i) inv[i] = 1.f / S[i];

  int ks[8]; float pis[8];
  unsigned fmask = 0;
  const int vbase = (t*32 + b)*7000 + v0 + sub;
  #pragma unroll
  for (int i = 0; i < 8; ++i){
    ks[i] = 0; pis[i] = 1.f;
    if (v0 + sub + 8*i >= 7000) fmask |= 1u << i;
  }
  int round = 0;
  while (true){
    const unsigned roff = (unsigned)round * 0x9E3779B9u;
    #pragma unroll
    for (int i = 0; i < 8; ++i){
      if (!((fmask >> i) & 1u)){
        const unsigned bse = (unsigned)(vbase + 8*i) * 2u;
        float u1 = u01(bse + roff);
        float u2 = u01(bse + 1u + roff);
        int kp = min((int)(u1 * 50.f), 49);
        float pi = __expf(th[b][kp] * be[kp][sub + 8*i]) * inv[i];
        if (u2 <= __expf(pi - PIMAX) || round >= 7){
          ks[i] = kp; pis[i] = pi; fmask |= 1u << i;
        }
      }
    }
    ++round;
    if (__all(fmask == 255u)) break;
  }

  float kA1 = 0.f, kB1 = 0.f, kA2 = 0.f, kB2 = 0.f;
  #pragma unroll
  for (int i = 0; i < 8; ++i){
    const int vl = sub + 8*i, v = v0 + vl;
    if (v < 7000){
      float lpis = __logf(pis[i]);
      float lt   = __logf(th[b][ks[i]]);
      if (v >= 5000){ kA2 += lt; kB2 += pis[i]*lpis; }
      else          { kA1 += lt; kB1 += pis[i]*lpis; }
      atomicAdd(&c0s[vl][ks[i]], 1.f);
      atomicAdd(&c1p[(v >= 5000) ? 1 : 0][b][ks[i] >> 1],
                (ks[i] & 1) ? 65536u : 1u);
    }
  }
  kA1 = wsum64(kA1); kB1 = wsum64(kB1); kA2 = wsum64(kA2); kB2 = wsum64(kB2);
  if ((tid & 63) == 0){
    atomicAdd(&kred[0], kA1); atomicAdd(&kred[1], kB1);
    atomicAdd(&kred[2], kA2); atomicAdd(&kred[3], kB2);
  }
  __syncthreads();
  #pragma unroll
  for (int j = 0; j < 13; ++j){
    int i = tid + j*256;
    if (i < 3200){
      int k = i >> 6, vl = i & 63, v = v0 + vl;
      if (v < 7000)
        bzg[(size_t)t*350000 + (size_t)k*7000 + v] = be[k][vl] * c0s[vl][k] * (1.f/32.f);
    }
  }
  for (int i = tid; i < 1600; i += 256){
    int b2 = i / 50, k2 = i % 50;
    unsigned w1 = c1p[0][b2][k2 >> 1];
    unsigned w2 = c1p[1][b2][k2 >> 1];
    unsigned cnt1 = (k2 & 1) ? (w1 >> 16) : (w1 & 0xFFFFu);
    unsigned cnt2 = (k2 & 1) ? (w2 >> 16) : (w2 & 0xFFFFu);
    if (cnt1) atomicAdd(&c1g1[(size_t)t*1600 + i], (float)cnt1);
    if (cnt2) atomicAdd(&c1g2[(size_t)t*1600 + i], (float)cnt2);
  }
  if (tid < 4) atomicAdd(&accs[tid], kred[tid]);
}

// ---------------- pass2: log-likelihood ----------------
__global__ __launch_bounds__(256) void pass2(
    const float* __restrict__ bzg, const float* __restrict__ theta,
    const float* __restrict__ c1g1, const float* __restrict__ c1g2,
    const float* __restrict__ bows, float* __restrict__ accs)
{
  const int t = blockIdx.y, v0 = blockIdx.x * 64;
  __shared__ float tz[2][32][50];
  __shared__ float bzs[50][64];
  __shared__ float sr[2];
  const int tid = threadIdx.x;
  if (tid < 2) sr[tid] = 0.f;
  for (int i = tid; i < 1600; i += 256){
    int b = i / 50, k = i % 50;
    float th_ = theta[(size_t)t*1600 + i];
    tz[0][b][k] = th_ * c1g1[(size_t)t*1600 + i] * (1.f/5000.f);
    tz[1][b][k] = th_ * c1g2[(size_t)t*1600 + i] * (1.f/2000.f);
  }
  for (int i = tid; i < 3200; i += 256){
    int k = i >> 6, vl = i & 63, v = v0 + vl;
    bzs[k][vl] = (v < 7000) ? bzg[(size_t)t*350000 + (size_t)k*7000 + v] : 0.f;
  }
  __syncthreads();

  const int b = tid >> 3, sub = tid & 7;
  int part[8];
  #pragma unroll
  for (int i = 0; i < 8; ++i) part[i] = (v0 + sub + 8*i >= 5000);
  float dot[8];
  #pragma unroll
  for (int i = 0; i < 8; ++i) dot[i] = 0.f;
  for (int k = 0; k < 50; ++k){
    float t0 = tz[0][b][k], t1 = tz[1][b][k];
    #pragma unroll
    for (int i = 0; i < 8; ++i)
      dot[i] = fmaf(part[i] ? t1 : t0, bzs[k][sub + 8*i], dot[i]);
  }
  float s1 = 0.f, s2 = 0.f;
  #pragma unroll
  for (int i = 0; i < 8; ++i){
    const int v = v0 + sub + 8*i;
    if (v < 7000){
      const float w = bows[((size_t)b*12 + t)*7000 + v];
      const float l = __logf(dot[i]) * w;
      if (part[i]) s2 += l; else s1 += l;
    }
  }
  s1 = wsum64(s1); s2 = wsum64(s2);
  if ((tid & 63) == 0){ atomicAdd(&sr[0], s1); atomicAdd(&sr[1], s2); }
  __syncthreads();
  if (tid < 2) atomicAdd(&accs[4 + tid], sr[tid]);
}

// ---------------- finalize ----------------
__global__ void finalize_k(const float* __restrict__ accs, float* __restrict__ out){
  if (threadIdx.x == 0 && blockIdx.x == 0){
    out[0] = -(accs[4] + accs[5]) * (1.f/32.f);
    out[1] = accs[6];
    out[2] = -accs[0]/(32.f*5000.f) - accs[1]/32.f;
    out[3] = -accs[2]/(32.f*2000.f) - accs[3]/32.f;
    out[4] = accs[7];
  }
}

// ---------------- host launcher ----------------
extern "C" void kernel_launch(void* const* d_in, const int* in_sizes, int n_in,
                              void* d_out, int out_size, void* d_ws, size_t ws_size,
                              hipStream_t stream)
{
  const float* bows   = (const float*)d_in[0];
  const float* nbows  = (const float*)d_in[1];
  const float* qmap_w = (const float*)d_in[2];
  const float* qmap_b = (const float*)d_in[3];
  const float* wih0   = (const float*)d_in[4];
  const float* whh0   = (const float*)d_in[5];
  const float* bih0   = (const float*)d_in[6];
  const float* bhh0   = (const float*)d_in[7];
  const float* wih1   = (const float*)d_in[8];
  const float* whh1   = (const float*)d_in[9];
  const float* bih1   = (const float*)d_in[10];
  const float* bhh1   = (const float*)d_in[11];
  const float* muW    = (const float*)d_in[12];
  const float* muB    = (const float*)d_in[13];
  const float* lsW    = (const float*)d_in[14];
  const float* lsB    = (const float*)d_in[15];
  const float* qmu    = (const float*)d_in[16];
  const float* qlsa   = (const float*)d_in[17];
  const float* rho1w  = (const float*)d_in[18];
  const float* rho1b  = (const float*)d_in[19];
  const float* rho2w  = (const float*)d_in[20];
  const float* rho2b  = (const float*)d_in[21];

  float* ws  = (float*)d_ws;
  float* out = (float*)d_out;

  float* c1g1  = ws + OFF_C1G1;
  float* c1g2  = ws + OFF_C1G2;
  float* accs  = ws + OFF_ACCS;
  float* bzg   = ws + OFF_C0G;
  float* beta  = ws + OFF_BETA;
  float* inpf  = ws + OFF_ALPHAT;
  float* X0    = ws + OFF_X0;
  float* hs0   = ws + OFF_OUT0;
  float* hs1   = ws + OFF_OUT1;
  float* cst0  = ws + OFF_CST;
  float* cst1  = ws + OFF_CST1;
  float* muH2  = ws + OFF_MUH;
  float* theta = ws + OFF_THETA;
  float* muW4  = ws + OFF_MUW4;
  float* bsum0 = ws + OFF_LTH;
  float* bsum1 = ws + OFF_LTH + 1600;
  float* mlb   = ws + OFF_LTH + 3200;
  float* rs    = ws + OFF_RS;
  unsigned short* nbbf  = (unsigned short*)(ws + OFF_NBBF);
  unsigned short* qwbf  = (unsigned short*)(ws + OFF_QWBF);
  unsigned short* inpbf = (unsigned short*)(ws + OFF_INP);
  unsigned short* w0bf  = (unsigned short*)(ws + OFF_W0BF);
  unsigned short* albf  = (unsigned short*)(ws + OFF_ALBF);
  unsigned short* r1bf  = (unsigned short*)(ws + OFF_R1BF);
  unsigned short* r2bf  = (unsigned short*)(ws + OFF_R2BF);
  float* w0T  = ws + OFF_W0T;
  float* w1T  = ws + OFF_W1T;
  float* wi1T = ws + OFF_WIH1T;

  prep_misc<<<4096, 256, 0, stream>>>(ws, muW, lsW, qmu, bih0, bhh0, bih1, bhh1,
                                      muB, lsB, qmap_b, whh0, whh1, wih1,
                                      nbows, qmap_w, wih0, rho1w, rho2w);
  kld_alpha_k<<<600, 64, 0, stream>>>(qmu, qlsa, accs);

  // inp_f32 += nbows_bf @ qmap_w_bf^T  (split-K x10; bias pre-init'd in prep)
  gemm_bf16<<<dim3(7,6,10), 256, 0, stream>>>(nbbf, 7040, qwbf, 7040,
                                              nullptr, nullptr, inpf, 400,
                                              384, 400, 7040, 704, nullptr, nullptr);
  cvt_inp<<<600, 256, 0, stream>>>(inpf, inpbf);

  // X0 = inp_bf @ wih0^T + (bih0+bhh0)     M=384 N=1600 Kp=416
  gemm_bf16<<<dim3(25,6,1), 256, 0, stream>>>(inpbf, 416, w0bf, 416,
                                              X0, nullptr, nullptr, 1600,
                                              384, 1600, 416, 416, bsum0, nullptr);
  // pipelined double-layer LSTM: 13 launches
  for (int i = 0; i < 13; ++i)
    lstm_pipe<<<400, 256, 0, stream>>>(X0, w0T, wi1T, w1T, bsum1,
                                       hs0, hs1, cst0, cst1, i);

  // muH2 = hs1 @ [muW4;lsW4]^T + [muB;lsB]
  gemm_f32<<<dim3(2,6), 256, 0, stream>>>(hs1, 400, muW4, 400, muH2, 100,
                                          384, 100, 400, mlb);
  theta_par<<<4, 512, 0, stream>>>(muH2, muW, lsW, theta, accs);

  // beta logits via MFMA + fused row sum(exp)
  gemm_bf16<<<dim3(79,10,1), 256, 0, stream>>>(albf, 320, r1bf, 320,
                                               beta, nullptr, nullptr, 7000,
                                               600, 5000, 320, 320, rho1b, rs);
  gemm_bf16<<<dim3(32,10,1), 256, 0, stream>>>(albf, 320, r2bf, 320,
                                               beta + 5000, nullptr, nullptr, 7000,
                                               600, 2000, 320, 320, rho2b, rs + 600);

  pass1<<<dim3(110,12), 256, 0, stream>>>(beta, rs, theta, bzg, c1g1, c1g2, accs);
  pass2<<<dim3(110,12), 256, 0, stream>>>(bzg, theta, c1g1, c1g2, bows, accs);

  finalize_k<<<1, 64, 0, stream>>>(accs, out);
}

// Round 10
// 459.553 us; speedup vs baseline: 1.8443x; 1.0155x over previous
//
#include <hip/hip_runtime.h>

// ---------------- constants ----------------
#define LOG_DELTA (-5.2983174f)   // ln(0.005)
#define LOG50     (3.9120230054f) // ln(50)

typedef __attribute__((ext_vector_type(8))) short short8v;
typedef __attribute__((ext_vector_type(4))) float f32x4;

// ws layout (float offsets)
constexpr size_t OFF_C1G1  = 0;                       // [12][32][50]
constexpr size_t OFF_C1G2  = 19200;                   // [12][32][50]
constexpr size_t OFF_ACCS  = 38400;                   // [16]
constexpr size_t OFF_C0G   = 38416;                   // bzg [12][50][7000]
constexpr size_t OFF_BETA  = OFF_C0G  + 4200000;      // [600][7000] logits
constexpr size_t OFF_ALPHAT= OFF_BETA + 4200000;      // inp_f32 [384][400]
constexpr size_t OFF_INP   = OFF_ALPHAT + 180000;     // inp_bf ushort[384][416]
constexpr size_t OFF_X0    = OFF_INP  + 153600;       // [384][1600]
constexpr size_t OFF_OUT0  = OFF_X0   + 614400;       // hs0 [384][400]
constexpr size_t OFF_X1    = OFF_OUT0 + 153600;       // cst1|albf|r2bf region
constexpr size_t OFF_OUT1  = OFF_X1   + 614400;       // hs1 [384][400]
constexpr size_t OFF_CST   = OFF_OUT1 + 153600;       // cst0 [32][400]
constexpr size_t OFF_MUH   = OFF_CST  + 12800;        // [384][100]
constexpr size_t OFF_THETA = OFF_MUH  + 38400;        // [12][32][50]
constexpr size_t OFF_LTH   = OFF_THETA+ 19200;        // bsum0|bsum1|mlb|rs
constexpr size_t OFF_MUW4  = OFF_LTH  + 19200;        // [50][400]
constexpr size_t OFF_LSW4  = OFF_MUW4 + 20000;        // [50][400]
constexpr size_t OFF_RS    = OFF_LTH  + 3300;         // rowsum [2][600]
// overlay in bzg region (dead before pass1):
constexpr size_t OFF_W0T   = OFF_C0G;                 // f32 [400][1600]
constexpr size_t OFF_W1T   = OFF_C0G + 640000;        // f32 [400][1600]
constexpr size_t OFF_WIH1T = OFF_C0G + 1280000;       // f32 [400][1600]
constexpr size_t OFF_NBBF  = OFF_C0G + 1920000;       // ushort[384][7040]
constexpr size_t OFF_R1BF  = OFF_C0G + 3271680;       // ushort[5000][320]
// overlay in beta region (dead before beta GEMMs):
constexpr size_t OFF_QWBF  = OFF_BETA;                // ushort[400][7040]
constexpr size_t OFF_W0BF  = OFF_BETA + 1408000;      // ushort[1600][416]
// overlay in X1 region (X1 eliminated):
constexpr size_t OFF_CST1  = OFF_X1;                  // f32 [32][400]
constexpr size_t OFF_ALBF  = OFF_X1 + 12800;          // ushort[600][320]
constexpr size_t OFF_R2BF  = OFF_X1 + 108800;         // ushort[2000][320]

// ---------------- helpers ----------------
__device__ __forceinline__ float wsum64(float x){
  #pragma unroll
  for (int o = 32; o; o >>= 1) x += __shfl_down(x, o);
  return x;
}
__device__ __forceinline__ float u01(unsigned int x){
  x ^= x >> 16; x *= 0x7feb352dU;
  x ^= x >> 15; x *= 0x846ca68bU;
  x ^= x >> 16;
  return ((float)x + 0.5f) * (1.0f/4294967296.0f);
}
__device__ __forceinline__ unsigned short f2bf(float x){
  unsigned int u = __float_as_uint(x);
  u += 0x7FFFu + ((u >> 16) & 1u);
  return (unsigned short)(u >> 16);
}

// ---------------- fused prep ----------------
__global__ void prep_misc(float* __restrict__ ws,
    const float* __restrict__ muW, const float* __restrict__ lsW,
    const float* __restrict__ qmu,
    const float* __restrict__ bi0, const float* __restrict__ bh0,
    const float* __restrict__ bi1, const float* __restrict__ bh1,
    const float* __restrict__ mb,  const float* __restrict__ lb,
    const float* __restrict__ qb,
    const float* __restrict__ whh0, const float* __restrict__ whh1,
    const float* __restrict__ wih1,
    const float* __restrict__ nbows, const float* __restrict__ qmap_w,
    const float* __restrict__ wih0,
    const float* __restrict__ rho1w, const float* __restrict__ rho2w)
{
  float* zbase = ws + OFF_C1G1;
  float* muW4  = ws + OFF_MUW4;
  float* lsW4  = ws + OFF_LSW4;
  unsigned short* albf = (unsigned short*)(ws + OFF_ALBF);
  float* bsum0 = ws + OFF_LTH;
  float* bsum1 = ws + OFF_LTH + 1600;
  float* mlb   = ws + OFF_LTH + 3200;
  float* rs    = ws + OFF_RS;
  unsigned int* inbz = (unsigned int*)(ws + OFF_INP);
  float* inpf  = ws + OFF_ALPHAT;
  float* w0T   = ws + OFF_W0T;
  float* w1T   = ws + OFF_W1T;
  float* wi1T  = ws + OFF_WIH1T;
  unsigned short* nbbf = (unsigned short*)(ws + OFF_NBBF);
  unsigned short* qwbf = (unsigned short*)(ws + OFF_QWBF);
  unsigned short* w0bf = (unsigned short*)(ws + OFF_W0BF);
  unsigned short* r1bf = (unsigned short*)(ws + OFF_R1BF);
  unsigned short* r2bf = (unsigned short*)(ws + OFF_R2BF);

  for (long long i = blockIdx.x*blockDim.x + threadIdx.x; i < 10853348LL;
       i += (long long)gridDim.x*blockDim.x){
    if (i < 38416) zbase[i] = 0.f;
    else if (i < 58416){ int j = i - 38416; muW4[j] = muW[(j/400)*450 + (j%400)]; }
    else if (i < 78416){ int j = i - 58416; lsW4[j] = lsW[(j/400)*450 + (j%400)]; }
    else if (i < 270416){
      int j = i - 78416; int m = j/320, r = j%320; int t = m/50, k = m%50;
      albf[j] = (r < 300) ? f2bf(qmu[((size_t)k*12 + t)*300 + r]) : 0;
    }
    else if (i < 272016){ int j = i - 270416; bsum0[j] = bi0[j] + bh0[j]; }
    else if (i < 273616){ int j = i - 272016; bsum1[j] = bi1[j] + bh1[j]; }
    else if (i < 273716){ int j = i - 273616; mlb[j] = (j < 50) ? mb[j] : lb[j-50]; }
    else if (i < 274916){ int j = i - 273716; rs[j] = 0.f; }
    else if (i < 354788){ int j = i - 274916; inbz[j] = 0u; }
    else if (i < 994788){
      int j = i - 354788; int r = j/1600, col = j%1600;
      int u = col >> 2, g = col & 3;
      w0T[j] = whh0[((size_t)(g*400 + u))*400 + r];
    }
    else if (i < 1634788){
      int j = i - 994788; int r = j/1600, col = j%1600;
      int u = col >> 2, g = col & 3;
      w1T[j] = whh1[((size_t)(g*400 + u))*400 + r];
    }
    else if (i < 2274788){
      int j = i - 1634788; int r = j/1600, col = j%1600;
      int u = col >> 2, g = col & 3;
      wi1T[j] = wih1[((size_t)(g*400 + u))*400 + r];
    }
    else if (i < 4978148){
      int j = i - 2274788; int row = j/7040, v = j%7040;
      nbbf[j] = (v < 7000) ? f2bf(nbows[(size_t)row*7000 + v]) : 0;
    }
    else if (i < 7794148){
      int j = i - 4978148; int row = j/7040, v = j%7040;
      qwbf[j] = (v < 7000) ? f2bf(qmap_w[(size_t)row*7000 + v]) : 0;
    }
    else if (i < 8459748){
      int j = i - 7794148; int row = j/416, r = j%416;
      w0bf[j] = (r < 400) ? f2bf(wih0[(size_t)row*400 + r]) : 0;
    }
    else if (i < 10059748){
      int j = i - 8459748; int row = j/320, r = j%320;
      r1bf[j] = (r < 300) ? f2bf(rho1w[(size_t)row*300 + r]) : 0;
    }
    else if (i < 10699748){
      int j = i - 10059748; int row = j/320, r = j%320;
      r2bf[j] = (r < 300) ? f2bf(rho2w[(size_t)row*300 + r]) : 0;
    }
    else { int j = i - 10699748; inpf[j] = qb[j % 400]; }   // inp_f32 = bias
  }
}

// ---------------- MFMA bf16 GEMM ----------------
__global__ __launch_bounds__(256) void gemm_bf16(
    const unsigned short* __restrict__ A, int lda,
    const unsigned short* __restrict__ B, int ldb,
    float* __restrict__ Cf, unsigned short* __restrict__ Cbf,
    float* __restrict__ Cacc, int ldc,
    int M, int N, int Kp, int kchunk,
    const float* __restrict__ bias, float* __restrict__ rowsum)
{
  __shared__ unsigned short As[64][40];
  __shared__ unsigned short Bs[64][40];
  __shared__ float sexp[64];
  const int tid = threadIdx.x;
  const int m0 = blockIdx.y * 64, n0 = blockIdx.x * 64;
  const int kbeg = blockIdx.z * kchunk;
  const int kend = min(Kp, kbeg + kchunk);
  const int wave = tid >> 6, lane = tid & 63;
  const int wm = (wave >> 1) * 32, wn = (wave & 1) * 32;
  const int ra = tid >> 2, ck = (tid & 3) << 3;
  const int fr = lane & 15, fo = (lane >> 4) << 3;
  if (rowsum && tid < 64) sexp[tid] = 0.f;

  f32x4 acc00 = {0.f,0.f,0.f,0.f}, acc01 = {0.f,0.f,0.f,0.f};
  f32x4 acc10 = {0.f,0.f,0.f,0.f}, acc11 = {0.f,0.f,0.f,0.f};
  int4 pa, pb;
  {
    int rA = m0 + ra, rB = n0 + ra;
    pa = (rA < M) ? *(const int4*)&A[(size_t)rA*lda + kbeg + ck] : make_int4(0,0,0,0);
    pb = (rB < N) ? *(const int4*)&B[(size_t)rB*ldb + kbeg + ck] : make_int4(0,0,0,0);
  }
  for (int k0 = kbeg; k0 < kend; k0 += 32){
    *(int4*)&As[ra][ck] = pa;
    *(int4*)&Bs[ra][ck] = pb;
    __syncthreads();
    if (k0 + 32 < kend){
      int rA = m0 + ra, rB = n0 + ra;
      pa = (rA < M) ? *(const int4*)&A[(size_t)rA*lda + k0 + 32 + ck] : make_int4(0,0,0,0);
      pb = (rB < N) ? *(const int4*)&B[(size_t)rB*ldb + k0 + 32 + ck] : make_int4(0,0,0,0);
    }
    short8v a0 = *(const short8v*)&As[wm      + fr][fo];
    short8v a1 = *(const short8v*)&As[wm + 16 + fr][fo];
    short8v b0 = *(const short8v*)&Bs[wn      + fr][fo];
    short8v b1 = *(const short8v*)&Bs[wn + 16 + fr][fo];
    acc00 = __builtin_amdgcn_mfma_f32_16x16x32_bf16(a0, b0, acc00, 0, 0, 0);
    acc01 = __builtin_amdgcn_mfma_f32_16x16x32_bf16(a0, b1, acc01, 0, 0, 0);
    acc10 = __builtin_amdgcn_mfma_f32_16x16x32_bf16(a1, b0, acc10, 0, 0, 0);
    acc11 = __builtin_amdgcn_mfma_f32_16x16x32_bf16(a1, b1, acc11, 0, 0, 0);
    __syncthreads();
  }
  const int rbase = (lane >> 4) << 2;
  auto epi = [&](f32x4 ac0, f32x4 ac1, int mi){
    #pragma unroll
    for (int reg = 0; reg < 4; ++reg){
      const int lr = wm + mi*16 + rbase + reg;
      const int gr = m0 + lr;
      float ex = 0.f;
      {
        int gc = n0 + wn + fr;
        if (gr < M && gc < N){
          if (Cacc) atomicAdd(&Cacc[(size_t)gr*ldc + gc], ac0[reg]);
          else {
            float val = ac0[reg] + (bias ? bias[gc] : 0.f);
            if (Cbf) Cbf[(size_t)gr*ldc + gc] = f2bf(val);
            else     Cf [(size_t)gr*ldc + gc] = val;
            if (rowsum) ex += __expf(val);
          }
        }
      }
      {
        int gc = n0 + wn + 16 + fr;
        if (gr < M && gc < N){
          if (Cacc) atomicAdd(&Cacc[(size_t)gr*ldc + gc], ac1[reg]);
          else {
            float val = ac1[reg] + (bias ? bias[gc] : 0.f);
            if (Cbf) Cbf[(size_t)gr*ldc + gc] = f2bf(val);
            else     Cf [(size_t)gr*ldc + gc] = val;
            if (rowsum) ex += __expf(val);
          }
        }
      }
      if (rowsum){
        ex += __shfl_xor(ex, 1); ex += __shfl_xor(ex, 2);
        ex += __shfl_xor(ex, 4); ex += __shfl_xor(ex, 8);
        if (fr == 0 && gr < M) atomicAdd(&sexp[lr], ex);
      }
    }
  };
  epi(acc00, acc01, 0);
  epi(acc10, acc11, 1);
  if (rowsum){
    __syncthreads();
    if (tid < 64 && m0 + tid < M) atomicAdd(&rowsum[m0 + tid], sexp[tid]);
  }
}

// ---------------- convert inp_f32 -> bf16 ----------------
__global__ void cvt_inp(const float* __restrict__ inpf, unsigned short* __restrict__ inpbf){
  int i = blockIdx.x*blockDim.x + threadIdx.x;
  if (i < 153600){
    int r = i / 400, c = i % 400;
    inpbf[r*416 + c] = f2bf(inpf[i]);
  }
}

// ---------------- f32 GEMM (kept for tiny muH2) ----------------
__device__ __forceinline__ float4 g4(const float* __restrict__ base, int row, int nrows,
                                     int ld, int k, int kend){
  float4 v; v.x = v.y = v.z = v.w = 0.f;
  if (row < nrows){
    const float* q = base + (size_t)row*ld + k;
    if (k + 3 < kend) v = *(const float4*)q;
  }
  return v;
}
__global__ __launch_bounds__(256) void gemm_f32(
    const float* __restrict__ A, int lda,
    const float* __restrict__ B, int ldb,
    float* __restrict__ C, int ldc,
    int M, int N, int K,
    const float* __restrict__ bias)
{
  __shared__ __align__(16) float As[16][68];
  __shared__ __align__(16) float Bs[16][68];
  const int tid = threadIdx.x;
  const int m0 = blockIdx.y * 64, n0 = blockIdx.x * 64;
  const int lm  = tid >> 2;
  const int lkq = (tid & 3) << 2;
  const int ty = tid >> 4, tx = tid & 15;
  float acc[4][4];
  #pragma unroll
  for (int i=0;i<4;++i)
    #pragma unroll
    for (int j=0;j<4;++j) acc[i][j] = 0.f;
  for (int k0 = 0; k0 < K; k0 += 16){
    float4 av = g4(A, m0+lm, M, lda, k0+lkq, K);
    float4 bv = g4(B, n0+lm, N, ldb, k0+lkq, K);
    As[lkq+0][lm]=av.x; As[lkq+1][lm]=av.y; As[lkq+2][lm]=av.z; As[lkq+3][lm]=av.w;
    Bs[lkq+0][lm]=bv.x; Bs[lkq+1][lm]=bv.y; Bs[lkq+2][lm]=bv.z; Bs[lkq+3][lm]=bv.w;
    __syncthreads();
    #pragma unroll
    for (int kk = 0; kk < 16; ++kk){
      const float4 a = *(const float4*)&As[kk][ty<<2];
      const float4 b = *(const float4*)&Bs[kk][tx<<2];
      float ar[4] = {a.x,a.y,a.z,a.w};
      float br[4] = {b.x,b.y,b.z,b.w};
      #pragma unroll
      for (int i=0;i<4;++i)
        #pragma unroll
        for (int j=0;j<4;++j) acc[i][j] = fmaf(ar[i], br[j], acc[i][j]);
    }
    __syncthreads();
  }
  const int om = m0 + (ty<<2), on = n0 + (tx<<2);
  #pragma unroll
  for (int i=0;i<4;++i)
    #pragma unroll
    for (int j=0;j<4;++j)
      if (om+i < M && on+j < N)
        C[(size_t)(om+i)*ldc + (on+j)] = acc[i][j] + (bias ? bias[on+j] : 0.f);
}

// ---------------- pipelined LSTM: layer0 step t || layer1 step t-1 ----------------
__global__ __launch_bounds__(256) void lstm_pipe(
    const float* __restrict__ X0,    const float* __restrict__ w0T,
    const float* __restrict__ wi1T,  const float* __restrict__ w1T,
    const float* __restrict__ bsum1,
    float* __restrict__ hs0, float* __restrict__ hs1,
    float* __restrict__ cst0, float* __restrict__ cst1, int step)
{
  __shared__ __align__(16) float4 hq4[100*32];
  __shared__ __align__(16) float4 red4[4][32][2];
  const int tid = threadIdx.x;
  const int rh = tid >> 6;
  const int b  = (tid & 63) >> 1;
  const int ul = tid & 1;
  const int rq0 = rh * 25;

  if (blockIdx.x < 200){
    const int t = step;
    if (t >= 12) return;
    const int U0 = blockIdx.x * 2;
    const int u = U0 + ul;
    if (t > 0){
      for (int i = tid; i < 3200; i += 256){
        int bb = i & 31, rq = i >> 5;
        hq4[rq*32 + bb] = *(const float4*)&hs0[((size_t)(bb*12 + (t-1)))*400 + rq*4];
      }
      __syncthreads();
      const float* wcol = w0T + (size_t)u*4;
      float4 acc = {0.f,0.f,0.f,0.f};
      #pragma unroll 5
      for (int rq = rq0; rq < rq0 + 25; ++rq){
        float4 h4 = hq4[rq*32 + b];
        float hr[4] = {h4.x, h4.y, h4.z, h4.w};
        #pragma unroll
        for (int dr = 0; dr < 4; ++dr){
          float4 w4 = *(const float4*)&wcol[(size_t)(rq*4 + dr)*1600];
          acc.x = fmaf(hr[dr], w4.x, acc.x);
          acc.y = fmaf(hr[dr], w4.y, acc.y);
          acc.z = fmaf(hr[dr], w4.z, acc.z);
          acc.w = fmaf(hr[dr], w4.w, acc.w);
        }
      }
      red4[rh][b][ul] = acc;
    }
    __syncthreads();
    if (tid < 64){
      const int bb = tid >> 1, uu = U0 + (tid & 1);
      float4 a = {0.f,0.f,0.f,0.f};
      if (t > 0){
        #pragma unroll
        for (int w = 0; w < 4; ++w){
          float4 r = red4[w][bb][tid & 1];
          a.x += r.x; a.y += r.y; a.z += r.z; a.w += r.w;
        }
      }
      const size_t xrow = ((size_t)bb*12 + t)*1600;
      float gi = a.x + X0[xrow          + uu];
      float gf = a.y + X0[xrow +  400   + uu];
      float gg = a.z + X0[xrow +  800   + uu];
      float go = a.w + X0[xrow + 1200   + uu];
      float ii = 1.f/(1.f + expf(-gi));
      float ff = 1.f/(1.f + expf(-gf));
      float tg = tanhf(gg);
      float oo = 1.f/(1.f + expf(-go));
      float c = (t == 0) ? 0.f : cst0[bb*400 + uu];
      c = ff*c + ii*tg;
      cst0[bb*400 + uu] = c;
      hs0[((size_t)bb*12 + t)*400 + uu] = oo * tanhf(c);
    }
  } else {
    const int t = step - 1;
    if (t < 0) return;
    const int U0 = (blockIdx.x - 200) * 2;
    const int u = U0 + ul;
    float4 acc = {0.f,0.f,0.f,0.f};
    for (int i = tid; i < 3200; i += 256){
      int bb = i & 31, rq = i >> 5;
      hq4[rq*32 + bb] = *(const float4*)&hs0[((size_t)(bb*12 + t))*400 + rq*4];
    }
    __syncthreads();
    {
      const float* wcol = wi1T + (size_t)u*4;
      #pragma unroll 5
      for (int rq = rq0; rq < rq0 + 25; ++rq){
        float4 h4 = hq4[rq*32 + b];
        float hr[4] = {h4.x, h4.y, h4.z, h4.w};
        #pragma unroll
        for (int dr = 0; dr < 4; ++dr){
          float4 w4 = *(const float4*)&wcol[(size_t)(rq*4 + dr)*1600];
          acc.x = fmaf(hr[dr], w4.x, acc.x);
          acc.y = fmaf(hr[dr], w4.y, acc.y);
          acc.z = fmaf(hr[dr], w4.z, acc.z);
          acc.w = fmaf(hr[dr], w4.w, acc.w);
        }
      }
    }
    __syncthreads();
    if (t > 0){
      for (int i = tid; i < 3200; i += 256){
        int bb = i & 31, rq = i >> 5;
        hq4[rq*32 + bb] = *(const float4*)&hs1[((size_t)(bb*12 + (t-1)))*400 + rq*4];
      }
    }
    __syncthreads();
    if (t > 0){
      const float* wcol = w1T + (size_t)u*4;
      #pragma unroll 5
      for (int rq = rq0; rq < rq0 + 25; ++rq){
        float4 h4 = hq4[rq*32 + b];
        float hr[4] = {h4.x, h4.y, h4.z, h4.w};
        #pragma unroll
        for (int dr = 0; dr < 4; ++dr){
          float4 w4 = *(const float4*)&wcol[(size_t)(rq*4 + dr)*1600];
          acc.x = fmaf(hr[dr], w4.x, acc.x);
          acc.y = fmaf(hr[dr], w4.y, acc.y);
          acc.z = fmaf(hr[dr], w4.z, acc.z);
          acc.w = fmaf(hr[dr], w4.w, acc.w);
        }
      }
    }
    red4[rh][b][ul] = acc;
    __syncthreads();
    if (tid < 64){
      const int bb = tid >> 1, uu = U0 + (tid & 1);
      float4 a = {0.f,0.f,0.f,0.f};
      #pragma unroll
      for (int w = 0; w < 4; ++w){
        float4 r = red4[w][bb][tid & 1];
        a.x += r.x; a.y += r.y; a.z += r.z; a.w += r.w;
      }
      float gi = a.x + bsum1[        uu];
      float gf = a.y + bsum1[ 400 + uu];
      float gg = a.z + bsum1[ 800 + uu];
      float go = a.w + bsum1[1200 + uu];
      float ii = 1.f/(1.f + expf(-gi));
      float ff = 1.f/(1.f + expf(-gf));
      float tg = tanhf(gg);
      float oo = 1.f/(1.f + expf(-go));
      float c = (t == 0) ? 0.f : cst1[bb*400 + uu];
      c = ff*c + ii*tg;
      cst1[bb*400 + uu] = c;
      hs1[((size_t)bb*12 + t)*400 + uu] = oo * tanhf(c);
    }
  }
}

// ---------------- theta head (4 blocks, 8 b's each) ----------------
__global__ __launch_bounds__(512) void theta_par(
    const float* __restrict__ muH2,
    const float* __restrict__ muW, const float* __restrict__ lsW,
    float* __restrict__ theta, float* __restrict__ accs)
{
  __shared__ float zsall[12][8][50];
  __shared__ float wm[50][51], wl[50][51];
  __shared__ float ktot;
  const int tid = threadIdx.x;
  const int b0 = blockIdx.x * 8;
  for (int i = tid; i < 2500; i += 512){
    int k = i / 50, j = i % 50;
    wm[k][j] = muW[k*450 + 400 + j];
    wl[k][j] = lsW[k*450 + 400 + j];
  }
  if (tid == 0) ktot = 0.f;
  __syncthreads();
  const float dd = expf(LOG_DELTA) + 1e-6f;
  for (int t = 0; t < 12; ++t){
    float kpart = 0.f;
    if (tid < 400){
      int bl = tid / 50, k = tid % 50, b = b0 + bl;
      float m = muH2[((size_t)b*12 + t)*100 + k];
      float l = muH2[((size_t)b*12 + t)*100 + 50 + k];
      float zp = 0.f;
      if (t > 0){
        zp = zsall[t-1][bl][k];
        float sm = 0.f, sl = 0.f;
        #pragma unroll 5
        for (int j = 0; j < 50; ++j){
          float z = zsall[t-1][bl][j];
          sm = fmaf(z, wm[k][j], sm);
          sl = fmaf(z, wl[k][j], sl);
        }
        m += sm; l += sl;
      }
      zsall[t][bl][k] = m;
      float denom = (t > 0) ? dd : (1.f + 1e-6f);
      float pls = (t > 0) ? LOG_DELTA : 0.f;
      float d = m - zp;
      kpart += (expf(l) + d*d)/denom - 1.f + pls - l;
    }
    kpart = wsum64(kpart);
    if ((tid & 63) == 0) atomicAdd(&ktot, 0.5f * kpart / 32.f);
    __syncthreads();
  }
  for (int rr = tid; rr < 96; rr += 512){
    int t = rr >> 3, bl = rr & 7, b = b0 + bl;
    float m = -3.0e38f;
    for (int k = 0; k < 50; ++k) m = fmaxf(m, zsall[t][bl][k]);
    float S = 0.f;
    for (int k = 0; k < 50; ++k) S += expf(zsall[t][bl][k] - m);
    float inv = 1.f/S;
    for (int k = 0; k < 50; ++k)
      theta[((size_t)t*32 + b)*50 + k] = expf(zsall[t][bl][k] - m) * inv;
  }
  if (tid == 0) atomicAdd(&accs[6], ktot);
}

// ---------------- kld_alpha ----------------
__global__ void kld_alpha_k(const float* __restrict__ qmu, const float* __restrict__ qls,
                            float* __restrict__ accs){
  const int t = blockIdx.x / 50, k = blockIdx.x % 50;
  const size_t base  = ((size_t)k*12 + t)*300;
  const size_t pbase = ((size_t)k*12 + (t-1))*300;
  const float dd  = (t > 0) ? (expf(LOG_DELTA) + 1e-6f) : (1.f + 1e-6f);
  const float pls = (t > 0) ? LOG_DELTA : 0.f;
  float s = 0.f;
  for (int r = threadIdx.x; r < 300; r += 64){
    float qm = qmu[base + r], ql = qls[base + r];
    float pm = (t > 0) ? qmu[pbase + r] : 0.f;
    float d = qm - pm;
    s += (expf(ql) + d*d)/dd - 1.f + pls - ql;
  }
  s = wsum64(s);
  if (threadIdx.x == 0) atomicAdd(&accs[7], 0.5f * s / 50.f);
}

// ---------------- pass1 v6: Taylor-exp (x = th*be < 1e-4), per-item bound,
// 1-round rejection. Trans ops/thread ~21 (13 staging exp + 8 log th).
__global__ __launch_bounds__(256) void pass1(
    const float* __restrict__ blog, const float* __restrict__ rs,
    const float* __restrict__ theta,
    float* __restrict__ bzg,
    float* __restrict__ c1g1, float* __restrict__ c1g2,
    float* __restrict__ accs)
{
  const int t = blockIdx.y;
  const int v0 = blockIdx.x * 64;
  __shared__ float th[32][50];
  __shared__ float be[50][64];
  __shared__ float c0s[64][50];
  __shared__ unsigned int c1p[2][32][25];
  __shared__ float rlog[2][50];
  __shared__ float kred[4];
  const int tid = threadIdx.x;

  if (tid < 100){
    int p = tid / 50, k = tid % 50;
    rlog[p][k] = __logf(rs[p*600 + t*50 + k]);
  }
  float lg[13];
  #pragma unroll
  for (int j = 0; j < 13; ++j){
    int i = tid + j*256;
    lg[j] = -40.f;
    if (i < 3200){
      int k = i >> 6, vl = i & 63, v = v0 + vl;
      if (v < 7000) lg[j] = blog[((size_t)t*50 + k)*7000 + v];
    }
  }
  #pragma unroll
  for (int j = 0; j < 7; ++j){
    int i = tid + j*256;
    if (i < 1600) th[i/50][i%50] = theta[(size_t)t*1600 + i];
  }
  #pragma unroll
  for (int j = 0; j < 13; ++j){
    int i = tid + j*256;
    if (i < 3200) ((float*)c0s)[i] = 0.f;
  }
  #pragma unroll
  for (int j = 0; j < 7; ++j){
    int i = tid + j*256;
    if (i < 1600) ((unsigned int*)c1p)[i] = 0u;
  }
  if (tid < 4) kred[tid] = 0.f;
  __syncthreads();
  #pragma unroll
  for (int j = 0; j < 13; ++j){
    int i = tid + j*256;
    if (i < 3200){
      int k = i >> 6, vl = i & 63, v = v0 + vl;
      int p = (v >= 5000);
      be[k][vl] = __expf(lg[j] - rlog[p][k]);
    }
  }
  __syncthreads();

  const int b = tid >> 3, sub = tid & 7;

  // sx = sum_k x, mx = max_k x, with x = th*be (< ~1e-4 => exp(x) ~= 1+x,
  // error x^2/2 < 1e-8, below f32 noise). S1 = 50 + sx.
  float sx[8], mx[8];
  #pragma unroll
  for (int i = 0; i < 8; ++i){ sx[i] = 0.f; mx[i] = 0.f; }
  for (int k = 0; k < 50; ++k){
    float tk = th[b][k];
    #pragma unroll
    for (int i = 0; i < 8; ++i){
      float x = tk * be[k][sub + 8*i];
      sx[i] += x;
      mx[i] = fmaxf(mx[i], x);
    }
  }
  float inv[8], lS1[8], bnd[8];
  #pragma unroll
  for (int i = 0; i < 8; ++i){
    inv[i] = 1.f / (50.f + sx[i]);
    lS1[i] = LOG50 + sx[i] * 0.02f;          // log(50+sx) ~= log50 + sx/50
    bnd[i] = (1.f + mx[i]) * inv[i];         // >= pi_k for all k (valid bound)
  }

  // rejection sampling: accept with prob exp(pi - bnd) ~= 1 + y + y^2/2
  // (y = pi-bnd in (-2e-6, 0]; poly error |y|^3/6, negligible; poly <= 1).
  int ks[8]; float xs[8];
  unsigned fmask = 0;
  const int vbase = (t*32 + b)*7000 + v0 + sub;
  #pragma unroll
  for (int i = 0; i < 8; ++i){
    ks[i] = 0; xs[i] = 0.f;
    if (v0 + sub + 8*i >= 7000) fmask |= 1u << i;
  }
  int round = 0;
  while (true){
    const unsigned roff = (unsigned)round * 0x9E3779B9u;
    #pragma unroll
    for (int i = 0; i < 8; ++i){
      if (!((fmask >> i) & 1u)){
        const unsigned bse = (unsigned)(vbase + 8*i) * 2u;
        float u1 = u01(bse + roff);
        float u2 = u01(bse + 1u + roff);
        int kp = min((int)(u1 * 50.f), 49);
        float x  = th[b][kp] * be[kp][sub + 8*i];
        float pi = (1.f + x) * inv[i];
        float y  = pi - bnd[i];
        float ap = 1.f + y + 0.5f*y*y;
        if (u2 <= ap || round >= 7){
          ks[i] = kp; xs[i] = x; fmask |= 1u << i;
        }
      }
    }
    ++round;
    if (__all(fmask == 255u)) break;
  }

  float kA1 = 0.f, kB1 = 0.f, kA2 = 0.f, kB2 = 0.f;
  #pragma unroll
  for (int i = 0; i < 8; ++i){
    const int vl = sub + 8*i, v = v0 + vl;
    if (v < 7000){
      float pis  = (1.f + xs[i]) * inv[i];
      float lpis = xs[i] - lS1[i];           // log((1+x)/S1) ~= x - log(S1)
      float lt   = __logf(th[b][ks[i]]);
      if (v >= 5000){ kA2 += lt; kB2 += pis*lpis; }
      else          { kA1 += lt; kB1 += pis*lpis; }
      atomicAdd(&c0s[vl][ks[i]], 1.f);
      atomicAdd(&c1p[(v >= 5000) ? 1 : 0][b][ks[i] >> 1],
                (ks[i] & 1) ? 65536u : 1u);
    }
  }
  kA1 = wsum64(kA1); kB1 = wsum64(kB1); kA2 = wsum64(kA2); kB2 = wsum64(kB2);
  if ((tid & 63) == 0){
    atomicAdd(&kred[0], kA1); atomicAdd(&kred[1], kB1);
    atomicAdd(&kred[2], kA2); atomicAdd(&kred[3], kB2);
  }
  __syncthreads();
  #pragma unroll
  for (int j = 0; j < 13; ++j){
    int i = tid + j*256;
    if (i < 3200){
      int k = i >> 6, vl = i & 63, v = v0 + vl;
      if (v < 7000)
        bzg[(size_t)t*350000 + (size_t)k*7000 + v] = be[k][vl] * c0s[vl][k] * (1.f/32.f);
    }
  }
  for (int i = tid; i < 1600; i += 256){
    int b2 = i / 50, k2 = i % 50;
    unsigned w1 = c1p[0][b2][k2 >> 1];
    unsigned w2 = c1p[1][b2][k2 >> 1];
    unsigned cnt1 = (k2 & 1) ? (w1 >> 16) : (w1 & 0xFFFFu);
    unsigned cnt2 = (k2 & 1) ? (w2 >> 16) : (w2 & 0xFFFFu);
    if (cnt1) atomicAdd(&c1g1[(size_t)t*1600 + i], (float)cnt1);
    if (cnt2) atomicAdd(&c1g2[(size_t)t*1600 + i], (float)cnt2);
  }
  if (tid < 4) atomicAdd(&accs[tid], kred[tid]);
}

// ---------------- pass2: log-likelihood ----------------
__global__ __launch_bounds__(256) void pass2(
    const float* __restrict__ bzg, const float* __restrict__ theta,
    const float* __restrict__ c1g1, const float* __restrict__ c1g2,
    const float* __restrict__ bows, float* __restrict__ accs)
{
  const int t = blockIdx.y, v0 = blockIdx.x * 64;
  __shared__ float tz[2][32][50];
  __shared__ float bzs[50][64];
  __shared__ float sr[2];
  const int tid = threadIdx.x;
  if (tid < 2) sr[tid] = 0.f;
  for (int i = tid; i < 1600; i += 256){
    int b = i / 50, k = i % 50;
    float th_ = theta[(size_t)t*1600 + i];
    tz[0][b][k] = th_ * c1g1[(size_t)t*1600 + i] * (1.f/5000.f);
    tz[1][b][k] = th_ * c1g2[(size_t)t*1600 + i] * (1.f/2000.f);
  }
  for (int i = tid; i < 3200; i += 256){
    int k = i >> 6, vl = i & 63, v = v0 + vl;
    bzs[k][vl] = (v < 7000) ? bzg[(size_t)t*350000 + (size_t)k*7000 + v] : 0.f;
  }
  __syncthreads();

  const int b = tid >> 3, sub = tid & 7;
  int part[8];
  #pragma unroll
  for (int i = 0; i < 8; ++i) part[i] = (v0 + sub + 8*i >= 5000);
  float dot[8];
  #pragma unroll
  for (int i = 0; i < 8; ++i) dot[i] = 0.f;
  for (int k = 0; k < 50; ++k){
    float t0 = tz[0][b][k], t1 = tz[1][b][k];
    #pragma unroll
    for (int i = 0; i < 8; ++i)
      dot[i] = fmaf(part[i] ? t1 : t0, bzs[k][sub + 8*i], dot[i]);
  }
  float s1 = 0.f, s2 = 0.f;
  #pragma unroll
  for (int i = 0; i < 8; ++i){
    const int v = v0 + sub + 8*i;
    if (v < 7000){
      const float w = bows[((size_t)b*12 + t)*7000 + v];
      const float l = __logf(dot[i]) * w;
      if (part[i]) s2 += l; else s1 += l;
    }
  }
  s1 = wsum64(s1); s2 = wsum64(s2);
  if ((tid & 63) == 0){ atomicAdd(&sr[0], s1); atomicAdd(&sr[1], s2); }
  __syncthreads();
  if (tid < 2) atomicAdd(&accs[4 + tid], sr[tid]);
}

// ---------------- finalize ----------------
__global__ void finalize_k(const float* __restrict__ accs, float* __restrict__ out){
  if (threadIdx.x == 0 && blockIdx.x == 0){
    out[0] = -(accs[4] + accs[5]) * (1.f/32.f);
    out[1] = accs[6];
    out[2] = -accs[0]/(32.f*5000.f) - accs[1]/32.f;
    out[3] = -accs[2]/(32.f*2000.f) - accs[3]/32.f;
    out[4] = accs[7];
  }
}

// ---------------- host launcher ----------------
extern "C" void kernel_launch(void* const* d_in, const int* in_sizes, int n_in,
                              void* d_out, int out_size, void* d_ws, size_t ws_size,
                              hipStream_t stream)
{
  const float* bows   = (const float*)d_in[0];
  const float* nbows  = (const float*)d_in[1];
  const float* qmap_w = (const float*)d_in[2];
  const float* qmap_b = (const float*)d_in[3];
  const float* wih0   = (const float*)d_in[4];
  const float* whh0   = (const float*)d_in[5];
  const float* bih0   = (const float*)d_in[6];
  const float* bhh0   = (const float*)d_in[7];
  const float* wih1   = (const float*)d_in[8];
  const float* whh1   = (const float*)d_in[9];
  const float* bih1   = (const float*)d_in[10];
  const float* bhh1   = (const float*)d_in[11];
  const float* muW    = (const float*)d_in[12];
  const float* muB    = (const float*)d_in[13];
  const float* lsW    = (const float*)d_in[14];
  const float* lsB    = (const float*)d_in[15];
  const float* qmu    = (const float*)d_in[16];
  const float* qlsa   = (const float*)d_in[17];
  const float* rho1w  = (const float*)d_in[18];
  const float* rho1b  = (const float*)d_in[19];
  const float* rho2w  = (const float*)d_in[20];
  const float* rho2b  = (const float*)d_in[21];

  float* ws  = (float*)d_ws;
  float* out = (float*)d_out;

  float* c1g1  = ws + OFF_C1G1;
  float* c1g2  = ws + OFF_C1G2;
  float* accs  = ws + OFF_ACCS;
  float* bzg   = ws + OFF_C0G;
  float* beta  = ws + OFF_BETA;
  float* inpf  = ws + OFF_ALPHAT;
  float* X0    = ws + OFF_X0;
  float* hs0   = ws + OFF_OUT0;
  float* hs1   = ws + OFF_OUT1;
  float* cst0  = ws + OFF_CST;
  float* cst1  = ws + OFF_CST1;
  float* muH2  = ws + OFF_MUH;
  float* theta = ws + OFF_THETA;
  float* muW4  = ws + OFF_MUW4;
  float* bsum0 = ws + OFF_LTH;
  float* bsum1 = ws + OFF_LTH + 1600;
  float* mlb   = ws + OFF_LTH + 3200;
  float* rs    = ws + OFF_RS;
  unsigned short* nbbf  = (unsigned short*)(ws + OFF_NBBF);
  unsigned short* qwbf  = (unsigned short*)(ws + OFF_QWBF);
  unsigned short* inpbf = (unsigned short*)(ws + OFF_INP);
  unsigned short* w0bf  = (unsigned short*)(ws + OFF_W0BF);
  unsigned short* albf  = (unsigned short*)(ws + OFF_ALBF);
  unsigned short* r1bf  = (unsigned short*)(ws + OFF_R1BF);
  unsigned short* r2bf  = (unsigned short*)(ws + OFF_R2BF);
  float* w0T  = ws + OFF_W0T;
  float* w1T  = ws + OFF_W1T;
  float* wi1T = ws + OFF_WIH1T;

  prep_misc<<<4096, 256, 0, stream>>>(ws, muW, lsW, qmu, bih0, bhh0, bih1, bhh1,
                                      muB, lsB, qmap_b, whh0, whh1, wih1,
                                      nbows, qmap_w, wih0, rho1w, rho2w);
  kld_alpha_k<<<600, 64, 0, stream>>>(qmu, qlsa, accs);

  // inp_f32 += nbows_bf @ qmap_w_bf^T  (split-K x10; bias pre-init'd in prep)
  gemm_bf16<<<dim3(7,6,10), 256, 0, stream>>>(nbbf, 7040, qwbf, 7040,
                                              nullptr, nullptr, inpf, 400,
                                              384, 400, 7040, 704, nullptr, nullptr);
  cvt_inp<<<600, 256, 0, stream>>>(inpf, inpbf);

  // X0 = inp_bf @ wih0^T + (bih0+bhh0)     M=384 N=1600 Kp=416
  gemm_bf16<<<dim3(25,6,1), 256, 0, stream>>>(inpbf, 416, w0bf, 416,
                                              X0, nullptr, nullptr, 1600,
                                              384, 1600, 416, 416, bsum0, nullptr);
  // pipelined double-layer LSTM: 13 launches
  for (int i = 0; i < 13; ++i)
    lstm_pipe<<<400, 256, 0, stream>>>(X0, w0T, wi1T, w1T, bsum1,
                                       hs0, hs1, cst0, cst1, i);

  // muH2 = hs1 @ [muW4;lsW4]^T + [muB;lsB]
  gemm_f32<<<dim3(2,6), 256, 0, stream>>>(hs1, 400, muW4, 400, muH2, 100,
                                          384, 100, 400, mlb);
  theta_par<<<4, 512, 0, stream>>>(muH2, muW, lsW, theta, accs);

  // beta logits via MFMA + fused row sum(exp)
  gemm_bf16<<<dim3(79,10,1), 256, 0, stream>>>(albf, 320, r1bf, 320,
                                               beta, nullptr, nullptr, 7000,
                                               600, 5000, 320, 320, rho1b, rs);
  gemm_bf16<<<dim3(32,10,1), 256, 0, stream>>>(albf, 320, r2bf, 320,
                                               beta + 5000, nullptr, nullptr, 7000,
                                               600, 2000, 320, 320, rho2b, rs + 600);

  pass1<<<dim3(110,12), 256, 0, stream>>>(beta, rs, theta, bzg, c1g1, c1g2, accs);
  pass2<<<dim3(110,12), 256, 0, stream>>>(bzg, theta, c1g1, c1g2, bows, accs);

  finalize_k<<<1, 64, 0, stream>>>(accs, out);
}

// Round 11
// 442.478 us; speedup vs baseline: 1.9154x; 1.0386x over previous
//
#include <hip/hip_runtime.h>

// ---------------- constants ----------------
#define LOG_DELTA (-5.2983174f)   // ln(0.005)
#define LOG50     (3.9120230054f) // ln(50)

typedef __attribute__((ext_vector_type(8))) short short8v;
typedef __attribute__((ext_vector_type(4))) float f32x4;

// ws layout (float offsets)
constexpr size_t OFF_C1G1  = 0;                       // [12][32][50]
constexpr size_t OFF_C1G2  = 19200;                   // [12][32][50]
constexpr size_t OFF_ACCS  = 38400;                   // [16]
constexpr size_t OFF_C0G   = 38416;                   // bzg [12][50][7000]
constexpr size_t OFF_BETA  = OFF_C0G  + 4200000;      // [600][7000] logits
constexpr size_t OFF_ALPHAT= OFF_BETA + 4200000;      // inp_f32 [384][400]
constexpr size_t OFF_INP   = OFF_ALPHAT + 180000;     // inp_bf ushort[384][416]
constexpr size_t OFF_X0    = OFF_INP  + 153600;       // [384][1600]
constexpr size_t OFF_OUT0  = OFF_X0   + 614400;       // hs0 [384][400]
constexpr size_t OFF_X1    = OFF_OUT0 + 153600;       // cst1|albf|r2bf region
constexpr size_t OFF_OUT1  = OFF_X1   + 614400;       // hs1 [384][400]
constexpr size_t OFF_CST   = OFF_OUT1 + 153600;       // cst0 [32][400]
constexpr size_t OFF_MUH   = OFF_CST  + 12800;        // [384][100]
constexpr size_t OFF_THETA = OFF_MUH  + 38400;        // [12][32][50]
constexpr size_t OFF_LTH   = OFF_THETA+ 19200;        // bsum0|bsum1|mlb|rs
constexpr size_t OFF_MUW4  = OFF_LTH  + 19200;        // [50][400]
constexpr size_t OFF_LSW4  = OFF_MUW4 + 20000;        // [50][400]
constexpr size_t OFF_RS    = OFF_LTH  + 3300;         // rowsum [2][600]
// overlay in bzg region (dead before pass1):
constexpr size_t OFF_W0T   = OFF_C0G;                 // f32 [400][1600]
constexpr size_t OFF_W1T   = OFF_C0G + 640000;        // f32 [400][1600]
constexpr size_t OFF_WIH1T = OFF_C0G + 1280000;       // f32 [400][1600]
constexpr size_t OFF_NBBF  = OFF_C0G + 1920000;       // ushort[384][7040]
constexpr size_t OFF_R1BF  = OFF_C0G + 3271680;       // ushort[5000][320]
// overlay in beta region (dead before beta GEMMs):
constexpr size_t OFF_QWBF  = OFF_BETA;                // ushort[400][7040]
constexpr size_t OFF_W0BF  = OFF_BETA + 1408000;      // ushort[1600][416]
// overlay in X1 region (X1 eliminated):
constexpr size_t OFF_CST1  = OFF_X1;                  // f32 [32][400]
constexpr size_t OFF_ALBF  = OFF_X1 + 12800;          // ushort[600][320]
constexpr size_t OFF_R2BF  = OFF_X1 + 108800;         // ushort[2000][320]

// ---------------- helpers ----------------
__device__ __forceinline__ float wsum64(float x){
  #pragma unroll
  for (int o = 32; o; o >>= 1) x += __shfl_down(x, o);
  return x;
}
__device__ __forceinline__ float u01(unsigned int x){
  x ^= x >> 16; x *= 0x7feb352dU;
  x ^= x >> 15; x *= 0x846ca68bU;
  x ^= x >> 16;
  return ((float)x + 0.5f) * (1.0f/4294967296.0f);
}
__device__ __forceinline__ unsigned short f2bf(float x){
  unsigned int u = __float_as_uint(x);
  u += 0x7FFFu + ((u >> 16) & 1u);
  return (unsigned short)(u >> 16);
}
__device__ __forceinline__ ushort4 f4bf(float4 v){
  ushort4 r;
  r.x = f2bf(v.x); r.y = f2bf(v.y); r.z = f2bf(v.z); r.w = f2bf(v.w);
  return r;
}

// ---------------- fused prep (vectorized: 4 elems/unit, float4/ushort4 I/O) ----
// unit ranges (cumulative):
//  S0  [0,9604)            zero zbase (38416 f32)
//  S1  [9604,14604)        muW4  (20000)
//  S2  [14604,19604)       lsW4  (20000)
//  S3  [19604,67604)       albf  (192000 us)
//  S4  [67604,68004)       bsum0 (1600)
//  S5  [68004,68404)       bsum1 (1600)
//  S6  [68404,68429)       mlb   (100)
//  S7  [68429,68729)       rs    (1200 zero)
//  S8  [68729,88697)       inbz  (79872 u32 zero)
//  S9  [88697,248697)      w0T   (640000)
//  S10 [248697,408697)     w1T
//  S11 [408697,568697)     wi1T
//  S12 [568697,1244537)    nbbf  (384x7040 us)
//  S13 [1244537,1948537)   qwbf  (400x7040 us)
//  S14 [1948537,2114937)   w0bf  (1600x416 us)
//  S15 [2114937,2514937)   r1bf  (5000x320 us)
//  S16 [2514937,2674937)   r2bf  (2000x320 us)
//  S17 [2674937,2713337)   inpf  (153600 = qb bias)
__global__ void prep_misc(float* __restrict__ ws,
    const float* __restrict__ muW, const float* __restrict__ lsW,
    const float* __restrict__ qmu,
    const float* __restrict__ bi0, const float* __restrict__ bh0,
    const float* __restrict__ bi1, const float* __restrict__ bh1,
    const float* __restrict__ mb,  const float* __restrict__ lb,
    const float* __restrict__ qb,
    const float* __restrict__ whh0, const float* __restrict__ whh1,
    const float* __restrict__ wih1,
    const float* __restrict__ nbows, const float* __restrict__ qmap_w,
    const float* __restrict__ wih0,
    const float* __restrict__ rho1w, const float* __restrict__ rho2w)
{
  float* zbase = ws + OFF_C1G1;
  float* muW4  = ws + OFF_MUW4;
  float* lsW4  = ws + OFF_LSW4;
  unsigned short* albf = (unsigned short*)(ws + OFF_ALBF);
  float* bsum0 = ws + OFF_LTH;
  float* bsum1 = ws + OFF_LTH + 1600;
  float* mlb   = ws + OFF_LTH + 3200;
  float* rs    = ws + OFF_RS;
  unsigned int* inbz = (unsigned int*)(ws + OFF_INP);
  float* inpf  = ws + OFF_ALPHAT;
  float* w0T   = ws + OFF_W0T;
  float* w1T   = ws + OFF_W1T;
  float* wi1T  = ws + OFF_WIH1T;
  unsigned short* nbbf = (unsigned short*)(ws + OFF_NBBF);
  unsigned short* qwbf = (unsigned short*)(ws + OFF_QWBF);
  unsigned short* w0bf = (unsigned short*)(ws + OFF_W0BF);
  unsigned short* r1bf = (unsigned short*)(ws + OFF_R1BF);
  unsigned short* r2bf = (unsigned short*)(ws + OFF_R2BF);
  const float4 z4 = {0.f, 0.f, 0.f, 0.f};

  for (long long un = blockIdx.x*blockDim.x + threadIdx.x; un < 2713337LL;
       un += (long long)gridDim.x*blockDim.x){
    if (un < 9604){
      int j = (int)un * 4;
      if (j + 3 < 38416) *(float4*)&zbase[j] = z4;
      else { for (int q = 0; q < 4 && j+q < 38416; ++q) zbase[j+q] = 0.f; }
    }
    else if (un < 14604){
      int j = (int)(un - 9604) * 4;
      int k = j / 400, c = j % 400;
      const float* s = &muW[k*450 + c];
      float4 v = {s[0], s[1], s[2], s[3]};
      *(float4*)&muW4[j] = v;
    }
    else if (un < 19604){
      int j = (int)(un - 14604) * 4;
      int k = j / 400, c = j % 400;
      const float* s = &lsW[k*450 + c];
      float4 v = {s[0], s[1], s[2], s[3]};
      *(float4*)&lsW4[j] = v;
    }
    else if (un < 67604){
      int j = (int)(un - 19604) * 4;
      int m = j / 320, r = j % 320;
      int t = m / 50, k = m % 50;
      ushort4 o = {0,0,0,0};
      if (r < 300) o = f4bf(*(const float4*)&qmu[((size_t)k*12 + t)*300 + r]);
      *(ushort4*)&albf[j] = o;
    }
    else if (un < 68004){
      int j = (int)(un - 67604) * 4;
      float4 a = *(const float4*)&bi0[j], b = *(const float4*)&bh0[j];
      float4 v = {a.x+b.x, a.y+b.y, a.z+b.z, a.w+b.w};
      *(float4*)&bsum0[j] = v;
    }
    else if (un < 68404){
      int j = (int)(un - 68004) * 4;
      float4 a = *(const float4*)&bi1[j], b = *(const float4*)&bh1[j];
      float4 v = {a.x+b.x, a.y+b.y, a.z+b.z, a.w+b.w};
      *(float4*)&bsum1[j] = v;
    }
    else if (un < 68429){
      int j = (int)(un - 68404) * 4;
      #pragma unroll
      for (int q = 0; q < 4; ++q){
        int jj = j + q;
        mlb[jj] = (jj < 50) ? mb[jj] : lb[jj-50];
      }
    }
    else if (un < 68729){
      int j = (int)(un - 68429) * 4;
      *(float4*)&rs[j] = z4;
    }
    else if (un < 88697){
      int j = (int)(un - 68729) * 4;
      *(uint4*)&inbz[j] = make_uint4(0u,0u,0u,0u);
    }
    else if (un < 568697){
      long long rel = un - 88697;
      int half = (int)(rel / 160000);
      int j = (int)(rel % 160000) * 4;
      int r = j / 1600, c = j % 1600;
      int u = c >> 2;
      const float* src = (half == 0) ? whh0 : (half == 1) ? whh1 : wih1;
      float* dst = (half == 0) ? w0T : (half == 1) ? w1T : wi1T;
      float4 v = { src[((size_t)(0*400 + u))*400 + r],
                   src[((size_t)(1*400 + u))*400 + r],
                   src[((size_t)(2*400 + u))*400 + r],
                   src[((size_t)(3*400 + u))*400 + r] };
      *(float4*)&dst[j] = v;
    }
    else if (un < 1244537){
      int j = (int)(un - 568697) * 4;
      int row = j / 7040, v = j % 7040;
      ushort4 o = {0,0,0,0};
      if (v < 7000) o = f4bf(*(const float4*)&nbows[(size_t)row*7000 + v]);
      *(ushort4*)&nbbf[j] = o;
    }
    else if (un < 1948537){
      int j = (int)(un - 1244537) * 4;
      int row = j / 7040, v = j % 7040;
      ushort4 o = {0,0,0,0};
      if (v < 7000) o = f4bf(*(const float4*)&qmap_w[(size_t)row*7000 + v]);
      *(ushort4*)&qwbf[j] = o;
    }
    else if (un < 2114937){
      int j = (int)(un - 1948537) * 4;
      int row = j / 416, r = j % 416;
      ushort4 o = {0,0,0,0};
      if (r < 400) o = f4bf(*(const float4*)&wih0[(size_t)row*400 + r]);
      *(ushort4*)&w0bf[j] = o;
    }
    else if (un < 2514937){
      int j = (int)(un - 2114937) * 4;
      int row = j / 320, r = j % 320;
      ushort4 o = {0,0,0,0};
      if (r < 300) o = f4bf(*(const float4*)&rho1w[(size_t)row*300 + r]);
      *(ushort4*)&r1bf[j] = o;
    }
    else if (un < 2674937){
      int j = (int)(un - 2514937) * 4;
      int row = j / 320, r = j % 320;
      ushort4 o = {0,0,0,0};
      if (r < 300) o = f4bf(*(const float4*)&rho2w[(size_t)row*300 + r]);
      *(ushort4*)&r2bf[j] = o;
    }
    else {
      int j = (int)(un - 2674937) * 4;
      int c = j % 400;
      *(float4*)&inpf[j] = *(const float4*)&qb[c];
    }
  }
}

// ---------------- MFMA bf16 GEMM ----------------
__global__ __launch_bounds__(256) void gemm_bf16(
    const unsigned short* __restrict__ A, int lda,
    const unsigned short* __restrict__ B, int ldb,
    float* __restrict__ Cf, unsigned short* __restrict__ Cbf,
    float* __restrict__ Cacc, int ldc,
    int M, int N, int Kp, int kchunk,
    const float* __restrict__ bias, float* __restrict__ rowsum)
{
  __shared__ unsigned short As[64][40];
  __shared__ unsigned short Bs[64][40];
  __shared__ float sexp[64];
  const int tid = threadIdx.x;
  const int m0 = blockIdx.y * 64, n0 = blockIdx.x * 64;
  const int kbeg = blockIdx.z * kchunk;
  const int kend = min(Kp, kbeg + kchunk);
  const int wave = tid >> 6, lane = tid & 63;
  const int wm = (wave >> 1) * 32, wn = (wave & 1) * 32;
  const int ra = tid >> 2, ck = (tid & 3) << 3;
  const int fr = lane & 15, fo = (lane >> 4) << 3;
  if (rowsum && tid < 64) sexp[tid] = 0.f;

  f32x4 acc00 = {0.f,0.f,0.f,0.f}, acc01 = {0.f,0.f,0.f,0.f};
  f32x4 acc10 = {0.f,0.f,0.f,0.f}, acc11 = {0.f,0.f,0.f,0.f};
  int4 pa, pb;
  {
    int rA = m0 + ra, rB = n0 + ra;
    pa = (rA < M) ? *(const int4*)&A[(size_t)rA*lda + kbeg + ck] : make_int4(0,0,0,0);
    pb = (rB < N) ? *(const int4*)&B[(size_t)rB*ldb + kbeg + ck] : make_int4(0,0,0,0);
  }
  for (int k0 = kbeg; k0 < kend; k0 += 32){
    *(int4*)&As[ra][ck] = pa;
    *(int4*)&Bs[ra][ck] = pb;
    __syncthreads();
    if (k0 + 32 < kend){
      int rA = m0 + ra, rB = n0 + ra;
      pa = (rA < M) ? *(const int4*)&A[(size_t)rA*lda + k0 + 32 + ck] : make_int4(0,0,0,0);
      pb = (rB < N) ? *(const int4*)&B[(size_t)rB*ldb + k0 + 32 + ck] : make_int4(0,0,0,0);
    }
    short8v a0 = *(const short8v*)&As[wm      + fr][fo];
    short8v a1 = *(const short8v*)&As[wm + 16 + fr][fo];
    short8v b0 = *(const short8v*)&Bs[wn      + fr][fo];
    short8v b1 = *(const short8v*)&Bs[wn + 16 + fr][fo];
    acc00 = __builtin_amdgcn_mfma_f32_16x16x32_bf16(a0, b0, acc00, 0, 0, 0);
    acc01 = __builtin_amdgcn_mfma_f32_16x16x32_bf16(a0, b1, acc01, 0, 0, 0);
    acc10 = __builtin_amdgcn_mfma_f32_16x16x32_bf16(a1, b0, acc10, 0, 0, 0);
    acc11 = __builtin_amdgcn_mfma_f32_16x16x32_bf16(a1, b1, acc11, 0, 0, 0);
    __syncthreads();
  }
  const int rbase = (lane >> 4) << 2;
  auto epi = [&](f32x4 ac0, f32x4 ac1, int mi){
    #pragma unroll
    for (int reg = 0; reg < 4; ++reg){
      const int lr = wm + mi*16 + rbase + reg;
      const int gr = m0 + lr;
      float ex = 0.f;
      {
        int gc = n0 + wn + fr;
        if (gr < M && gc < N){
          if (Cacc) atomicAdd(&Cacc[(size_t)gr*ldc + gc], ac0[reg]);
          else {
            float val = ac0[reg] + (bias ? bias[gc] : 0.f);
            if (Cbf) Cbf[(size_t)gr*ldc + gc] = f2bf(val);
            else     Cf [(size_t)gr*ldc + gc] = val;
            if (rowsum) ex += __expf(val);
          }
        }
      }
      {
        int gc = n0 + wn + 16 + fr;
        if (gr < M && gc < N){
          if (Cacc) atomicAdd(&Cacc[(size_t)gr*ldc + gc], ac1[reg]);
          else {
            float val = ac1[reg] + (bias ? bias[gc] : 0.f);
            if (Cbf) Cbf[(size_t)gr*ldc + gc] = f2bf(val);
            else     Cf [(size_t)gr*ldc + gc] = val;
            if (rowsum) ex += __expf(val);
          }
        }
      }
      if (rowsum){
        ex += __shfl_xor(ex, 1); ex += __shfl_xor(ex, 2);
        ex += __shfl_xor(ex, 4); ex += __shfl_xor(ex, 8);
        if (fr == 0 && gr < M) atomicAdd(&sexp[lr], ex);
      }
    }
  };
  epi(acc00, acc01, 0);
  epi(acc10, acc11, 1);
  if (rowsum){
    __syncthreads();
    if (tid < 64 && m0 + tid < M) atomicAdd(&rowsum[m0 + tid], sexp[tid]);
  }
}

// ---------------- convert inp_f32 -> bf16 (vectorized) ----------------
__global__ void cvt_inp(const float* __restrict__ inpf, unsigned short* __restrict__ inpbf){
  int un = blockIdx.x*blockDim.x + threadIdx.x;
  if (un < 38400){
    int j = un * 4;
    int r = j / 400, c = j % 400;
    ushort4 o = f4bf(*(const float4*)&inpf[j]);
    *(ushort4*)&inpbf[r*416 + c] = o;
  }
}

// ---------------- f32 GEMM (kept for tiny muH2) ----------------
__device__ __forceinline__ float4 g4(const float* __restrict__ base, int row, int nrows,
                                     int ld, int k, int kend){
  float4 v; v.x = v.y = v.z = v.w = 0.f;
  if (row < nrows){
    const float* q = base + (size_t)row*ld + k;
    if (k + 3 < kend) v = *(const float4*)q;
  }
  return v;
}
__global__ __launch_bounds__(256) void gemm_f32(
    const float* __restrict__ A, int lda,
    const float* __restrict__ B, int ldb,
    float* __restrict__ C, int ldc,
    int M, int N, int K,
    const float* __restrict__ bias)
{
  __shared__ __align__(16) float As[16][68];
  __shared__ __align__(16) float Bs[16][68];
  const int tid = threadIdx.x;
  const int m0 = blockIdx.y * 64, n0 = blockIdx.x * 64;
  const int lm  = tid >> 2;
  const int lkq = (tid & 3) << 2;
  const int ty = tid >> 4, tx = tid & 15;
  float acc[4][4];
  #pragma unroll
  for (int i=0;i<4;++i)
    #pragma unroll
    for (int j=0;j<4;++j) acc[i][j] = 0.f;
  for (int k0 = 0; k0 < K; k0 += 16){
    float4 av = g4(A, m0+lm, M, lda, k0+lkq, K);
    float4 bv = g4(B, n0+lm, N, ldb, k0+lkq, K);
    As[lkq+0][lm]=av.x; As[lkq+1][lm]=av.y; As[lkq+2][lm]=av.z; As[lkq+3][lm]=av.w;
    Bs[lkq+0][lm]=bv.x; Bs[lkq+1][lm]=bv.y; Bs[lkq+2][lm]=bv.z; Bs[lkq+3][lm]=bv.w;
    __syncthreads();
    #pragma unroll
    for (int kk = 0; kk < 16; ++kk){
      const float4 a = *(const float4*)&As[kk][ty<<2];
      const float4 b = *(const float4*)&Bs[kk][tx<<2];
      float ar[4] = {a.x,a.y,a.z,a.w};
      float br[4] = {b.x,b.y,b.z,b.w};
      #pragma unroll
      for (int i=0;i<4;++i)
        #pragma unroll
        for (int j=0;j<4;++j) acc[i][j] = fmaf(ar[i], br[j], acc[i][j]);
    }
    __syncthreads();
  }
  const int om = m0 + (ty<<2), on = n0 + (tx<<2);
  #pragma unroll
  for (int i=0;i<4;++i)
    #pragma unroll
    for (int j=0;j<4;++j)
      if (om+i < M && on+j < N)
        C[(size_t)(om+i)*ldc + (on+j)] = acc[i][j] + (bias ? bias[on+j] : 0.f);
}

// ---------------- pipelined LSTM: layer0 step t || layer1 step t-1 ----------------
__global__ __launch_bounds__(256) void lstm_pipe(
    const float* __restrict__ X0,    const float* __restrict__ w0T,
    const float* __restrict__ wi1T,  const float* __restrict__ w1T,
    const float* __restrict__ bsum1,
    float* __restrict__ hs0, float* __restrict__ hs1,
    float* __restrict__ cst0, float* __restrict__ cst1, int step)
{
  __shared__ __align__(16) float4 hq4[100*32];
  __shared__ __align__(16) float4 red4[4][32][2];
  const int tid = threadIdx.x;
  const int rh = tid >> 6;
  const int b  = (tid & 63) >> 1;
  const int ul = tid & 1;
  const int rq0 = rh * 25;

  if (blockIdx.x < 200){
    const int t = step;
    if (t >= 12) return;
    const int U0 = blockIdx.x * 2;
    const int u = U0 + ul;
    if (t > 0){
      for (int i = tid; i < 3200; i += 256){
        int bb = i & 31, rq = i >> 5;
        hq4[rq*32 + bb] = *(const float4*)&hs0[((size_t)(bb*12 + (t-1)))*400 + rq*4];
      }
      __syncthreads();
      const float* wcol = w0T + (size_t)u*4;
      float4 acc = {0.f,0.f,0.f,0.f};
      #pragma unroll 5
      for (int rq = rq0; rq < rq0 + 25; ++rq){
        float4 h4 = hq4[rq*32 + b];
        float hr[4] = {h4.x, h4.y, h4.z, h4.w};
        #pragma unroll
        for (int dr = 0; dr < 4; ++dr){
          float4 w4 = *(const float4*)&wcol[(size_t)(rq*4 + dr)*1600];
          acc.x = fmaf(hr[dr], w4.x, acc.x);
          acc.y = fmaf(hr[dr], w4.y, acc.y);
          acc.z = fmaf(hr[dr], w4.z, acc.z);
          acc.w = fmaf(hr[dr], w4.w, acc.w);
        }
      }
      red4[rh][b][ul] = acc;
    }
    __syncthreads();
    if (tid < 64){
      const int bb = tid >> 1, uu = U0 + (tid & 1);
      float4 a = {0.f,0.f,0.f,0.f};
      if (t > 0){
        #pragma unroll
        for (int w = 0; w < 4; ++w){
          float4 r = red4[w][bb][tid & 1];
          a.x += r.x; a.y += r.y; a.z += r.z; a.w += r.w;
        }
      }
      const size_t xrow = ((size_t)bb*12 + t)*1600;
      float gi = a.x + X0[xrow          + uu];
      float gf = a.y + X0[xrow +  400   + uu];
      float gg = a.z + X0[xrow +  800   + uu];
      float go = a.w + X0[xrow + 1200   + uu];
      float ii = 1.f/(1.f + expf(-gi));
      float ff = 1.f/(1.f + expf(-gf));
      float tg = tanhf(gg);
      float oo = 1.f/(1.f + expf(-go));
      float c = (t == 0) ? 0.f : cst0[bb*400 + uu];
      c = ff*c + ii*tg;
      cst0[bb*400 + uu] = c;
      hs0[((size_t)bb*12 + t)*400 + uu] = oo * tanhf(c);
    }
  } else {
    const int t = step - 1;
    if (t < 0) return;
    const int U0 = (blockIdx.x - 200) * 2;
    const int u = U0 + ul;
    float4 acc = {0.f,0.f,0.f,0.f};
    for (int i = tid; i < 3200; i += 256){
      int bb = i & 31, rq = i >> 5;
      hq4[rq*32 + bb] = *(const float4*)&hs0[((size_t)(bb*12 + t))*400 + rq*4];
    }
    __syncthreads();
    {
      const float* wcol = wi1T + (size_t)u*4;
      #pragma unroll 5
      for (int rq = rq0; rq < rq0 + 25; ++rq){
        float4 h4 = hq4[rq*32 + b];
        float hr[4] = {h4.x, h4.y, h4.z, h4.w};
        #pragma unroll
        for (int dr = 0; dr < 4; ++dr){
          float4 w4 = *(const float4*)&wcol[(size_t)(rq*4 + dr)*1600];
          acc.x = fmaf(hr[dr], w4.x, acc.x);
          acc.y = fmaf(hr[dr], w4.y, acc.y);
          acc.z = fmaf(hr[dr], w4.z, acc.z);
          acc.w = fmaf(hr[dr], w4.w, acc.w);
        }
      }
    }
    __syncthreads();
    if (t > 0){
      for (int i = tid; i < 3200; i += 256){
        int bb = i & 31, rq = i >> 5;
        hq4[rq*32 + bb] = *(const float4*)&hs1[((size_t)(bb*12 + (t-1)))*400 + rq*4];
      }
    }
    __syncthreads();
    if (t > 0){
      const float* wcol = w1T + (size_t)u*4;
      #pragma unroll 5
      for (int rq = rq0; rq < rq0 + 25; ++rq){
        float4 h4 = hq4[rq*32 + b];
        float hr[4] = {h4.x, h4.y, h4.z, h4.w};
        #pragma unroll
        for (int dr = 0; dr < 4; ++dr){
          float4 w4 = *(const float4*)&wcol[(size_t)(rq*4 + dr)*1600];
          acc.x = fmaf(hr[dr], w4.x, acc.x);
          acc.y = fmaf(hr[dr], w4.y, acc.y);
          acc.z = fmaf(hr[dr], w4.z, acc.z);
          acc.w = fmaf(hr[dr], w4.w, acc.w);
        }
      }
    }
    red4[rh][b][ul] = acc;
    __syncthreads();
    if (tid < 64){
      const int bb = tid >> 1, uu = U0 + (tid & 1);
      float4 a = {0.f,0.f,0.f,0.f};
      #pragma unroll
      for (int w = 0; w < 4; ++w){
        float4 r = red4[w][bb][tid & 1];
        a.x += r.x; a.y += r.y; a.z += r.z; a.w += r.w;
      }
      float gi = a.x + bsum1[        uu];
      float gf = a.y + bsum1[ 400 + uu];
      float gg = a.z + bsum1[ 800 + uu];
      float go = a.w + bsum1[1200 + uu];
      float ii = 1.f/(1.f + expf(-gi));
      float ff = 1.f/(1.f + expf(-gf));
      float tg = tanhf(gg);
      float oo = 1.f/(1.f + expf(-go));
      float c = (t == 0) ? 0.f : cst1[bb*400 + uu];
      c = ff*c + ii*tg;
      cst1[bb*400 + uu] = c;
      hs1[((size_t)bb*12 + t)*400 + uu] = oo * tanhf(c);
    }
  }
}

// ---------------- theta head (4 blocks, 8 b's each) ----------------
__global__ __launch_bounds__(512) void theta_par(
    const float* __restrict__ muH2,
    const float* __restrict__ muW, const float* __restrict__ lsW,
    float* __restrict__ theta, float* __restrict__ accs)
{
  __shared__ float zsall[12][8][50];
  __shared__ float wm[50][51], wl[50][51];
  __shared__ float ktot;
  const int tid = threadIdx.x;
  const int b0 = blockIdx.x * 8;
  for (int i = tid; i < 2500; i += 512){
    int k = i / 50, j = i % 50;
    wm[k][j] = muW[k*450 + 400 + j];
    wl[k][j] = lsW[k*450 + 400 + j];
  }
  if (tid == 0) ktot = 0.f;
  __syncthreads();
  const float dd = expf(LOG_DELTA) + 1e-6f;
  for (int t = 0; t < 12; ++t){
    float kpart = 0.f;
    if (tid < 400){
      int bl = tid / 50, k = tid % 50, b = b0 + bl;
      float m = muH2[((size_t)b*12 + t)*100 + k];
      float l = muH2[((size_t)b*12 + t)*100 + 50 + k];
      float zp = 0.f;
      if (t > 0){
        zp = zsall[t-1][bl][k];
        float sm = 0.f, sl = 0.f;
        #pragma unroll 5
        for (int j = 0; j < 50; ++j){
          float z = zsall[t-1][bl][j];
          sm = fmaf(z, wm[k][j], sm);
          sl = fmaf(z, wl[k][j], sl);
        }
        m += sm; l += sl;
      }
      zsall[t][bl][k] = m;
      float denom = (t > 0) ? dd : (1.f + 1e-6f);
      float pls = (t > 0) ? LOG_DELTA : 0.f;
      float d = m - zp;
      kpart += (expf(l) + d*d)/denom - 1.f + pls - l;
    }
    kpart = wsum64(kpart);
    if ((tid & 63) == 0) atomicAdd(&ktot, 0.5f * kpart / 32.f);
    __syncthreads();
  }
  for (int rr = tid; rr < 96; rr += 512){
    int t = rr >> 3, bl = rr & 7, b = b0 + bl;
    float m = -3.0e38f;
    for (int k = 0; k < 50; ++k) m = fmaxf(m, zsall[t][bl][k]);
    float S = 0.f;
    for (int k = 0; k < 50; ++k) S += expf(zsall[t][bl][k] - m);
    float inv = 1.f/S;
    for (int k = 0; k < 50; ++k)
      theta[((size_t)t*32 + b)*50 + k] = expf(zsall[t][bl][k] - m) * inv;
  }
  if (tid == 0) atomicAdd(&accs[6], ktot);
}

// ---------------- kld_alpha ----------------
__global__ void kld_alpha_k(const float* __restrict__ qmu, const float* __restrict__ qls,
                            float* __restrict__ accs){
  const int t = blockIdx.x / 50, k = blockIdx.x % 50;
  const size_t base  = ((size_t)k*12 + t)*300;
  const size_t pbase = ((size_t)k*12 + (t-1))*300;
  const float dd  = (t > 0) ? (expf(LOG_DELTA) + 1e-6f) : (1.f + 1e-6f);
  const float pls = (t > 0) ? LOG_DELTA : 0.f;
  float s = 0.f;
  for (int r = threadIdx.x; r < 300; r += 64){
    float qm = qmu[base + r], ql = qls[base + r];
    float pm = (t > 0) ? qmu[pbase + r] : 0.f;
    float d = qm - pm;
    s += (expf(ql) + d*d)/dd - 1.f + pls - ql;
  }
  s = wsum64(s);
  if (threadIdx.x == 0) atomicAdd(&accs[7], 0.5f * s / 50.f);
}

// ---------------- pass1 v6: Taylor-exp, per-item bound, 1-round rejection ----
__global__ __launch_bounds__(256) void pass1(
    const float* __restrict__ blog, const float* __restrict__ rs,
    const float* __restrict__ theta,
    float* __restrict__ bzg,
    float* __restrict__ c1g1, float* __restrict__ c1g2,
    float* __restrict__ accs)
{
  const int t = blockIdx.y;
  const int v0 = blockIdx.x * 64;
  __shared__ float th[32][50];
  __shared__ float be[50][64];
  __shared__ float c0s[64][50];
  __shared__ unsigned int c1p[2][32][25];
  __shared__ float rlog[2][50];
  __shared__ float kred[4];
  const int tid = threadIdx.x;

  if (tid < 100){
    int p = tid / 50, k = tid % 50;
    rlog[p][k] = __logf(rs[p*600 + t*50 + k]);
  }
  float lg[13];
  #pragma unroll
  for (int j = 0; j < 13; ++j){
    int i = tid + j*256;
    lg[j] = -40.f;
    if (i < 3200){
      int k = i >> 6, vl = i & 63, v = v0 + vl;
      if (v < 7000) lg[j] = blog[((size_t)t*50 + k)*7000 + v];
    }
  }
  #pragma unroll
  for (int j = 0; j < 7; ++j){
    int i = tid + j*256;
    if (i < 1600) th[i/50][i%50] = theta[(size_t)t*1600 + i];
  }
  #pragma unroll
  for (int j = 0; j < 13; ++j){
    int i = tid + j*256;
    if (i < 3200) ((float*)c0s)[i] = 0.f;
  }
  #pragma unroll
  for (int j = 0; j < 7; ++j){
    int i = tid + j*256;
    if (i < 1600) ((unsigned int*)c1p)[i] = 0u;
  }
  if (tid < 4) kred[tid] = 0.f;
  __syncthreads();
  #pragma unroll
  for (int j = 0; j < 13; ++j){
    int i = tid + j*256;
    if (i < 3200){
      int k = i >> 6, vl = i & 63, v = v0 + vl;
      int p = (v >= 5000);
      be[k][vl] = __expf(lg[j] - rlog[p][k]);
    }
  }
  __syncthreads();

  const int b = tid >> 3, sub = tid & 7;

  float sx[8], mx[8];
  #pragma unroll
  for (int i = 0; i < 8; ++i){ sx[i] = 0.f; mx[i] = 0.f; }
  for (int k = 0; k < 50; ++k){
    float tk = th[b][k];
    #pragma unroll
    for (int i = 0; i < 8; ++i){
      float x = tk * be[k][sub + 8*i];
      sx[i] += x;
      mx[i] = fmaxf(mx[i], x);
    }
  }
  float inv[8], lS1[8], bnd[8];
  #pragma unroll
  for (int i = 0; i < 8; ++i){
    inv[i] = 1.f / (50.f + sx[i]);
    lS1[i] = LOG50 + sx[i] * 0.02f;
    bnd[i] = (1.f + mx[i]) * inv[i];
  }

  int ks[8]; float xs[8];
  unsigned fmask = 0;
  const int vbase = (t*32 + b)*7000 + v0 + sub;
  #pragma unroll
  for (int i = 0; i < 8; ++i){
    ks[i] = 0; xs[i] = 0.f;
    if (v0 + sub + 8*i >= 7000) fmask |= 1u << i;
  }
  int round = 0;
  while (true){
    const unsigned roff = (unsigned)round * 0x9E3779B9u;
    #pragma unroll
    for (int i = 0; i < 8; ++i){
      if (!((fmask >> i) & 1u)){
        const unsigned bse = (unsigned)(vbase + 8*i) * 2u;
        float u1 = u01(bse + roff);
        float u2 = u01(bse + 1u + roff);
        int kp = min((int)(u1 * 50.f), 49);
        float x  = th[b][kp] * be[kp][sub + 8*i];
        float pi = (1.f + x) * inv[i];
        float y  = pi - bnd[i];
        float ap = 1.f + y + 0.5f*y*y;
        if (u2 <= ap || round >= 7){
          ks[i] = kp; xs[i] = x; fmask |= 1u << i;
        }
      }
    }
    ++round;
    if (__all(fmask == 255u)) break;
  }

  float kA1 = 0.f, kB1 = 0.f, kA2 = 0.f, kB2 = 0.f;
  #pragma unroll
  for (int i = 0; i < 8; ++i){
    const int vl = sub + 8*i, v = v0 + vl;
    if (v < 7000){
      float pis  = (1.f + xs[i]) * inv[i];
      float lpis = xs[i] - lS1[i];
      float lt   = __logf(th[b][ks[i]]);
      if (v >= 5000){ kA2 += lt; kB2 += pis*lpis; }
      else          { kA1 += lt; kB1 += pis*lpis; }
      atomicAdd(&c0s[vl][ks[i]], 1.f);
      atomicAdd(&c1p[(v >= 5000) ? 1 : 0][b][ks[i] >> 1],
                (ks[i] & 1) ? 65536u : 1u);
    }
  }
  kA1 = wsum64(kA1); kB1 = wsum64(kB1); kA2 = wsum64(kA2); kB2 = wsum64(kB2);
  if ((tid & 63) == 0){
    atomicAdd(&kred[0], kA1); atomicAdd(&kred[1], kB1);
    atomicAdd(&kred[2], kA2); atomicAdd(&kred[3], kB2);
  }
  __syncthreads();
  #pragma unroll
  for (int j = 0; j < 13; ++j){
    int i = tid + j*256;
    if (i < 3200){
      int k = i >> 6, vl = i & 63, v = v0 + vl;
      if (v < 7000)
        bzg[(size_t)t*350000 + (size_t)k*7000 + v] = be[k][vl] * c0s[vl][k] * (1.f/32.f);
    }
  }
  for (int i = tid; i < 1600; i += 256){
    int b2 = i / 50, k2 = i % 50;
    unsigned w1 = c1p[0][b2][k2 >> 1];
    unsigned w2 = c1p[1][b2][k2 >> 1];
    unsigned cnt1 = (k2 & 1) ? (w1 >> 16) : (w1 & 0xFFFFu);
    unsigned cnt2 = (k2 & 1) ? (w2 >> 16) : (w2 & 0xFFFFu);
    if (cnt1) atomicAdd(&c1g1[(size_t)t*1600 + i], (float)cnt1);
    if (cnt2) atomicAdd(&c1g2[(size_t)t*1600 + i], (float)cnt2);
  }
  if (tid < 4) atomicAdd(&accs[tid], kred[tid]);
}

// ---------------- pass2: log-likelihood ----------------
__global__ __launch_bounds__(256) void pass2(
    const float* __restrict__ bzg, const float* __restrict__ theta,
    const float* __restrict__ c1g1, const float* __restrict__ c1g2,
    const float* __restrict__ bows, float* __restrict__ accs)
{
  const int t = blockIdx.y, v0 = blockIdx.x * 64;
  __shared__ float tz[2][32][50];
  __shared__ float bzs[50][64];
  __shared__ float sr[2];
  const int tid = threadIdx.x;
  if (tid < 2) sr[tid] = 0.f;
  for (int i = tid; i < 1600; i += 256){
    int b = i / 50, k = i % 50;
    float th_ = theta[(size_t)t*1600 + i];
    tz[0][b][k] = th_ * c1g1[(size_t)t*1600 + i] * (1.f/5000.f);
    tz[1][b][k] = th_ * c1g2[(size_t)t*1600 + i] * (1.f/2000.f);
  }
  for (int i = tid; i < 3200; i += 256){
    int k = i >> 6, vl = i & 63, v = v0 + vl;
    bzs[k][vl] = (v < 7000) ? bzg[(size_t)t*350000 + (size_t)k*7000 + v] : 0.f;
  }
  __syncthreads();

  const int b = tid >> 3, sub = tid & 7;
  int part[8];
  #pragma unroll
  for (int i = 0; i < 8; ++i) part[i] = (v0 + sub + 8*i >= 5000);
  float dot[8];
  #pragma unroll
  for (int i = 0; i < 8; ++i) dot[i] = 0.f;
  for (int k = 0; k < 50; ++k){
    float t0 = tz[0][b][k], t1 = tz[1][b][k];
    #pragma unroll
    for (int i = 0; i < 8; ++i)
      dot[i] = fmaf(part[i] ? t1 : t0, bzs[k][sub + 8*i], dot[i]);
  }
  float s1 = 0.f, s2 = 0.f;
  #pragma unroll
  for (int i = 0; i < 8; ++i){
    const int v = v0 + sub + 8*i;
    if (v < 7000){
      const float w = bows[((size_t)b*12 + t)*7000 + v];
      const float l = __logf(dot[i]) * w;
      if (part[i]) s2 += l; else s1 += l;
    }
  }
  s1 = wsum64(s1); s2 = wsum64(s2);
  if ((tid & 63) == 0){ atomicAdd(&sr[0], s1); atomicAdd(&sr[1], s2); }
  __syncthreads();
  if (tid < 2) atomicAdd(&accs[4 + tid], sr[tid]);
}

// ---------------- finalize ----------------
__global__ void finalize_k(const float* __restrict__ accs, float* __restrict__ out){
  if (threadIdx.x == 0 && blockIdx.x == 0){
    out[0] = -(accs[4] + accs[5]) * (1.f/32.f);
    out[1] = accs[6];
    out[2] = -accs[0]/(32.f*5000.f) - accs[1]/32.f;
    out[3] = -accs[2]/(32.f*2000.f) - accs[3]/32.f;
    out[4] = accs[7];
  }
}

// ---------------- host launcher ----------------
extern "C" void kernel_launch(void* const* d_in, const int* in_sizes, int n_in,
                              void* d_out, int out_size, void* d_ws, size_t ws_size,
                              hipStream_t stream)
{
  const float* bows   = (const float*)d_in[0];
  const float* nbows  = (const float*)d_in[1];
  const float* qmap_w = (const float*)d_in[2];
  const float* qmap_b = (const float*)d_in[3];
  const float* wih0   = (const float*)d_in[4];
  const float* whh0   = (const float*)d_in[5];
  const float* bih0   = (const float*)d_in[6];
  const float* bhh0   = (const float*)d_in[7];
  const float* wih1   = (const float*)d_in[8];
  const float* whh1   = (const float*)d_in[9];
  const float* bih1   = (const float*)d_in[10];
  const float* bhh1   = (const float*)d_in[11];
  const float* muW    = (const float*)d_in[12];
  const float* muB    = (const float*)d_in[13];
  const float* lsW    = (const float*)d_in[14];
  const float* lsB    = (const float*)d_in[15];
  const float* qmu    = (const float*)d_in[16];
  const float* qlsa   = (const float*)d_in[17];
  const float* rho1w  = (const float*)d_in[18];
  const float* rho1b  = (const float*)d_in[19];
  const float* rho2w  = (const float*)d_in[20];
  const float* rho2b  = (const float*)d_in[21];

  float* ws  = (float*)d_ws;
  float* out = (float*)d_out;

  float* c1g1  = ws + OFF_C1G1;
  float* c1g2  = ws + OFF_C1G2;
  float* accs  = ws + OFF_ACCS;
  float* bzg   = ws + OFF_C0G;
  float* beta  = ws + OFF_BETA;
  float* inpf  = ws + OFF_ALPHAT;
  float* X0    = ws + OFF_X0;
  float* hs0   = ws + OFF_OUT0;
  float* hs1   = ws + OFF_OUT1;
  float* cst0  = ws + OFF_CST;
  float* cst1  = ws + OFF_CST1;
  float* muH2  = ws + OFF_MUH;
  float* theta = ws + OFF_THETA;
  float* muW4  = ws + OFF_MUW4;
  float* bsum0 = ws + OFF_LTH;
  float* bsum1 = ws + OFF_LTH + 1600;
  float* mlb   = ws + OFF_LTH + 3200;
  float* rs    = ws + OFF_RS;
  unsigned short* nbbf  = (unsigned short*)(ws + OFF_NBBF);
  unsigned short* qwbf  = (unsigned short*)(ws + OFF_QWBF);
  unsigned short* inpbf = (unsigned short*)(ws + OFF_INP);
  unsigned short* w0bf  = (unsigned short*)(ws + OFF_W0BF);
  unsigned short* albf  = (unsigned short*)(ws + OFF_ALBF);
  unsigned short* r1bf  = (unsigned short*)(ws + OFF_R1BF);
  unsigned short* r2bf  = (unsigned short*)(ws + OFF_R2BF);
  float* w0T  = ws + OFF_W0T;
  float* w1T  = ws + OFF_W1T;
  float* wi1T = ws + OFF_WIH1T;

  prep_misc<<<2048, 256, 0, stream>>>(ws, muW, lsW, qmu, bih0, bhh0, bih1, bhh1,
                                      muB, lsB, qmap_b, whh0, whh1, wih1,
                                      nbows, qmap_w, wih0, rho1w, rho2w);
  kld_alpha_k<<<600, 64, 0, stream>>>(qmu, qlsa, accs);

  // inp_f32 += nbows_bf @ qmap_w_bf^T  (split-K x10; bias pre-init'd in prep)
  gemm_bf16<<<dim3(7,6,10), 256, 0, stream>>>(nbbf, 7040, qwbf, 7040,
                                              nullptr, nullptr, inpf, 400,
                                              384, 400, 7040, 704, nullptr, nullptr);
  cvt_inp<<<150, 256, 0, stream>>>(inpf, inpbf);

  // X0 = inp_bf @ wih0^T + (bih0+bhh0)     M=384 N=1600 Kp=416
  gemm_bf16<<<dim3(25,6,1), 256, 0, stream>>>(inpbf, 416, w0bf, 416,
                                              X0, nullptr, nullptr, 1600,
                                              384, 1600, 416, 416, bsum0, nullptr);
  // pipelined double-layer LSTM: 13 launches
  for (int i = 0; i < 13; ++i)
    lstm_pipe<<<400, 256, 0, stream>>>(X0, w0T, wi1T, w1T, bsum1,
                                       hs0, hs1, cst0, cst1, i);

  // muH2 = hs1 @ [muW4;lsW4]^T + [muB;lsB]
  gemm_f32<<<dim3(2,6), 256, 0, stream>>>(hs1, 400, muW4, 400, muH2, 100,
                                          384, 100, 400, mlb);
  theta_par<<<4, 512, 0, stream>>>(muH2, muW, lsW, theta, accs);

  // beta logits via MFMA + fused row sum(exp)
  gemm_bf16<<<dim3(79,10,1), 256, 0, stream>>>(albf, 320, r1bf, 320,
                                               beta, nullptr, nullptr, 7000,
                                               600, 5000, 320, 320, rho1b, rs);
  gemm_bf16<<<dim3(32,10,1), 256, 0, stream>>>(albf, 320, r2bf, 320,
                                               beta + 5000, nullptr, nullptr, 7000,
                                               600, 2000, 320, 320, rho2b, rs + 600);

  pass1<<<dim3(110,12), 256, 0, stream>>>(beta, rs, theta, bzg, c1g1, c1g2, accs);
  pass2<<<dim3(110,12), 256, 0, stream>>>(bzg, theta, c1g1, c1g2, bows, accs);

  finalize_k<<<1, 64, 0, stream>>>(accs, out);
}

// Round 12
// 433.710 us; speedup vs baseline: 1.9542x; 1.0202x over previous
//
#include <hip/hip_runtime.h>

// ---------------- constants ----------------
#define LOG_DELTA (-5.2983174f)   // ln(0.005)
#define LOG50     (3.9120230054f) // ln(50)

typedef __attribute__((ext_vector_type(8))) short short8v;
typedef __attribute__((ext_vector_type(4))) float f32x4;

// ws layout (float offsets)
constexpr size_t OFF_C1G1  = 0;                       // [12][32][50]
constexpr size_t OFF_C1G2  = 19200;                   // [12][32][50]
constexpr size_t OFF_ACCS  = 38400;                   // [16]
constexpr size_t OFF_C0G   = 38416;                   // bzg [12][50][7000]
constexpr size_t OFF_BETA  = OFF_C0G  + 4200000;      // [600][7000] logits
constexpr size_t OFF_ALPHAT= OFF_BETA + 4200000;      // inp_f32 [384][400]
constexpr size_t OFF_INP   = OFF_ALPHAT + 180000;     // inp_bf ushort[384][416]
constexpr size_t OFF_X0    = OFF_INP  + 153600;       // [384][1600]
constexpr size_t OFF_OUT0  = OFF_X0   + 614400;       // hs0 [384][400]
constexpr size_t OFF_X1    = OFF_OUT0 + 153600;       // cst1|albf|r2bf region
constexpr size_t OFF_OUT1  = OFF_X1   + 614400;       // hs1 [384][400]
constexpr size_t OFF_CST   = OFF_OUT1 + 153600;       // cst0 [32][400]
constexpr size_t OFF_MUH   = OFF_CST  + 12800;        // [384][100]
constexpr size_t OFF_THETA = OFF_MUH  + 38400;        // [12][32][50]
constexpr size_t OFF_LTH   = OFF_THETA+ 19200;        // bsum0|bsum1|mlb|rs
constexpr size_t OFF_MUW4  = OFF_LTH  + 19200;        // [50][400]
constexpr size_t OFF_LSW4  = OFF_MUW4 + 20000;        // [50][400]
constexpr size_t OFF_RS    = OFF_LTH  + 3300;         // rowsum [2][600]
// overlay in bzg region (dead before pass1):
constexpr size_t OFF_W0T   = OFF_C0G;                 // f32 [400][1600]
constexpr size_t OFF_W1T   = OFF_C0G + 640000;        // f32 [400][1600]
constexpr size_t OFF_WIH1T = OFF_C0G + 1280000;       // f32 [400][1600]
constexpr size_t OFF_NBBF  = OFF_C0G + 1920000;       // ushort[384][7040]
constexpr size_t OFF_R1BF  = OFF_C0G + 3271680;       // ushort[5000][320]
// overlay in beta region (dead before beta GEMMs):
constexpr size_t OFF_QWBF  = OFF_BETA;                // ushort[400][7040]
constexpr size_t OFF_W0BF  = OFF_BETA + 1408000;      // ushort[1600][416]
// overlay in X1 region (X1 eliminated):
constexpr size_t OFF_CST1  = OFF_X1;                  // f32 [32][400]
constexpr size_t OFF_ALBF  = OFF_X1 + 12800;          // ushort[600][320]
constexpr size_t OFF_R2BF  = OFF_X1 + 108800;         // ushort[2000][320]

// ---------------- helpers ----------------
__device__ __forceinline__ float wsum64(float x){
  #pragma unroll
  for (int o = 32; o; o >>= 1) x += __shfl_down(x, o);
  return x;
}
__device__ __forceinline__ float u01(unsigned int x){
  x ^= x >> 16; x *= 0x7feb352dU;
  x ^= x >> 15; x *= 0x846ca68bU;
  x ^= x >> 16;
  return ((float)x + 0.5f) * (1.0f/4294967296.0f);
}
__device__ __forceinline__ unsigned short f2bf(float x){
  unsigned int u = __float_as_uint(x);
  u += 0x7FFFu + ((u >> 16) & 1u);
  return (unsigned short)(u >> 16);
}
__device__ __forceinline__ ushort4 f4bf(float4 v){
  ushort4 r;
  r.x = f2bf(v.x); r.y = f2bf(v.y); r.z = f2bf(v.z); r.w = f2bf(v.w);
  return r;
}

// ---------------- fused prep (vectorized) ----------------
__global__ void prep_misc(float* __restrict__ ws,
    const float* __restrict__ muW, const float* __restrict__ lsW,
    const float* __restrict__ qmu,
    const float* __restrict__ bi0, const float* __restrict__ bh0,
    const float* __restrict__ bi1, const float* __restrict__ bh1,
    const float* __restrict__ mb,  const float* __restrict__ lb,
    const float* __restrict__ qb,
    const float* __restrict__ whh0, const float* __restrict__ whh1,
    const float* __restrict__ wih1,
    const float* __restrict__ nbows, const float* __restrict__ qmap_w,
    const float* __restrict__ wih0,
    const float* __restrict__ rho1w, const float* __restrict__ rho2w)
{
  float* zbase = ws + OFF_C1G1;
  float* muW4  = ws + OFF_MUW4;
  float* lsW4  = ws + OFF_LSW4;
  unsigned short* albf = (unsigned short*)(ws + OFF_ALBF);
  float* bsum0 = ws + OFF_LTH;
  float* bsum1 = ws + OFF_LTH + 1600;
  float* mlb   = ws + OFF_LTH + 3200;
  float* rs    = ws + OFF_RS;
  unsigned int* inbz = (unsigned int*)(ws + OFF_INP);
  float* inpf  = ws + OFF_ALPHAT;
  float* w0T   = ws + OFF_W0T;
  float* w1T   = ws + OFF_W1T;
  float* wi1T  = ws + OFF_WIH1T;
  unsigned short* nbbf = (unsigned short*)(ws + OFF_NBBF);
  unsigned short* qwbf = (unsigned short*)(ws + OFF_QWBF);
  unsigned short* w0bf = (unsigned short*)(ws + OFF_W0BF);
  unsigned short* r1bf = (unsigned short*)(ws + OFF_R1BF);
  unsigned short* r2bf = (unsigned short*)(ws + OFF_R2BF);
  const float4 z4 = {0.f, 0.f, 0.f, 0.f};

  for (long long un = blockIdx.x*blockDim.x + threadIdx.x; un < 2713337LL;
       un += (long long)gridDim.x*blockDim.x){
    if (un < 9604){
      int j = (int)un * 4;
      if (j + 3 < 38416) *(float4*)&zbase[j] = z4;
      else { for (int q = 0; q < 4 && j+q < 38416; ++q) zbase[j+q] = 0.f; }
    }
    else if (un < 14604){
      int j = (int)(un - 9604) * 4;
      int k = j / 400, c = j % 400;
      const float* s = &muW[k*450 + c];
      float4 v = {s[0], s[1], s[2], s[3]};
      *(float4*)&muW4[j] = v;
    }
    else if (un < 19604){
      int j = (int)(un - 14604) * 4;
      int k = j / 400, c = j % 400;
      const float* s = &lsW[k*450 + c];
      float4 v = {s[0], s[1], s[2], s[3]};
      *(float4*)&lsW4[j] = v;
    }
    else if (un < 67604){
      int j = (int)(un - 19604) * 4;
      int m = j / 320, r = j % 320;
      int t = m / 50, k = m % 50;
      ushort4 o = {0,0,0,0};
      if (r < 300) o = f4bf(*(const float4*)&qmu[((size_t)k*12 + t)*300 + r]);
      *(ushort4*)&albf[j] = o;
    }
    else if (un < 68004){
      int j = (int)(un - 67604) * 4;
      float4 a = *(const float4*)&bi0[j], b = *(const float4*)&bh0[j];
      float4 v = {a.x+b.x, a.y+b.y, a.z+b.z, a.w+b.w};
      *(float4*)&bsum0[j] = v;
    }
    else if (un < 68404){
      int j = (int)(un - 68004) * 4;
      float4 a = *(const float4*)&bi1[j], b = *(const float4*)&bh1[j];
      float4 v = {a.x+b.x, a.y+b.y, a.z+b.z, a.w+b.w};
      *(float4*)&bsum1[j] = v;
    }
    else if (un < 68429){
      int j = (int)(un - 68404) * 4;
      #pragma unroll
      for (int q = 0; q < 4; ++q){
        int jj = j + q;
        mlb[jj] = (jj < 50) ? mb[jj] : lb[jj-50];
      }
    }
    else if (un < 68729){
      int j = (int)(un - 68429) * 4;
      *(float4*)&rs[j] = z4;
    }
    else if (un < 88697){
      int j = (int)(un - 68729) * 4;
      *(uint4*)&inbz[j] = make_uint4(0u,0u,0u,0u);
    }
    else if (un < 568697){
      long long rel = un - 88697;
      int half = (int)(rel / 160000);
      int j = (int)(rel % 160000) * 4;
      int r = j / 1600, c = j % 1600;
      int u = c >> 2;
      const float* src = (half == 0) ? whh0 : (half == 1) ? whh1 : wih1;
      float* dst = (half == 0) ? w0T : (half == 1) ? w1T : wi1T;
      float4 v = { src[((size_t)(0*400 + u))*400 + r],
                   src[((size_t)(1*400 + u))*400 + r],
                   src[((size_t)(2*400 + u))*400 + r],
                   src[((size_t)(3*400 + u))*400 + r] };
      *(float4*)&dst[j] = v;
    }
    else if (un < 1244537){
      int j = (int)(un - 568697) * 4;
      int row = j / 7040, v = j % 7040;
      ushort4 o = {0,0,0,0};
      if (v < 7000) o = f4bf(*(const float4*)&nbows[(size_t)row*7000 + v]);
      *(ushort4*)&nbbf[j] = o;
    }
    else if (un < 1948537){
      int j = (int)(un - 1244537) * 4;
      int row = j / 7040, v = j % 7040;
      ushort4 o = {0,0,0,0};
      if (v < 7000) o = f4bf(*(const float4*)&qmap_w[(size_t)row*7000 + v]);
      *(ushort4*)&qwbf[j] = o;
    }
    else if (un < 2114937){
      int j = (int)(un - 1948537) * 4;
      int row = j / 416, r = j % 416;
      ushort4 o = {0,0,0,0};
      if (r < 400) o = f4bf(*(const float4*)&wih0[(size_t)row*400 + r]);
      *(ushort4*)&w0bf[j] = o;
    }
    else if (un < 2514937){
      int j = (int)(un - 2114937) * 4;
      int row = j / 320, r = j % 320;
      ushort4 o = {0,0,0,0};
      if (r < 300) o = f4bf(*(const float4*)&rho1w[(size_t)row*300 + r]);
      *(ushort4*)&r1bf[j] = o;
    }
    else if (un < 2674937){
      int j = (int)(un - 2514937) * 4;
      int row = j / 320, r = j % 320;
      ushort4 o = {0,0,0,0};
      if (r < 300) o = f4bf(*(const float4*)&rho2w[(size_t)row*300 + r]);
      *(ushort4*)&r2bf[j] = o;
    }
    else {
      int j = (int)(un - 2674937) * 4;
      int c = j % 400;
      *(float4*)&inpf[j] = *(const float4*)&qb[c];
    }
  }
}

// ---------------- MFMA bf16 GEMM ----------------
__global__ __launch_bounds__(256) void gemm_bf16(
    const unsigned short* __restrict__ A, int lda,
    const unsigned short* __restrict__ B, int ldb,
    float* __restrict__ Cf, unsigned short* __restrict__ Cbf,
    float* __restrict__ Cacc, int ldc,
    int M, int N, int Kp, int kchunk,
    const float* __restrict__ bias, float* __restrict__ rowsum)
{
  __shared__ unsigned short As[64][40];
  __shared__ unsigned short Bs[64][40];
  __shared__ float sexp[64];
  const int tid = threadIdx.x;
  const int m0 = blockIdx.y * 64, n0 = blockIdx.x * 64;
  const int kbeg = blockIdx.z * kchunk;
  const int kend = min(Kp, kbeg + kchunk);
  const int wave = tid >> 6, lane = tid & 63;
  const int wm = (wave >> 1) * 32, wn = (wave & 1) * 32;
  const int ra = tid >> 2, ck = (tid & 3) << 3;
  const int fr = lane & 15, fo = (lane >> 4) << 3;
  if (rowsum && tid < 64) sexp[tid] = 0.f;

  f32x4 acc00 = {0.f,0.f,0.f,0.f}, acc01 = {0.f,0.f,0.f,0.f};
  f32x4 acc10 = {0.f,0.f,0.f,0.f}, acc11 = {0.f,0.f,0.f,0.f};
  int4 pa, pb;
  {
    int rA = m0 + ra, rB = n0 + ra;
    pa = (rA < M) ? *(const int4*)&A[(size_t)rA*lda + kbeg + ck] : make_int4(0,0,0,0);
    pb = (rB < N) ? *(const int4*)&B[(size_t)rB*ldb + kbeg + ck] : make_int4(0,0,0,0);
  }
  for (int k0 = kbeg; k0 < kend; k0 += 32){
    *(int4*)&As[ra][ck] = pa;
    *(int4*)&Bs[ra][ck] = pb;
    __syncthreads();
    if (k0 + 32 < kend){
      int rA = m0 + ra, rB = n0 + ra;
      pa = (rA < M) ? *(const int4*)&A[(size_t)rA*lda + k0 + 32 + ck] : make_int4(0,0,0,0);
      pb = (rB < N) ? *(const int4*)&B[(size_t)rB*ldb + k0 + 32 + ck] : make_int4(0,0,0,0);
    }
    short8v a0 = *(const short8v*)&As[wm      + fr][fo];
    short8v a1 = *(const short8v*)&As[wm + 16 + fr][fo];
    short8v b0 = *(const short8v*)&Bs[wn      + fr][fo];
    short8v b1 = *(const short8v*)&Bs[wn + 16 + fr][fo];
    acc00 = __builtin_amdgcn_mfma_f32_16x16x32_bf16(a0, b0, acc00, 0, 0, 0);
    acc01 = __builtin_amdgcn_mfma_f32_16x16x32_bf16(a0, b1, acc01, 0, 0, 0);
    acc10 = __builtin_amdgcn_mfma_f32_16x16x32_bf16(a1, b0, acc10, 0, 0, 0);
    acc11 = __builtin_amdgcn_mfma_f32_16x16x32_bf16(a1, b1, acc11, 0, 0, 0);
    __syncthreads();
  }
  const int rbase = (lane >> 4) << 2;
  auto epi = [&](f32x4 ac0, f32x4 ac1, int mi){
    #pragma unroll
    for (int reg = 0; reg < 4; ++reg){
      const int lr = wm + mi*16 + rbase + reg;
      const int gr = m0 + lr;
      float ex = 0.f;
      {
        int gc = n0 + wn + fr;
        if (gr < M && gc < N){
          if (Cacc) atomicAdd(&Cacc[(size_t)gr*ldc + gc], ac0[reg]);
          else {
            float val = ac0[reg] + (bias ? bias[gc] : 0.f);
            if (Cbf) Cbf[(size_t)gr*ldc + gc] = f2bf(val);
            else     Cf [(size_t)gr*ldc + gc] = val;
            if (rowsum) ex += __expf(val);
          }
        }
      }
      {
        int gc = n0 + wn + 16 + fr;
        if (gr < M && gc < N){
          if (Cacc) atomicAdd(&Cacc[(size_t)gr*ldc + gc], ac1[reg]);
          else {
            float val = ac1[reg] + (bias ? bias[gc] : 0.f);
            if (Cbf) Cbf[(size_t)gr*ldc + gc] = f2bf(val);
            else     Cf [(size_t)gr*ldc + gc] = val;
            if (rowsum) ex += __expf(val);
          }
        }
      }
      if (rowsum){
        ex += __shfl_xor(ex, 1); ex += __shfl_xor(ex, 2);
        ex += __shfl_xor(ex, 4); ex += __shfl_xor(ex, 8);
        if (fr == 0 && gr < M) atomicAdd(&sexp[lr], ex);
      }
    }
  };
  epi(acc00, acc01, 0);
  epi(acc10, acc11, 1);
  if (rowsum){
    __syncthreads();
    if (tid < 64 && m0 + tid < M) atomicAdd(&rowsum[m0 + tid], sexp[tid]);
  }
}

// ---------------- convert inp_f32 -> bf16 (vectorized) ----------------
__global__ void cvt_inp(const float* __restrict__ inpf, unsigned short* __restrict__ inpbf){
  int un = blockIdx.x*blockDim.x + threadIdx.x;
  if (un < 38400){
    int j = un * 4;
    int r = j / 400, c = j % 400;
    ushort4 o = f4bf(*(const float4*)&inpf[j]);
    *(ushort4*)&inpbf[r*416 + c] = o;
  }
}

// ---------------- f32 GEMM (kept for tiny muH2) ----------------
__device__ __forceinline__ float4 g4(const float* __restrict__ base, int row, int nrows,
                                     int ld, int k, int kend){
  float4 v; v.x = v.y = v.z = v.w = 0.f;
  if (row < nrows){
    const float* q = base + (size_t)row*ld + k;
    if (k + 3 < kend) v = *(const float4*)q;
  }
  return v;
}
__global__ __launch_bounds__(256) void gemm_f32(
    const float* __restrict__ A, int lda,
    const float* __restrict__ B, int ldb,
    float* __restrict__ C, int ldc,
    int M, int N, int K,
    const float* __restrict__ bias)
{
  __shared__ __align__(16) float As[16][68];
  __shared__ __align__(16) float Bs[16][68];
  const int tid = threadIdx.x;
  const int m0 = blockIdx.y * 64, n0 = blockIdx.x * 64;
  const int lm  = tid >> 2;
  const int lkq = (tid & 3) << 2;
  const int ty = tid >> 4, tx = tid & 15;
  float acc[4][4];
  #pragma unroll
  for (int i=0;i<4;++i)
    #pragma unroll
    for (int j=0;j<4;++j) acc[i][j] = 0.f;
  for (int k0 = 0; k0 < K; k0 += 16){
    float4 av = g4(A, m0+lm, M, lda, k0+lkq, K);
    float4 bv = g4(B, n0+lm, N, ldb, k0+lkq, K);
    As[lkq+0][lm]=av.x; As[lkq+1][lm]=av.y; As[lkq+2][lm]=av.z; As[lkq+3][lm]=av.w;
    Bs[lkq+0][lm]=bv.x; Bs[lkq+1][lm]=bv.y; Bs[lkq+2][lm]=bv.z; Bs[lkq+3][lm]=bv.w;
    __syncthreads();
    #pragma unroll
    for (int kk = 0; kk < 16; ++kk){
      const float4 a = *(const float4*)&As[kk][ty<<2];
      const float4 b = *(const float4*)&Bs[kk][tx<<2];
      float ar[4] = {a.x,a.y,a.z,a.w};
      float br[4] = {b.x,b.y,b.z,b.w};
      #pragma unroll
      for (int i=0;i<4;++i)
        #pragma unroll
        for (int j=0;j<4;++j) acc[i][j] = fmaf(ar[i], br[j], acc[i][j]);
    }
    __syncthreads();
  }
  const int om = m0 + (ty<<2), on = n0 + (tx<<2);
  #pragma unroll
  for (int i=0;i<4;++i)
    #pragma unroll
    for (int j=0;j<4;++j)
      if (om+i < M && on+j < N)
        C[(size_t)(om+i)*ldc + (on+j)] = acc[i][j] + (bias ? bias[on+j] : 0.f);
}

// ---------------- pipelined LSTM: layer0 step t || layer1 step t-1 ----------------
__global__ __launch_bounds__(256) void lstm_pipe(
    const float* __restrict__ X0,    const float* __restrict__ w0T,
    const float* __restrict__ wi1T,  const float* __restrict__ w1T,
    const float* __restrict__ bsum1,
    float* __restrict__ hs0, float* __restrict__ hs1,
    float* __restrict__ cst0, float* __restrict__ cst1, int step)
{
  __shared__ __align__(16) float4 hq4[100*32];
  __shared__ __align__(16) float4 red4[4][32][2];
  const int tid = threadIdx.x;
  const int rh = tid >> 6;
  const int b  = (tid & 63) >> 1;
  const int ul = tid & 1;
  const int rq0 = rh * 25;

  if (blockIdx.x < 200){
    const int t = step;
    if (t >= 12) return;
    const int U0 = blockIdx.x * 2;
    const int u = U0 + ul;
    if (t > 0){
      for (int i = tid; i < 3200; i += 256){
        int bb = i & 31, rq = i >> 5;
        hq4[rq*32 + bb] = *(const float4*)&hs0[((size_t)(bb*12 + (t-1)))*400 + rq*4];
      }
      __syncthreads();
      const float* wcol = w0T + (size_t)u*4;
      float4 acc = {0.f,0.f,0.f,0.f};
      #pragma unroll 5
      for (int rq = rq0; rq < rq0 + 25; ++rq){
        float4 h4 = hq4[rq*32 + b];
        float hr[4] = {h4.x, h4.y, h4.z, h4.w};
        #pragma unroll
        for (int dr = 0; dr < 4; ++dr){
          float4 w4 = *(const float4*)&wcol[(size_t)(rq*4 + dr)*1600];
          acc.x = fmaf(hr[dr], w4.x, acc.x);
          acc.y = fmaf(hr[dr], w4.y, acc.y);
          acc.z = fmaf(hr[dr], w4.z, acc.z);
          acc.w = fmaf(hr[dr], w4.w, acc.w);
        }
      }
      red4[rh][b][ul] = acc;
    }
    __syncthreads();
    if (tid < 64){
      const int bb = tid >> 1, uu = U0 + (tid & 1);
      float4 a = {0.f,0.f,0.f,0.f};
      if (t > 0){
        #pragma unroll
        for (int w = 0; w < 4; ++w){
          float4 r = red4[w][bb][tid & 1];
          a.x += r.x; a.y += r.y; a.z += r.z; a.w += r.w;
        }
      }
      const size_t xrow = ((size_t)bb*12 + t)*1600;
      float gi = a.x + X0[xrow          + uu];
      float gf = a.y + X0[xrow +  400   + uu];
      float gg = a.z + X0[xrow +  800   + uu];
      float go = a.w + X0[xrow + 1200   + uu];
      float ii = 1.f/(1.f + expf(-gi));
      float ff = 1.f/(1.f + expf(-gf));
      float tg = tanhf(gg);
      float oo = 1.f/(1.f + expf(-go));
      float c = (t == 0) ? 0.f : cst0[bb*400 + uu];
      c = ff*c + ii*tg;
      cst0[bb*400 + uu] = c;
      hs0[((size_t)bb*12 + t)*400 + uu] = oo * tanhf(c);
    }
  } else {
    const int t = step - 1;
    if (t < 0) return;
    const int U0 = (blockIdx.x - 200) * 2;
    const int u = U0 + ul;
    float4 acc = {0.f,0.f,0.f,0.f};
    for (int i = tid; i < 3200; i += 256){
      int bb = i & 31, rq = i >> 5;
      hq4[rq*32 + bb] = *(const float4*)&hs0[((size_t)(bb*12 + t))*400 + rq*4];
    }
    __syncthreads();
    {
      const float* wcol = wi1T + (size_t)u*4;
      #pragma unroll 5
      for (int rq = rq0; rq < rq0 + 25; ++rq){
        float4 h4 = hq4[rq*32 + b];
        float hr[4] = {h4.x, h4.y, h4.z, h4.w};
        #pragma unroll
        for (int dr = 0; dr < 4; ++dr){
          float4 w4 = *(const float4*)&wcol[(size_t)(rq*4 + dr)*1600];
          acc.x = fmaf(hr[dr], w4.x, acc.x);
          acc.y = fmaf(hr[dr], w4.y, acc.y);
          acc.z = fmaf(hr[dr], w4.z, acc.z);
          acc.w = fmaf(hr[dr], w4.w, acc.w);
        }
      }
    }
    __syncthreads();
    if (t > 0){
      for (int i = tid; i < 3200; i += 256){
        int bb = i & 31, rq = i >> 5;
        hq4[rq*32 + bb] = *(const float4*)&hs1[((size_t)(bb*12 + (t-1)))*400 + rq*4];
      }
    }
    __syncthreads();
    if (t > 0){
      const float* wcol = w1T + (size_t)u*4;
      #pragma unroll 5
      for (int rq = rq0; rq < rq0 + 25; ++rq){
        float4 h4 = hq4[rq*32 + b];
        float hr[4] = {h4.x, h4.y, h4.z, h4.w};
        #pragma unroll
        for (int dr = 0; dr < 4; ++dr){
          float4 w4 = *(const float4*)&wcol[(size_t)(rq*4 + dr)*1600];
          acc.x = fmaf(hr[dr], w4.x, acc.x);
          acc.y = fmaf(hr[dr], w4.y, acc.y);
          acc.z = fmaf(hr[dr], w4.z, acc.z);
          acc.w = fmaf(hr[dr], w4.w, acc.w);
        }
      }
    }
    red4[rh][b][ul] = acc;
    __syncthreads();
    if (tid < 64){
      const int bb = tid >> 1, uu = U0 + (tid & 1);
      float4 a = {0.f,0.f,0.f,0.f};
      #pragma unroll
      for (int w = 0; w < 4; ++w){
        float4 r = red4[w][bb][tid & 1];
        a.x += r.x; a.y += r.y; a.z += r.z; a.w += r.w;
      }
      float gi = a.x + bsum1[        uu];
      float gf = a.y + bsum1[ 400 + uu];
      float gg = a.z + bsum1[ 800 + uu];
      float go = a.w + bsum1[1200 + uu];
      float ii = 1.f/(1.f + expf(-gi));
      float ff = 1.f/(1.f + expf(-gf));
      float tg = tanhf(gg);
      float oo = 1.f/(1.f + expf(-go));
      float c = (t == 0) ? 0.f : cst1[bb*400 + uu];
      c = ff*c + ii*tg;
      cst1[bb*400 + uu] = c;
      hs1[((size_t)bb*12 + t)*400 + uu] = oo * tanhf(c);
    }
  }
}

// ---------------- theta head: one block per batch row b ----------------
__global__ __launch_bounds__(64) void theta_par(
    const float* __restrict__ muH2,
    const float* __restrict__ muW, const float* __restrict__ lsW,
    float* __restrict__ theta, float* __restrict__ accs)
{
  __shared__ float wm[50][51], wl[50][51];
  __shared__ float zs[12][50];
  const int tid = threadIdx.x;
  const int b = blockIdx.x;
  for (int i = tid; i < 2500; i += 64){
    int k = i / 50, j = i % 50;
    wm[k][j] = muW[k*450 + 400 + j];
    wl[k][j] = lsW[k*450 + 400 + j];
  }
  __syncthreads();
  const float dd = expf(LOG_DELTA) + 1e-6f;
  float kacc = 0.f;
  for (int t = 0; t < 12; ++t){
    float kpart = 0.f;
    if (tid < 50){
      int k = tid;
      float m = muH2[((size_t)b*12 + t)*100 + k];
      float l = muH2[((size_t)b*12 + t)*100 + 50 + k];
      float zp = 0.f;
      if (t > 0){
        zp = zs[t-1][k];
        float sm = 0.f, sl = 0.f;
        #pragma unroll 5
        for (int j = 0; j < 50; ++j){
          float z = zs[t-1][j];
          sm = fmaf(z, wm[k][j], sm);
          sl = fmaf(z, wl[k][j], sl);
        }
        m += sm; l += sl;
      }
      zs[t][k] = m;
      float denom = (t > 0) ? dd : (1.f + 1e-6f);
      float pls = (t > 0) ? LOG_DELTA : 0.f;
      float d = m - zp;
      kpart = (expf(l) + d*d)/denom - 1.f + pls - l;
    }
    kpart = wsum64(kpart);
    if (tid == 0) kacc += 0.5f * kpart / 32.f;
    __syncthreads();
  }
  // softmax rows: threads 0..11 each handle one t
  if (tid < 12){
    int t = tid;
    float m = -3.0e38f;
    for (int k = 0; k < 50; ++k) m = fmaxf(m, zs[t][k]);
    float S = 0.f;
    for (int k = 0; k < 50; ++k) S += expf(zs[t][k] - m);
    float inv = 1.f/S;
    for (int k = 0; k < 50; ++k)
      theta[((size_t)t*32 + b)*50 + k] = expf(zs[t][k] - m) * inv;
  }
  if (tid == 0) atomicAdd(&accs[6], kacc);
}

// ---------------- kld_alpha ----------------
__global__ void kld_alpha_k(const float* __restrict__ qmu, const float* __restrict__ qls,
                            float* __restrict__ accs){
  const int t = blockIdx.x / 50, k = blockIdx.x % 50;
  const size_t base  = ((size_t)k*12 + t)*300;
  const size_t pbase = ((size_t)k*12 + (t-1))*300;
  const float dd  = (t > 0) ? (expf(LOG_DELTA) + 1e-6f) : (1.f + 1e-6f);
  const float pls = (t > 0) ? LOG_DELTA : 0.f;
  float s = 0.f;
  for (int r = threadIdx.x; r < 300; r += 64){
    float qm = qmu[base + r], ql = qls[base + r];
    float pm = (t > 0) ? qmu[pbase + r] : 0.f;
    float d = qm - pm;
    s += (expf(ql) + d*d)/dd - 1.f + pls - ql;
  }
  s = wsum64(s);
  if (threadIdx.x == 0) atomicAdd(&accs[7], 0.5f * s / 50.f);
}

// ---------------- pass1 v7: consecutive-v items, float4 LDS, packed c0 ----
__global__ __launch_bounds__(256) void pass1(
    const float* __restrict__ blog, const float* __restrict__ rs,
    const float* __restrict__ theta,
    float* __restrict__ bzg,
    float* __restrict__ c1g1, float* __restrict__ c1g2,
    float* __restrict__ accs)
{
  const int t = blockIdx.y;
  const int v0 = blockIdx.x * 64;
  __shared__ float th[32][50];
  __shared__ __align__(16) float be[50][64];
  __shared__ unsigned int c0p[64][13];   // 4x u8 count fields per word (cnt<=32)
  __shared__ unsigned int c1p[2][32][25];
  __shared__ float rlog[2][50];
  __shared__ float kred[4];
  const int tid = threadIdx.x;

  if (tid < 100){
    int p = tid / 50, k = tid % 50;
    rlog[p][k] = __logf(rs[p*600 + t*50 + k]);
  }
  float lg[13];
  #pragma unroll
  for (int j = 0; j < 13; ++j){
    int i = tid + j*256;
    lg[j] = -40.f;
    if (i < 3200){
      int k = i >> 6, vl = i & 63, v = v0 + vl;
      if (v < 7000) lg[j] = blog[((size_t)t*50 + k)*7000 + v];
    }
  }
  #pragma unroll
  for (int j = 0; j < 7; ++j){
    int i = tid + j*256;
    if (i < 1600) th[i/50][i%50] = theta[(size_t)t*1600 + i];
  }
  for (int i = tid; i < 832; i += 256) ((unsigned int*)c0p)[i] = 0u;
  #pragma unroll
  for (int j = 0; j < 7; ++j){
    int i = tid + j*256;
    if (i < 1600) ((unsigned int*)c1p)[i] = 0u;
  }
  if (tid < 4) kred[tid] = 0.f;
  __syncthreads();
  #pragma unroll
  for (int j = 0; j < 13; ++j){
    int i = tid + j*256;
    if (i < 3200){
      int k = i >> 6, vl = i & 63, v = v0 + vl;
      int p = (v >= 5000);
      be[k][vl] = __expf(lg[j] - rlog[p][k]);
    }
  }
  __syncthreads();

  const int b = tid >> 3, sub = tid & 7;
  const int vb = sub << 3;                 // consecutive 8 v's per thread

  float sx[8], mx[8];
  #pragma unroll
  for (int i = 0; i < 8; ++i){ sx[i] = 0.f; mx[i] = 0.f; }
  for (int k = 0; k < 50; ++k){
    float tk = th[b][k];
    float4 q0 = *(const float4*)&be[k][vb];
    float4 q1 = *(const float4*)&be[k][vb + 4];
    float bv[8] = {q0.x,q0.y,q0.z,q0.w,q1.x,q1.y,q1.z,q1.w};
    #pragma unroll
    for (int i = 0; i < 8; ++i){
      float x = tk * bv[i];
      sx[i] += x;
      mx[i] = fmaxf(mx[i], x);
    }
  }
  float inv[8], lS1[8], bnd[8];
  #pragma unroll
  for (int i = 0; i < 8; ++i){
    inv[i] = 1.f / (50.f + sx[i]);
    lS1[i] = LOG50 + sx[i] * 0.02f;
    bnd[i] = (1.f + mx[i]) * inv[i];
  }

  int ks[8]; float xs[8];
  unsigned fmask = 0;
  const int vbase = (t*32 + b)*7000 + v0 + vb;
  #pragma unroll
  for (int i = 0; i < 8; ++i){
    ks[i] = 0; xs[i] = 0.f;
    if (v0 + vb + i >= 7000) fmask |= 1u << i;
  }
  int round = 0;
  while (true){
    const unsigned roff = (unsigned)round * 0x9E3779B9u;
    #pragma unroll
    for (int i = 0; i < 8; ++i){
      if (!((fmask >> i) & 1u)){
        const unsigned bse = (unsigned)(vbase + i) * 2u;
        float u1 = u01(bse + roff);
        float u2 = u01(bse + 1u + roff);
        int kp = min((int)(u1 * 50.f), 49);
        float x  = th[b][kp] * be[kp][vb + i];
        float pi = (1.f + x) * inv[i];
        float y  = pi - bnd[i];
        float ap = 1.f + y + 0.5f*y*y;
        if (u2 <= ap || round >= 7){
          ks[i] = kp; xs[i] = x; fmask |= 1u << i;
        }
      }
    }
    ++round;
    if (__all(fmask == 255u)) break;
  }

  float kA1 = 0.f, kB1 = 0.f, kA2 = 0.f, kB2 = 0.f;
  #pragma unroll
  for (int i = 0; i < 8; ++i){
    const int vl = vb + i, v = v0 + vl;
    if (v < 7000){
      float pis  = (1.f + xs[i]) * inv[i];
      float lpis = xs[i] - lS1[i];
      float lt   = __logf(th[b][ks[i]]);
      if (v >= 5000){ kA2 += lt; kB2 += pis*lpis; }
      else          { kA1 += lt; kB1 += pis*lpis; }
      atomicAdd(&c0p[vl][ks[i] >> 2], 1u << (8*(ks[i] & 3)));
      atomicAdd(&c1p[(v >= 5000) ? 1 : 0][b][ks[i] >> 1],
                (ks[i] & 1) ? 65536u : 1u);
    }
  }
  kA1 = wsum64(kA1); kB1 = wsum64(kB1); kA2 = wsum64(kA2); kB2 = wsum64(kB2);
  if ((tid & 63) == 0){
    atomicAdd(&kred[0], kA1); atomicAdd(&kred[1], kB1);
    atomicAdd(&kred[2], kA2); atomicAdd(&kred[3], kB2);
  }
  __syncthreads();
  #pragma unroll
  for (int j = 0; j < 13; ++j){
    int i = tid + j*256;
    if (i < 3200){
      int k = i >> 6, vl = i & 63, v = v0 + vl;
      if (v < 7000){
        float cnt = (float)((c0p[vl][k >> 2] >> (8*(k & 3))) & 0xFFu);
        bzg[(size_t)t*350000 + (size_t)k*7000 + v] = be[k][vl] * cnt * (1.f/32.f);
      }
    }
  }
  for (int i = tid; i < 1600; i += 256){
    int b2 = i / 50, k2 = i % 50;
    unsigned w1 = c1p[0][b2][k2 >> 1];
    unsigned w2 = c1p[1][b2][k2 >> 1];
    unsigned cnt1 = (k2 & 1) ? (w1 >> 16) : (w1 & 0xFFFFu);
    unsigned cnt2 = (k2 & 1) ? (w2 >> 16) : (w2 & 0xFFFFu);
    if (cnt1) atomicAdd(&c1g1[(size_t)t*1600 + i], (float)cnt1);
    if (cnt2) atomicAdd(&c1g2[(size_t)t*1600 + i], (float)cnt2);
  }
  if (tid < 4) atomicAdd(&accs[tid], kred[tid]);
}

// ---------------- pass2: log-likelihood (consecutive-v, float4 reads) ----------
__global__ __launch_bounds__(256) void pass2(
    const float* __restrict__ bzg, const float* __restrict__ theta,
    const float* __restrict__ c1g1, const float* __restrict__ c1g2,
    const float* __restrict__ bows, float* __restrict__ accs)
{
  const int t = blockIdx.y, v0 = blockIdx.x * 64;
  __shared__ float tz[2][32][50];
  __shared__ __align__(16) float bzs[50][64];
  __shared__ float sr[2];
  const int tid = threadIdx.x;
  if (tid < 2) sr[tid] = 0.f;
  for (int i = tid; i < 1600; i += 256){
    int b = i / 50, k = i % 50;
    float th_ = theta[(size_t)t*1600 + i];
    tz[0][b][k] = th_ * c1g1[(size_t)t*1600 + i] * (1.f/5000.f);
    tz[1][b][k] = th_ * c1g2[(size_t)t*1600 + i] * (1.f/2000.f);
  }
  for (int i = tid; i < 3200; i += 256){
    int k = i >> 6, vl = i & 63, v = v0 + vl;
    bzs[k][vl] = (v < 7000) ? bzg[(size_t)t*350000 + (size_t)k*7000 + v] : 0.f;
  }
  __syncthreads();

  const int b = tid >> 3, sub = tid & 7;
  const int vb = sub << 3;
  int part[8];
  #pragma unroll
  for (int i = 0; i < 8; ++i) part[i] = (v0 + vb + i >= 5000);
  float dot[8];
  #pragma unroll
  for (int i = 0; i < 8; ++i) dot[i] = 0.f;
  for (int k = 0; k < 50; ++k){
    float t0 = tz[0][b][k], t1 = tz[1][b][k];
    float4 q0 = *(const float4*)&bzs[k][vb];
    float4 q1 = *(const float4*)&bzs[k][vb + 4];
    float bv[8] = {q0.x,q0.y,q0.z,q0.w,q1.x,q1.y,q1.z,q1.w};
    #pragma unroll
    for (int i = 0; i < 8; ++i)
      dot[i] = fmaf(part[i] ? t1 : t0, bv[i], dot[i]);
  }
  // weights: 8 consecutive bows values
  float w8[8];
  const size_t brow = ((size_t)b*12 + t)*7000;
  if (v0 + vb + 7 < 7000){
    float4 wa = *(const float4*)&bows[brow + v0 + vb];
    float4 wb = *(const float4*)&bows[brow + v0 + vb + 4];
    w8[0]=wa.x; w8[1]=wa.y; w8[2]=wa.z; w8[3]=wa.w;
    w8[4]=wb.x; w8[5]=wb.y; w8[6]=wb.z; w8[7]=wb.w;
  } else {
    #pragma unroll
    for (int i = 0; i < 8; ++i)
      w8[i] = (v0 + vb + i < 7000) ? bows[brow + v0 + vb + i] : 0.f;
  }
  float s1 = 0.f, s2 = 0.f;
  #pragma unroll
  for (int i = 0; i < 8; ++i){
    const int v = v0 + vb + i;
    if (v < 7000){
      const float l = __logf(dot[i]) * w8[i];
      if (part[i]) s2 += l; else s1 += l;
    }
  }
  s1 = wsum64(s1); s2 = wsum64(s2);
  if ((tid & 63) == 0){ atomicAdd(&sr[0], s1); atomicAdd(&sr[1], s2); }
  __syncthreads();
  if (tid < 2) atomicAdd(&accs[4 + tid], sr[tid]);
}

// ---------------- finalize ----------------
__global__ void finalize_k(const float* __restrict__ accs, float* __restrict__ out){
  if (threadIdx.x == 0 && blockIdx.x == 0){
    out[0] = -(accs[4] + accs[5]) * (1.f/32.f);
    out[1] = accs[6];
    out[2] = -accs[0]/(32.f*5000.f) - accs[1]/32.f;
    out[3] = -accs[2]/(32.f*2000.f) - accs[3]/32.f;
    out[4] = accs[7];
  }
}

// ---------------- host launcher ----------------
extern "C" void kernel_launch(void* const* d_in, const int* in_sizes, int n_in,
                              void* d_out, int out_size, void* d_ws, size_t ws_size,
                              hipStream_t stream)
{
  const float* bows   = (const float*)d_in[0];
  const float* nbows  = (const float*)d_in[1];
  const float* qmap_w = (const float*)d_in[2];
  const float* qmap_b = (const float*)d_in[3];
  const float* wih0   = (const float*)d_in[4];
  const float* whh0   = (const float*)d_in[5];
  const float* bih0   = (const float*)d_in[6];
  const float* bhh0   = (const float*)d_in[7];
  const float* wih1   = (const float*)d_in[8];
  const float* whh1   = (const float*)d_in[9];
  const float* bih1   = (const float*)d_in[10];
  const float* bhh1   = (const float*)d_in[11];
  const float* muW    = (const float*)d_in[12];
  const float* muB    = (const float*)d_in[13];
  const float* lsW    = (const float*)d_in[14];
  const float* lsB    = (const float*)d_in[15];
  const float* qmu    = (const float*)d_in[16];
  const float* qlsa   = (const float*)d_in[17];
  const float* rho1w  = (const float*)d_in[18];
  const float* rho1b  = (const float*)d_in[19];
  const float* rho2w  = (const float*)d_in[20];
  const float* rho2b  = (const float*)d_in[21];

  float* ws  = (float*)d_ws;
  float* out = (float*)d_out;

  float* c1g1  = ws + OFF_C1G1;
  float* c1g2  = ws + OFF_C1G2;
  float* accs  = ws + OFF_ACCS;
  float* bzg   = ws + OFF_C0G;
  float* beta  = ws + OFF_BETA;
  float* inpf  = ws + OFF_ALPHAT;
  float* X0    = ws + OFF_X0;
  float* hs0   = ws + OFF_OUT0;
  float* hs1   = ws + OFF_OUT1;
  float* cst0  = ws + OFF_CST;
  float* cst1  = ws + OFF_CST1;
  float* muH2  = ws + OFF_MUH;
  float* theta = ws + OFF_THETA;
  float* muW4  = ws + OFF_MUW4;
  float* bsum0 = ws + OFF_LTH;
  float* bsum1 = ws + OFF_LTH + 1600;
  float* mlb   = ws + OFF_LTH + 3200;
  float* rs    = ws + OFF_RS;
  unsigned short* nbbf  = (unsigned short*)(ws + OFF_NBBF);
  unsigned short* qwbf  = (unsigned short*)(ws + OFF_QWBF);
  unsigned short* inpbf = (unsigned short*)(ws + OFF_INP);
  unsigned short* w0bf  = (unsigned short*)(ws + OFF_W0BF);
  unsigned short* albf  = (unsigned short*)(ws + OFF_ALBF);
  unsigned short* r1bf  = (unsigned short*)(ws + OFF_R1BF);
  unsigned short* r2bf  = (unsigned short*)(ws + OFF_R2BF);
  float* w0T  = ws + OFF_W0T;
  float* w1T  = ws + OFF_W1T;
  float* wi1T = ws + OFF_WIH1T;

  prep_misc<<<2048, 256, 0, stream>>>(ws, muW, lsW, qmu, bih0, bhh0, bih1, bhh1,
                                      muB, lsB, qmap_b, whh0, whh1, wih1,
                                      nbows, qmap_w, wih0, rho1w, rho2w);
  kld_alpha_k<<<600, 64, 0, stream>>>(qmu, qlsa, accs);

  // inp_f32 += nbows_bf @ qmap_w_bf^T  (split-K x10; bias pre-init'd in prep)
  gemm_bf16<<<dim3(7,6,10), 256, 0, stream>>>(nbbf, 7040, qwbf, 7040,
                                              nullptr, nullptr, inpf, 400,
                                              384, 400, 7040, 704, nullptr, nullptr);
  cvt_inp<<<150, 256, 0, stream>>>(inpf, inpbf);

  // X0 = inp_bf @ wih0^T + (bih0+bhh0)     M=384 N=1600 Kp=416
  gemm_bf16<<<dim3(25,6,1), 256, 0, stream>>>(inpbf, 416, w0bf, 416,
                                              X0, nullptr, nullptr, 1600,
                                              384, 1600, 416, 416, bsum0, nullptr);
  // pipelined double-layer LSTM: 13 launches
  for (int i = 0; i < 13; ++i)
    lstm_pipe<<<400, 256, 0, stream>>>(X0, w0T, wi1T, w1T, bsum1,
                                       hs0, hs1, cst0, cst1, i);

  // muH2 = hs1 @ [muW4;lsW4]^T + [muB;lsB]
  gemm_f32<<<dim3(2,6), 256, 0, stream>>>(hs1, 400, muW4, 400, muH2, 100,
                                          384, 100, 400, mlb);
  theta_par<<<32, 64, 0, stream>>>(muH2, muW, lsW, theta, accs);

  // beta logits via MFMA + fused row sum(exp)
  gemm_bf16<<<dim3(79,10,1), 256, 0, stream>>>(albf, 320, r1bf, 320,
                                               beta, nullptr, nullptr, 7000,
                                               600, 5000, 320, 320, rho1b, rs);
  gemm_bf16<<<dim3(32,10,1), 256, 0, stream>>>(albf, 320, r2bf, 320,
                                               beta + 5000, nullptr, nullptr, 7000,
                                               600, 2000, 320, 320, rho2b, rs + 600);

  pass1<<<dim3(110,12), 256, 0, stream>>>(beta, rs, theta, bzg, c1g1, c1g2, accs);
  pass2<<<dim3(110,12), 256, 0, stream>>>(bzg, theta, c1g1, c1g2, bows, accs);

  finalize_k<<<1, 64, 0, stream>>>(accs, out);
}

// Round 13
// 394.235 us; speedup vs baseline: 2.1498x; 1.1001x over previous
//
#include <hip/hip_runtime.h>

// ---------------- constants ----------------
#define LOG_DELTA (-5.2983174f)   // ln(0.005)
#define LOG50     (3.9120230054f) // ln(50)

typedef __attribute__((ext_vector_type(8))) short short8v;
typedef __attribute__((ext_vector_type(4))) float f32x4;

// ws layout (float offsets)
constexpr size_t OFF_C1G1  = 0;                       // [12][32][50]
constexpr size_t OFF_C1G2  = 19200;                   // [12][32][50]
constexpr size_t OFF_ACCS  = 38400;                   // [16]
constexpr size_t OFF_C0G   = 38416;                   // bzg [12][50][7000]
constexpr size_t OFF_BETA  = OFF_C0G  + 4200000;      // [600][7000] logits
constexpr size_t OFF_ALPHAT= OFF_BETA + 4200000;      // inp_f32 [384][400]
constexpr size_t OFF_INP   = OFF_ALPHAT + 180000;     // inp_bf ushort[384][416]
constexpr size_t OFF_X0    = OFF_INP  + 153600;       // [384][1600]
constexpr size_t OFF_OUT0  = OFF_X0   + 614400;       // hs0 [384][400]
constexpr size_t OFF_X1    = OFF_OUT0 + 153600;       // cst1|albf|r2bf region
constexpr size_t OFF_OUT1  = OFF_X1   + 614400;       // hs1 [384][400]
constexpr size_t OFF_CST   = OFF_OUT1 + 153600;       // cst0 [32][400]
constexpr size_t OFF_MUH   = OFF_CST  + 12800;        // [384][100]
constexpr size_t OFF_THETA = OFF_MUH  + 38400;        // [12][32][50]
constexpr size_t OFF_LTH   = OFF_THETA+ 19200;        // bsum0|bsum1|mlb|rs
constexpr size_t OFF_MUW4  = OFF_LTH  + 19200;        // [50][400]
constexpr size_t OFF_LSW4  = OFF_MUW4 + 20000;        // [50][400]
constexpr size_t OFF_RS    = OFF_LTH  + 3300;         // rowsum [2][600]
// overlay in bzg region (dead before pass1): block-packed LSTM weights
constexpr size_t OFF_W0P   = OFF_C0G;                 // f32 [200][400][8]
constexpr size_t OFF_W1P   = OFF_C0G + 640000;        // f32 [200][400][8]
constexpr size_t OFF_WI1P  = OFF_C0G + 1280000;       // f32 [200][400][8]
constexpr size_t OFF_NBBF  = OFF_C0G + 1920000;       // ushort[384][7040]
constexpr size_t OFF_R1BF  = OFF_C0G + 3271680;       // ushort[5000][320]
// overlay in beta region (dead before beta GEMMs):
constexpr size_t OFF_QWBF  = OFF_BETA;                // ushort[400][7040]
constexpr size_t OFF_W0BF  = OFF_BETA + 1408000;      // ushort[1600][416]
// overlay in X1 region (X1 eliminated):
constexpr size_t OFF_CST1  = OFF_X1;                  // f32 [32][400]
constexpr size_t OFF_ALBF  = OFF_X1 + 12800;          // ushort[600][320]
constexpr size_t OFF_R2BF  = OFF_X1 + 108800;         // ushort[2000][320]

// ---------------- helpers ----------------
__device__ __forceinline__ float wsum64(float x){
  #pragma unroll
  for (int o = 32; o; o >>= 1) x += __shfl_down(x, o);
  return x;
}
__device__ __forceinline__ float u01(unsigned int x){
  x ^= x >> 16; x *= 0x7feb352dU;
  x ^= x >> 15; x *= 0x846ca68bU;
  x ^= x >> 16;
  return ((float)x + 0.5f) * (1.0f/4294967296.0f);
}
__device__ __forceinline__ unsigned short f2bf(float x){
  unsigned int u = __float_as_uint(x);
  u += 0x7FFFu + ((u >> 16) & 1u);
  return (unsigned short)(u >> 16);
}
__device__ __forceinline__ ushort4 f4bf(float4 v){
  ushort4 r;
  r.x = f2bf(v.x); r.y = f2bf(v.y); r.z = f2bf(v.z); r.w = f2bf(v.w);
  return r;
}

// ---------------- fused prep (vectorized) ----------------
// S9-S11 now emit block-packed weights: wP[ub][r][ul*4+g] = whh[(g*400+ub*2+ul)*400 + r]
__global__ void prep_misc(float* __restrict__ ws,
    const float* __restrict__ muW, const float* __restrict__ lsW,
    const float* __restrict__ qmu,
    const float* __restrict__ bi0, const float* __restrict__ bh0,
    const float* __restrict__ bi1, const float* __restrict__ bh1,
    const float* __restrict__ mb,  const float* __restrict__ lb,
    const float* __restrict__ qb,
    const float* __restrict__ whh0, const float* __restrict__ whh1,
    const float* __restrict__ wih1,
    const float* __restrict__ nbows, const float* __restrict__ qmap_w,
    const float* __restrict__ wih0,
    const float* __restrict__ rho1w, const float* __restrict__ rho2w)
{
  float* zbase = ws + OFF_C1G1;
  float* muW4  = ws + OFF_MUW4;
  float* lsW4  = ws + OFF_LSW4;
  unsigned short* albf = (unsigned short*)(ws + OFF_ALBF);
  float* bsum0 = ws + OFF_LTH;
  float* bsum1 = ws + OFF_LTH + 1600;
  float* mlb   = ws + OFF_LTH + 3200;
  float* rs    = ws + OFF_RS;
  unsigned int* inbz = (unsigned int*)(ws + OFF_INP);
  float* inpf  = ws + OFF_ALPHAT;
  float* w0P   = ws + OFF_W0P;
  float* w1P   = ws + OFF_W1P;
  float* wi1P  = ws + OFF_WI1P;
  unsigned short* nbbf = (unsigned short*)(ws + OFF_NBBF);
  unsigned short* qwbf = (unsigned short*)(ws + OFF_QWBF);
  unsigned short* w0bf = (unsigned short*)(ws + OFF_W0BF);
  unsigned short* r1bf = (unsigned short*)(ws + OFF_R1BF);
  unsigned short* r2bf = (unsigned short*)(ws + OFF_R2BF);
  const float4 z4 = {0.f, 0.f, 0.f, 0.f};

  for (long long un = blockIdx.x*blockDim.x + threadIdx.x; un < 2713337LL;
       un += (long long)gridDim.x*blockDim.x){
    if (un < 9604){
      int j = (int)un * 4;
      if (j + 3 < 38416) *(float4*)&zbase[j] = z4;
      else { for (int q = 0; q < 4 && j+q < 38416; ++q) zbase[j+q] = 0.f; }
    }
    else if (un < 14604){
      int j = (int)(un - 9604) * 4;
      int k = j / 400, c = j % 400;
      const float* s = &muW[k*450 + c];
      float4 v = {s[0], s[1], s[2], s[3]};
      *(float4*)&muW4[j] = v;
    }
    else if (un < 19604){
      int j = (int)(un - 14604) * 4;
      int k = j / 400, c = j % 400;
      const float* s = &lsW[k*450 + c];
      float4 v = {s[0], s[1], s[2], s[3]};
      *(float4*)&lsW4[j] = v;
    }
    else if (un < 67604){
      int j = (int)(un - 19604) * 4;
      int m = j / 320, r = j % 320;
      int t = m / 50, k = m % 50;
      ushort4 o = {0,0,0,0};
      if (r < 300) o = f4bf(*(const float4*)&qmu[((size_t)k*12 + t)*300 + r]);
      *(ushort4*)&albf[j] = o;
    }
    else if (un < 68004){
      int j = (int)(un - 67604) * 4;
      float4 a = *(const float4*)&bi0[j], b = *(const float4*)&bh0[j];
      float4 v = {a.x+b.x, a.y+b.y, a.z+b.z, a.w+b.w};
      *(float4*)&bsum0[j] = v;
    }
    else if (un < 68404){
      int j = (int)(un - 68004) * 4;
      float4 a = *(const float4*)&bi1[j], b = *(const float4*)&bh1[j];
      float4 v = {a.x+b.x, a.y+b.y, a.z+b.z, a.w+b.w};
      *(float4*)&bsum1[j] = v;
    }
    else if (un < 68429){
      int j = (int)(un - 68404) * 4;
      #pragma unroll
      for (int q = 0; q < 4; ++q){
        int jj = j + q;
        mlb[jj] = (jj < 50) ? mb[jj] : lb[jj-50];
      }
    }
    else if (un < 68729){
      int j = (int)(un - 68429) * 4;
      *(float4*)&rs[j] = z4;
    }
    else if (un < 88697){
      int j = (int)(un - 68729) * 4;
      *(uint4*)&inbz[j] = make_uint4(0u,0u,0u,0u);
    }
    else if (un < 568697){
      long long rel = un - 88697;
      int half = (int)(rel / 160000);
      int j = (int)(rel % 160000) * 4;          // j = ub*3200 + r*8 + c, c in {0,4}
      int ub = j / 3200, rem = j % 3200;
      int r = rem / 8, c = rem % 8;
      int ul = c >> 2;
      int u = ub*2 + ul;
      const float* src = (half == 0) ? whh0 : (half == 1) ? whh1 : wih1;
      float* dst = (half == 0) ? w0P : (half == 1) ? w1P : wi1P;
      float4 v = { src[((size_t)(0*400 + u))*400 + r],
                   src[((size_t)(1*400 + u))*400 + r],
                   src[((size_t)(2*400 + u))*400 + r],
                   src[((size_t)(3*400 + u))*400 + r] };
      *(float4*)&dst[j] = v;
    }
    else if (un < 1244537){
      int j = (int)(un - 568697) * 4;
      int row = j / 7040, v = j % 7040;
      ushort4 o = {0,0,0,0};
      if (v < 7000) o = f4bf(*(const float4*)&nbows[(size_t)row*7000 + v]);
      *(ushort4*)&nbbf[j] = o;
    }
    else if (un < 1948537){
      int j = (int)(un - 1244537) * 4;
      int row = j / 7040, v = j % 7040;
      ushort4 o = {0,0,0,0};
      if (v < 7000) o = f4bf(*(const float4*)&qmap_w[(size_t)row*7000 + v]);
      *(ushort4*)&qwbf[j] = o;
    }
    else if (un < 2114937){
      int j = (int)(un - 1948537) * 4;
      int row = j / 416, r = j % 416;
      ushort4 o = {0,0,0,0};
      if (r < 400) o = f4bf(*(const float4*)&wih0[(size_t)row*400 + r]);
      *(ushort4*)&w0bf[j] = o;
    }
    else if (un < 2514937){
      int j = (int)(un - 2114937) * 4;
      int row = j / 320, r = j % 320;
      ushort4 o = {0,0,0,0};
      if (r < 300) o = f4bf(*(const float4*)&rho1w[(size_t)row*300 + r]);
      *(ushort4*)&r1bf[j] = o;
    }
    else if (un < 2674937){
      int j = (int)(un - 2514937) * 4;
      int row = j / 320, r = j % 320;
      ushort4 o = {0,0,0,0};
      if (r < 300) o = f4bf(*(const float4*)&rho2w[(size_t)row*300 + r]);
      *(ushort4*)&r2bf[j] = o;
    }
    else {
      int j = (int)(un - 2674937) * 4;
      int c = j % 400;
      *(float4*)&inpf[j] = *(const float4*)&qb[c];
    }
  }
}

// ---------------- MFMA bf16 GEMM ----------------
__global__ __launch_bounds__(256) void gemm_bf16(
    const unsigned short* __restrict__ A, int lda,
    const unsigned short* __restrict__ B, int ldb,
    float* __restrict__ Cf, unsigned short* __restrict__ Cbf,
    float* __restrict__ Cacc, int ldc,
    int M, int N, int Kp, int kchunk,
    const float* __restrict__ bias, float* __restrict__ rowsum)
{
  __shared__ unsigned short As[64][40];
  __shared__ unsigned short Bs[64][40];
  __shared__ float sexp[64];
  const int tid = threadIdx.x;
  const int m0 = blockIdx.y * 64, n0 = blockIdx.x * 64;
  const int kbeg = blockIdx.z * kchunk;
  const int kend = min(Kp, kbeg + kchunk);
  const int wave = tid >> 6, lane = tid & 63;
  const int wm = (wave >> 1) * 32, wn = (wave & 1) * 32;
  const int ra = tid >> 2, ck = (tid & 3) << 3;
  const int fr = lane & 15, fo = (lane >> 4) << 3;
  if (rowsum && tid < 64) sexp[tid] = 0.f;

  f32x4 acc00 = {0.f,0.f,0.f,0.f}, acc01 = {0.f,0.f,0.f,0.f};
  f32x4 acc10 = {0.f,0.f,0.f,0.f}, acc11 = {0.f,0.f,0.f,0.f};
  int4 pa, pb;
  {
    int rA = m0 + ra, rB = n0 + ra;
    pa = (rA < M) ? *(const int4*)&A[(size_t)rA*lda + kbeg + ck] : make_int4(0,0,0,0);
    pb = (rB < N) ? *(const int4*)&B[(size_t)rB*ldb + kbeg + ck] : make_int4(0,0,0,0);
  }
  for (int k0 = kbeg; k0 < kend; k0 += 32){
    *(int4*)&As[ra][ck] = pa;
    *(int4*)&Bs[ra][ck] = pb;
    __syncthreads();
    if (k0 + 32 < kend){
      int rA = m0 + ra, rB = n0 + ra;
      pa = (rA < M) ? *(const int4*)&A[(size_t)rA*lda + k0 + 32 + ck] : make_int4(0,0,0,0);
      pb = (rB < N) ? *(const int4*)&B[(size_t)rB*ldb + k0 + 32 + ck] : make_int4(0,0,0,0);
    }
    short8v a0 = *(const short8v*)&As[wm      + fr][fo];
    short8v a1 = *(const short8v*)&As[wm + 16 + fr][fo];
    short8v b0 = *(const short8v*)&Bs[wn      + fr][fo];
    short8v b1 = *(const short8v*)&Bs[wn + 16 + fr][fo];
    acc00 = __builtin_amdgcn_mfma_f32_16x16x32_bf16(a0, b0, acc00, 0, 0, 0);
    acc01 = __builtin_amdgcn_mfma_f32_16x16x32_bf16(a0, b1, acc01, 0, 0, 0);
    acc10 = __builtin_amdgcn_mfma_f32_16x16x32_bf16(a1, b0, acc10, 0, 0, 0);
    acc11 = __builtin_amdgcn_mfma_f32_16x16x32_bf16(a1, b1, acc11, 0, 0, 0);
    __syncthreads();
  }
  const int rbase = (lane >> 4) << 2;
  auto epi = [&](f32x4 ac0, f32x4 ac1, int mi){
    #pragma unroll
    for (int reg = 0; reg < 4; ++reg){
      const int lr = wm + mi*16 + rbase + reg;
      const int gr = m0 + lr;
      float ex = 0.f;
      {
        int gc = n0 + wn + fr;
        if (gr < M && gc < N){
          if (Cacc) atomicAdd(&Cacc[(size_t)gr*ldc + gc], ac0[reg]);
          else {
            float val = ac0[reg] + (bias ? bias[gc] : 0.f);
            if (Cbf) Cbf[(size_t)gr*ldc + gc] = f2bf(val);
            else     Cf [(size_t)gr*ldc + gc] = val;
            if (rowsum) ex += __expf(val);
          }
        }
      }
      {
        int gc = n0 + wn + 16 + fr;
        if (gr < M && gc < N){
          if (Cacc) atomicAdd(&Cacc[(size_t)gr*ldc + gc], ac1[reg]);
          else {
            float val = ac1[reg] + (bias ? bias[gc] : 0.f);
            if (Cbf) Cbf[(size_t)gr*ldc + gc] = f2bf(val);
            else     Cf [(size_t)gr*ldc + gc] = val;
            if (rowsum) ex += __expf(val);
          }
        }
      }
      if (rowsum){
        ex += __shfl_xor(ex, 1); ex += __shfl_xor(ex, 2);
        ex += __shfl_xor(ex, 4); ex += __shfl_xor(ex, 8);
        if (fr == 0 && gr < M) atomicAdd(&sexp[lr], ex);
      }
    }
  };
  epi(acc00, acc01, 0);
  epi(acc10, acc11, 1);
  if (rowsum){
    __syncthreads();
    if (tid < 64 && m0 + tid < M) atomicAdd(&rowsum[m0 + tid], sexp[tid]);
  }
}

// ---------------- convert inp_f32 -> bf16 (vectorized) ----------------
__global__ void cvt_inp(const float* __restrict__ inpf, unsigned short* __restrict__ inpbf){
  int un = blockIdx.x*blockDim.x + threadIdx.x;
  if (un < 38400){
    int j = un * 4;
    int r = j / 400, c = j % 400;
    ushort4 o = f4bf(*(const float4*)&inpf[j]);
    *(ushort4*)&inpbf[r*416 + c] = o;
  }
}

// ---------------- f32 GEMM (kept for tiny muH2) ----------------
__device__ __forceinline__ float4 g4(const float* __restrict__ base, int row, int nrows,
                                     int ld, int k, int kend){
  float4 v; v.x = v.y = v.z = v.w = 0.f;
  if (row < nrows){
    const float* q = base + (size_t)row*ld + k;
    if (k + 3 < kend) v = *(const float4*)q;
  }
  return v;
}
__global__ __launch_bounds__(256) void gemm_f32(
    const float* __restrict__ A, int lda,
    const float* __restrict__ B, int ldb,
    float* __restrict__ C, int ldc,
    int M, int N, int K,
    const float* __restrict__ bias)
{
  __shared__ __align__(16) float As[16][68];
  __shared__ __align__(16) float Bs[16][68];
  const int tid = threadIdx.x;
  const int m0 = blockIdx.y * 64, n0 = blockIdx.x * 64;
  const int lm  = tid >> 2;
  const int lkq = (tid & 3) << 2;
  const int ty = tid >> 4, tx = tid & 15;
  float acc[4][4];
  #pragma unroll
  for (int i=0;i<4;++i)
    #pragma unroll
    for (int j=0;j<4;++j) acc[i][j] = 0.f;
  for (int k0 = 0; k0 < K; k0 += 16){
    float4 av = g4(A, m0+lm, M, lda, k0+lkq, K);
    float4 bv = g4(B, n0+lm, N, ldb, k0+lkq, K);
    As[lkq+0][lm]=av.x; As[lkq+1][lm]=av.y; As[lkq+2][lm]=av.z; As[lkq+3][lm]=av.w;
    Bs[lkq+0][lm]=bv.x; Bs[lkq+1][lm]=bv.y; Bs[lkq+2][lm]=bv.z; Bs[lkq+3][lm]=bv.w;
    __syncthreads();
    #pragma unroll
    for (int kk = 0; kk < 16; ++kk){
      const float4 a = *(const float4*)&As[kk][ty<<2];
      const float4 b = *(const float4*)&Bs[kk][tx<<2];
      float ar[4] = {a.x,a.y,a.z,a.w};
      float br[4] = {b.x,b.y,b.z,b.w};
      #pragma unroll
      for (int i=0;i<4;++i)
        #pragma unroll
        for (int j=0;j<4;++j) acc[i][j] = fmaf(ar[i], br[j], acc[i][j]);
    }
    __syncthreads();
  }
  const int om = m0 + (ty<<2), on = n0 + (tx<<2);
  #pragma unroll
  for (int i=0;i<4;++i)
    #pragma unroll
    for (int j=0;j<4;++j)
      if (om+i < M && on+j < N)
        C[(size_t)(om+i)*ldc + (on+j)] = acc[i][j] + (bias ? bias[on+j] : 0.f);
}

// ---------------- pipelined LSTM v2: LDS-staged packed weights ----------------
// grid 400 x 256. blocks <200: layer0 step t. blocks >=200: layer1 step t-1
// (wih1 fused via phase A). Weights read via block-contiguous wP[ub][r][8]
// staged into LDS (12.8KB), h staged into LDS (51.2KB). Inner loop pure LDS.
__global__ __launch_bounds__(256) void lstm_pipe(
    const float* __restrict__ X0,    const float* __restrict__ w0P,
    const float* __restrict__ wi1P,  const float* __restrict__ w1P,
    const float* __restrict__ bsum1,
    float* __restrict__ hs0, float* __restrict__ hs1,
    float* __restrict__ cst0, float* __restrict__ cst1, int step)
{
  __shared__ __align__(16) float4 hq4[100*32];   // [rq][b]  51.2KB
  __shared__ __align__(16) float4 wq4[400*2];    // [r][ul]  12.8KB
  __shared__ __align__(16) float4 red4[4][32][2];
  const int tid = threadIdx.x;
  const int rh = tid >> 6;
  const int b  = (tid & 63) >> 1;
  const int ul = tid & 1;
  const int rq0 = rh * 25;

  if (blockIdx.x < 200){
    const int t = step;
    if (t >= 12) return;
    const int ub = blockIdx.x;
    const int U0 = ub * 2;
    if (t > 0){
      for (int i = tid; i < 3200; i += 256){
        int bb = i & 31, rq = i >> 5;
        hq4[rq*32 + bb] = *(const float4*)&hs0[((size_t)(bb*12 + (t-1)))*400 + rq*4];
      }
      for (int i = tid; i < 800; i += 256)
        wq4[i] = *(const float4*)&w0P[(size_t)ub*3200 + i*4];
      __syncthreads();
      float4 acc = {0.f,0.f,0.f,0.f};
      #pragma unroll 5
      for (int rq = rq0; rq < rq0 + 25; ++rq){
        float4 h4 = hq4[rq*32 + b];
        float hr[4] = {h4.x, h4.y, h4.z, h4.w};
        #pragma unroll
        for (int dr = 0; dr < 4; ++dr){
          float4 w4 = wq4[(rq*4 + dr)*2 + ul];
          acc.x = fmaf(hr[dr], w4.x, acc.x);
          acc.y = fmaf(hr[dr], w4.y, acc.y);
          acc.z = fmaf(hr[dr], w4.z, acc.z);
          acc.w = fmaf(hr[dr], w4.w, acc.w);
        }
      }
      red4[rh][b][ul] = acc;
    }
    __syncthreads();
    if (tid < 64){
      const int bb = tid >> 1, uu = U0 + (tid & 1);
      float4 a = {0.f,0.f,0.f,0.f};
      if (t > 0){
        #pragma unroll
        for (int w = 0; w < 4; ++w){
          float4 r = red4[w][bb][tid & 1];
          a.x += r.x; a.y += r.y; a.z += r.z; a.w += r.w;
        }
      }
      const size_t xrow = ((size_t)bb*12 + t)*1600;
      float gi = a.x + X0[xrow          + uu];
      float gf = a.y + X0[xrow +  400   + uu];
      float gg = a.z + X0[xrow +  800   + uu];
      float go = a.w + X0[xrow + 1200   + uu];
      float ii = 1.f/(1.f + expf(-gi));
      float ff = 1.f/(1.f + expf(-gf));
      float tg = tanhf(gg);
      float oo = 1.f/(1.f + expf(-go));
      float c = (t == 0) ? 0.f : cst0[bb*400 + uu];
      c = ff*c + ii*tg;
      cst0[bb*400 + uu] = c;
      hs0[((size_t)bb*12 + t)*400 + uu] = oo * tanhf(c);
    }
  } else {
    const int t = step - 1;
    if (t < 0) return;
    const int ub = blockIdx.x - 200;
    const int U0 = ub * 2;
    float4 acc = {0.f,0.f,0.f,0.f};
    // phase A: h0(t) @ wih1 (staged)
    for (int i = tid; i < 3200; i += 256){
      int bb = i & 31, rq = i >> 5;
      hq4[rq*32 + bb] = *(const float4*)&hs0[((size_t)(bb*12 + t))*400 + rq*4];
    }
    for (int i = tid; i < 800; i += 256)
      wq4[i] = *(const float4*)&wi1P[(size_t)ub*3200 + i*4];
    __syncthreads();
    {
      #pragma unroll 5
      for (int rq = rq0; rq < rq0 + 25; ++rq){
        float4 h4 = hq4[rq*32 + b];
        float hr[4] = {h4.x, h4.y, h4.z, h4.w};
        #pragma unroll
        for (int dr = 0; dr < 4; ++dr){
          float4 w4 = wq4[(rq*4 + dr)*2 + ul];
          acc.x = fmaf(hr[dr], w4.x, acc.x);
          acc.y = fmaf(hr[dr], w4.y, acc.y);
          acc.z = fmaf(hr[dr], w4.z, acc.z);
          acc.w = fmaf(hr[dr], w4.w, acc.w);
        }
      }
    }
    __syncthreads();
    // phase B: h1(t-1) @ whh1 (restage both buffers)
    if (t > 0){
      for (int i = tid; i < 3200; i += 256){
        int bb = i & 31, rq = i >> 5;
        hq4[rq*32 + bb] = *(const float4*)&hs1[((size_t)(bb*12 + (t-1)))*400 + rq*4];
      }
      for (int i = tid; i < 800; i += 256)
        wq4[i] = *(const float4*)&w1P[(size_t)ub*3200 + i*4];
    }
    __syncthreads();
    if (t > 0){
      #pragma unroll 5
      for (int rq = rq0; rq < rq0 + 25; ++rq){
        float4 h4 = hq4[rq*32 + b];
        float hr[4] = {h4.x, h4.y, h4.z, h4.w};
        #pragma unroll
        for (int dr = 0; dr < 4; ++dr){
          float4 w4 = wq4[(rq*4 + dr)*2 + ul];
          acc.x = fmaf(hr[dr], w4.x, acc.x);
          acc.y = fmaf(hr[dr], w4.y, acc.y);
          acc.z = fmaf(hr[dr], w4.z, acc.z);
          acc.w = fmaf(hr[dr], w4.w, acc.w);
        }
      }
    }
    red4[rh][b][ul] = acc;
    __syncthreads();
    if (tid < 64){
      const int bb = tid >> 1, uu = U0 + (tid & 1);
      float4 a = {0.f,0.f,0.f,0.f};
      #pragma unroll
      for (int w = 0; w < 4; ++w){
        float4 r = red4[w][bb][tid & 1];
        a.x += r.x; a.y += r.y; a.z += r.z; a.w += r.w;
      }
      float gi = a.x + bsum1[        uu];
      float gf = a.y + bsum1[ 400 + uu];
      float gg = a.z + bsum1[ 800 + uu];
      float go = a.w + bsum1[1200 + uu];
      float ii = 1.f/(1.f + expf(-gi));
      float ff = 1.f/(1.f + expf(-gf));
      float tg = tanhf(gg);
      float oo = 1.f/(1.f + expf(-go));
      float c = (t == 0) ? 0.f : cst1[bb*400 + uu];
      c = ff*c + ii*tg;
      cst1[bb*400 + uu] = c;
      hs1[((size_t)bb*12 + t)*400 + uu] = oo * tanhf(c);
    }
  }
}

// ---------------- theta head: one block per batch row b ----------------
__global__ __launch_bounds__(64) void theta_par(
    const float* __restrict__ muH2,
    const float* __restrict__ muW, const float* __restrict__ lsW,
    float* __restrict__ theta, float* __restrict__ accs)
{
  __shared__ float wm[50][51], wl[50][51];
  __shared__ float zs[12][50];
  const int tid = threadIdx.x;
  const int b = blockIdx.x;
  for (int i = tid; i < 2500; i += 64){
    int k = i / 50, j = i % 50;
    wm[k][j] = muW[k*450 + 400 + j];
    wl[k][j] = lsW[k*450 + 400 + j];
  }
  __syncthreads();
  const float dd = expf(LOG_DELTA) + 1e-6f;
  float kacc = 0.f;
  for (int t = 0; t < 12; ++t){
    float kpart = 0.f;
    if (tid < 50){
      int k = tid;
      float m = muH2[((size_t)b*12 + t)*100 + k];
      float l = muH2[((size_t)b*12 + t)*100 + 50 + k];
      float zp = 0.f;
      if (t > 0){
        zp = zs[t-1][k];
        float sm = 0.f, sl = 0.f;
        #pragma unroll 5
        for (int j = 0; j < 50; ++j){
          float z = zs[t-1][j];
          sm = fmaf(z, wm[k][j], sm);
          sl = fmaf(z, wl[k][j], sl);
        }
        m += sm; l += sl;
      }
      zs[t][k] = m;
      float denom = (t > 0) ? dd : (1.f + 1e-6f);
      float pls = (t > 0) ? LOG_DELTA : 0.f;
      float d = m - zp;
      kpart = (expf(l) + d*d)/denom - 1.f + pls - l;
    }
    kpart = wsum64(kpart);
    if (tid == 0) kacc += 0.5f * kpart / 32.f;
    __syncthreads();
  }
  if (tid < 12){
    int t = tid;
    float m = -3.0e38f;
    for (int k = 0; k < 50; ++k) m = fmaxf(m, zs[t][k]);
    float S = 0.f;
    for (int k = 0; k < 50; ++k) S += expf(zs[t][k] - m);
    float inv = 1.f/S;
    for (int k = 0; k < 50; ++k)
      theta[((size_t)t*32 + b)*50 + k] = expf(zs[t][k] - m) * inv;
  }
  if (tid == 0) atomicAdd(&accs[6], kacc);
}

// ---------------- kld_alpha ----------------
__global__ void kld_alpha_k(const float* __restrict__ qmu, const float* __restrict__ qls,
                            float* __restrict__ accs){
  const int t = blockIdx.x / 50, k = blockIdx.x % 50;
  const size_t base  = ((size_t)k*12 + t)*300;
  const size_t pbase = ((size_t)k*12 + (t-1))*300;
  const float dd  = (t > 0) ? (expf(LOG_DELTA) + 1e-6f) : (1.f + 1e-6f);
  const float pls = (t > 0) ? LOG_DELTA : 0.f;
  float s = 0.f;
  for (int r = threadIdx.x; r < 300; r += 64){
    float qm = qmu[base + r], ql = qls[base + r];
    float pm = (t > 0) ? qmu[pbase + r] : 0.f;
    float d = qm - pm;
    s += (expf(ql) + d*d)/dd - 1.f + pls - ql;
  }
  s = wsum64(s);
  if (threadIdx.x == 0) atomicAdd(&accs[7], 0.5f * s / 50.f);
}

// ---------------- pass1 v7: consecutive-v items, float4 LDS, packed c0 ----
__global__ __launch_bounds__(256) void pass1(
    const float* __restrict__ blog, const float* __restrict__ rs,
    const float* __restrict__ theta,
    float* __restrict__ bzg,
    float* __restrict__ c1g1, float* __restrict__ c1g2,
    float* __restrict__ accs)
{
  const int t = blockIdx.y;
  const int v0 = blockIdx.x * 64;
  __shared__ float th[32][50];
  __shared__ __align__(16) float be[50][64];
  __shared__ unsigned int c0p[64][13];
  __shared__ unsigned int c1p[2][32][25];
  __shared__ float rlog[2][50];
  __shared__ float kred[4];
  const int tid = threadIdx.x;

  if (tid < 100){
    int p = tid / 50, k = tid % 50;
    rlog[p][k] = __logf(rs[p*600 + t*50 + k]);
  }
  float lg[13];
  #pragma unroll
  for (int j = 0; j < 13; ++j){
    int i = tid + j*256;
    lg[j] = -40.f;
    if (i < 3200){
      int k = i >> 6, vl = i & 63, v = v0 + vl;
      if (v < 7000) lg[j] = blog[((size_t)t*50 + k)*7000 + v];
    }
  }
  #pragma unroll
  for (int j = 0; j < 7; ++j){
    int i = tid + j*256;
    if (i < 1600) th[i/50][i%50] = theta[(size_t)t*1600 + i];
  }
  for (int i = tid; i < 832; i += 256) ((unsigned int*)c0p)[i] = 0u;
  #pragma unroll
  for (int j = 0; j < 7; ++j){
    int i = tid + j*256;
    if (i < 1600) ((unsigned int*)c1p)[i] = 0u;
  }
  if (tid < 4) kred[tid] = 0.f;
  __syncthreads();
  #pragma unroll
  for (int j = 0; j < 13; ++j){
    int i = tid + j*256;
    if (i < 3200){
      int k = i >> 6, vl = i & 63, v = v0 + vl;
      int p = (v >= 5000);
      be[k][vl] = __expf(lg[j] - rlog[p][k]);
    }
  }
  __syncthreads();

  const int b = tid >> 3, sub = tid & 7;
  const int vb = sub << 3;

  float sx[8], mx[8];
  #pragma unroll
  for (int i = 0; i < 8; ++i){ sx[i] = 0.f; mx[i] = 0.f; }
  for (int k = 0; k < 50; ++k){
    float tk = th[b][k];
    float4 q0 = *(const float4*)&be[k][vb];
    float4 q1 = *(const float4*)&be[k][vb + 4];
    float bv[8] = {q0.x,q0.y,q0.z,q0.w,q1.x,q1.y,q1.z,q1.w};
    #pragma unroll
    for (int i = 0; i < 8; ++i){
      float x = tk * bv[i];
      sx[i] += x;
      mx[i] = fmaxf(mx[i], x);
    }
  }
  float inv[8], lS1[8], bnd[8];
  #pragma unroll
  for (int i = 0; i < 8; ++i){
    inv[i] = 1.f / (50.f + sx[i]);
    lS1[i] = LOG50 + sx[i] * 0.02f;
    bnd[i] = (1.f + mx[i]) * inv[i];
  }

  int ks[8]; float xs[8];
  unsigned fmask = 0;
  const int vbase = (t*32 + b)*7000 + v0 + vb;
  #pragma unroll
  for (int i = 0; i < 8; ++i){
    ks[i] = 0; xs[i] = 0.f;
    if (v0 + vb + i >= 7000) fmask |= 1u << i;
  }
  int round = 0;
  while (true){
    const unsigned roff = (unsigned)round * 0x9E3779B9u;
    #pragma unroll
    for (int i = 0; i < 8; ++i){
      if (!((fmask >> i) & 1u)){
        const unsigned bse = (unsigned)(vbase + i) * 2u;
        float u1 = u01(bse + roff);
        float u2 = u01(bse + 1u + roff);
        int kp = min((int)(u1 * 50.f), 49);
        float x  = th[b][kp] * be[kp][vb + i];
        float pi = (1.f + x) * inv[i];
        float y  = pi - bnd[i];
        float ap = 1.f + y + 0.5f*y*y;
        if (u2 <= ap || round >= 7){
          ks[i] = kp; xs[i] = x; fmask |= 1u << i;
        }
      }
    }
    ++round;
    if (__all(fmask == 255u)) break;
  }

  float kA1 = 0.f, kB1 = 0.f, kA2 = 0.f, kB2 = 0.f;
  #pragma unroll
  for (int i = 0; i < 8; ++i){
    const int vl = vb + i, v = v0 + vl;
    if (v < 7000){
      float pis  = (1.f + xs[i]) * inv[i];
      float lpis = xs[i] - lS1[i];
      float lt   = __logf(th[b][ks[i]]);
      if (v >= 5000){ kA2 += lt; kB2 += pis*lpis; }
      else          { kA1 += lt; kB1 += pis*lpis; }
      atomicAdd(&c0p[vl][ks[i] >> 2], 1u << (8*(ks[i] & 3)));
      atomicAdd(&c1p[(v >= 5000) ? 1 : 0][b][ks[i] >> 1],
                (ks[i] & 1) ? 65536u : 1u);
    }
  }
  kA1 = wsum64(kA1); kB1 = wsum64(kB1); kA2 = wsum64(kA2); kB2 = wsum64(kB2);
  if ((tid & 63) == 0){
    atomicAdd(&kred[0], kA1); atomicAdd(&kred[1], kB1);
    atomicAdd(&kred[2], kA2); atomicAdd(&kred[3], kB2);
  }
  __syncthreads();
  #pragma unroll
  for (int j = 0; j < 13; ++j){
    int i = tid + j*256;
    if (i < 3200){
      int k = i >> 6, vl = i & 63, v = v0 + vl;
      if (v < 7000){
        float cnt = (float)((c0p[vl][k >> 2] >> (8*(k & 3))) & 0xFFu);
        bzg[(size_t)t*350000 + (size_t)k*7000 + v] = be[k][vl] * cnt * (1.f/32.f);
      }
    }
  }
  for (int i = tid; i < 1600; i += 256){
    int b2 = i / 50, k2 = i % 50;
    unsigned w1 = c1p[0][b2][k2 >> 1];
    unsigned w2 = c1p[1][b2][k2 >> 1];
    unsigned cnt1 = (k2 & 1) ? (w1 >> 16) : (w1 & 0xFFFFu);
    unsigned cnt2 = (k2 & 1) ? (w2 >> 16) : (w2 & 0xFFFFu);
    if (cnt1) atomicAdd(&c1g1[(size_t)t*1600 + i], (float)cnt1);
    if (cnt2) atomicAdd(&c1g2[(size_t)t*1600 + i], (float)cnt2);
  }
  if (tid < 4) atomicAdd(&accs[tid], kred[tid]);
}

// ---------------- pass2: log-likelihood (consecutive-v, float4 reads) ----------
__global__ __launch_bounds__(256) void pass2(
    const float* __restrict__ bzg, const float* __restrict__ theta,
    const float* __restrict__ c1g1, const float* __restrict__ c1g2,
    const float* __restrict__ bows, float* __restrict__ accs)
{
  const int t = blockIdx.y, v0 = blockIdx.x * 64;
  __shared__ float tz[2][32][50];
  __shared__ __align__(16) float bzs[50][64];
  __shared__ float sr[2];
  const int tid = threadIdx.x;
  if (tid < 2) sr[tid] = 0.f;
  for (int i = tid; i < 1600; i += 256){
    int b = i / 50, k = i % 50;
    float th_ = theta[(size_t)t*1600 + i];
    tz[0][b][k] = th_ * c1g1[(size_t)t*1600 + i] * (1.f/5000.f);
    tz[1][b][k] = th_ * c1g2[(size_t)t*1600 + i] * (1.f/2000.f);
  }
  for (int i = tid; i < 3200; i += 256){
    int k = i >> 6, vl = i & 63, v = v0 + vl;
    bzs[k][vl] = (v < 7000) ? bzg[(size_t)t*350000 + (size_t)k*7000 + v] : 0.f;
  }
  __syncthreads();

  const int b = tid >> 3, sub = tid & 7;
  const int vb = sub << 3;
  int part[8];
  #pragma unroll
  for (int i = 0; i < 8; ++i) part[i] = (v0 + vb + i >= 5000);
  float dot[8];
  #pragma unroll
  for (int i = 0; i < 8; ++i) dot[i] = 0.f;
  for (int k = 0; k < 50; ++k){
    float t0 = tz[0][b][k], t1 = tz[1][b][k];
    float4 q0 = *(const float4*)&bzs[k][vb];
    float4 q1 = *(const float4*)&bzs[k][vb + 4];
    float bv[8] = {q0.x,q0.y,q0.z,q0.w,q1.x,q1.y,q1.z,q1.w};
    #pragma unroll
    for (int i = 0; i < 8; ++i)
      dot[i] = fmaf(part[i] ? t1 : t0, bv[i], dot[i]);
  }
  float w8[8];
  const size_t brow = ((size_t)b*12 + t)*7000;
  if (v0 + vb + 7 < 7000){
    float4 wa = *(const float4*)&bows[brow + v0 + vb];
    float4 wb = *(const float4*)&bows[brow + v0 + vb + 4];
    w8[0]=wa.x; w8[1]=wa.y; w8[2]=wa.z; w8[3]=wa.w;
    w8[4]=wb.x; w8[5]=wb.y; w8[6]=wb.z; w8[7]=wb.w;
  } else {
    #pragma unroll
    for (int i = 0; i < 8; ++i)
      w8[i] = (v0 + vb + i < 7000) ? bows[brow + v0 + vb + i] : 0.f;
  }
  float s1 = 0.f, s2 = 0.f;
  #pragma unroll
  for (int i = 0; i < 8; ++i){
    const int v = v0 + vb + i;
    if (v < 7000){
      const float l = __logf(dot[i]) * w8[i];
      if (part[i]) s2 += l; else s1 += l;
    }
  }
  s1 = wsum64(s1); s2 = wsum64(s2);
  if ((tid & 63) == 0){ atomicAdd(&sr[0], s1); atomicAdd(&sr[1], s2); }
  __syncthreads();
  if (tid < 2) atomicAdd(&accs[4 + tid], sr[tid]);
}

// ---------------- finalize ----------------
__global__ void finalize_k(const float* __restrict__ accs, float* __restrict__ out){
  if (threadIdx.x == 0 && blockIdx.x == 0){
    out[0] = -(accs[4] + accs[5]) * (1.f/32.f);
    out[1] = accs[6];
    out[2] = -accs[0]/(32.f*5000.f) - accs[1]/32.f;
    out[3] = -accs[2]/(32.f*2000.f) - accs[3]/32.f;
    out[4] = accs[7];
  }
}

// ---------------- host launcher ----------------
extern "C" void kernel_launch(void* const* d_in, const int* in_sizes, int n_in,
                              void* d_out, int out_size, void* d_ws, size_t ws_size,
                              hipStream_t stream)
{
  const float* bows   = (const float*)d_in[0];
  const float* nbows  = (const float*)d_in[1];
  const float* qmap_w = (const float*)d_in[2];
  const float* qmap_b = (const float*)d_in[3];
  const float* wih0   = (const float*)d_in[4];
  const float* whh0   = (const float*)d_in[5];
  const float* bih0   = (const float*)d_in[6];
  const float* bhh0   = (const float*)d_in[7];
  const float* wih1   = (const float*)d_in[8];
  const float* whh1   = (const float*)d_in[9];
  const float* bih1   = (const float*)d_in[10];
  const float* bhh1   = (const float*)d_in[11];
  const float* muW    = (const float*)d_in[12];
  const float* muB    = (const float*)d_in[13];
  const float* lsW    = (const float*)d_in[14];
  const float* lsB    = (const float*)d_in[15];
  const float* qmu    = (const float*)d_in[16];
  const float* qlsa   = (const float*)d_in[17];
  const float* rho1w  = (const float*)d_in[18];
  const float* rho1b  = (const float*)d_in[19];
  const float* rho2w  = (const float*)d_in[20];
  const float* rho2b  = (const float*)d_in[21];

  float* ws  = (float*)d_ws;
  float* out = (float*)d_out;

  float* c1g1  = ws + OFF_C1G1;
  float* c1g2  = ws + OFF_C1G2;
  float* accs  = ws + OFF_ACCS;
  float* bzg   = ws + OFF_C0G;
  float* beta  = ws + OFF_BETA;
  float* inpf  = ws + OFF_ALPHAT;
  float* X0    = ws + OFF_X0;
  float* hs0   = ws + OFF_OUT0;
  float* hs1   = ws + OFF_OUT1;
  float* cst0  = ws + OFF_CST;
  float* cst1  = ws + OFF_CST1;
  float* muH2  = ws + OFF_MUH;
  float* theta = ws + OFF_THETA;
  float* muW4  = ws + OFF_MUW4;
  float* bsum0 = ws + OFF_LTH;
  float* bsum1 = ws + OFF_LTH + 1600;
  float* mlb   = ws + OFF_LTH + 3200;
  float* rs    = ws + OFF_RS;
  unsigned short* nbbf  = (unsigned short*)(ws + OFF_NBBF);
  unsigned short* qwbf  = (unsigned short*)(ws + OFF_QWBF);
  unsigned short* inpbf = (unsigned short*)(ws + OFF_INP);
  unsigned short* w0bf  = (unsigned short*)(ws + OFF_W0BF);
  unsigned short* albf  = (unsigned short*)(ws + OFF_ALBF);
  unsigned short* r1bf  = (unsigned short*)(ws + OFF_R1BF);
  unsigned short* r2bf  = (unsigned short*)(ws + OFF_R2BF);
  float* w0P  = ws + OFF_W0P;
  float* w1P  = ws + OFF_W1P;
  float* wi1P = ws + OFF_WI1P;

  prep_misc<<<2048, 256, 0, stream>>>(ws, muW, lsW, qmu, bih0, bhh0, bih1, bhh1,
                                      muB, lsB, qmap_b, whh0, whh1, wih1,
                                      nbows, qmap_w, wih0, rho1w, rho2w);
  kld_alpha_k<<<600, 64, 0, stream>>>(qmu, qlsa, accs);

  // inp_f32 += nbows_bf @ qmap_w_bf^T  (split-K x10; bias pre-init'd in prep)
  gemm_bf16<<<dim3(7,6,10), 256, 0, stream>>>(nbbf, 7040, qwbf, 7040,
                                              nullptr, nullptr, inpf, 400,
                                              384, 400, 7040, 704, nullptr, nullptr);
  cvt_inp<<<150, 256, 0, stream>>>(inpf, inpbf);

  // X0 = inp_bf @ wih0^T + (bih0+bhh0)     M=384 N=1600 Kp=416
  gemm_bf16<<<dim3(25,6,1), 256, 0, stream>>>(inpbf, 416, w0bf, 416,
                                              X0, nullptr, nullptr, 1600,
                                              384, 1600, 416, 416, bsum0, nullptr);
  // pipelined double-layer LSTM: 13 launches
  for (int i = 0; i < 13; ++i)
    lstm_pipe<<<400, 256, 0, stream>>>(X0, w0P, wi1P, w1P, bsum1,
                                       hs0, hs1, cst0, cst1, i);

  // muH2 = hs1 @ [muW4;lsW4]^T + [muB;lsB]
  gemm_f32<<<dim3(2,6), 256, 0, stream>>>(hs1, 400, muW4, 400, muH2, 100,
                                          384, 100, 400, mlb);
  theta_par<<<32, 64, 0, stream>>>(muH2, muW, lsW, theta, accs);

  // beta logits via MFMA + fused row sum(exp)
  gemm_bf16<<<dim3(79,10,1), 256, 0, stream>>>(albf, 320, r1bf, 320,
                                               beta, nullptr, nullptr, 7000,
                                               600, 5000, 320, 320, rho1b, rs);
  gemm_bf16<<<dim3(32,10,1), 256, 0, stream>>>(albf, 320, r2bf, 320,
                                               beta + 5000, nullptr, nullptr, 7000,
                                               600, 2000, 320, 320, rho2b, rs + 600);

  pass1<<<dim3(110,12), 256, 0, stream>>>(beta, rs, theta, bzg, c1g1, c1g2, accs);
  pass2<<<dim3(110,12), 256, 0, stream>>>(bzg, theta, c1g1, c1g2, bows, accs);

  finalize_k<<<1, 64, 0, stream>>>(accs, out);
}

// Round 14
// 391.617 us; speedup vs baseline: 2.1642x; 1.0067x over previous
//
#include <hip/hip_runtime.h>

// ---------------- constants ----------------
#define LOG_DELTA (-5.2983174f)   // ln(0.005)
#define LOG50     (3.9120230054f) // ln(50)

typedef __attribute__((ext_vector_type(8))) short short8v;
typedef __attribute__((ext_vector_type(4))) float f32x4;

// ws layout (float offsets)
constexpr size_t OFF_C1G1  = 0;                       // c1u u32 [12][32][50]
constexpr size_t OFF_C1G2  = 19200;                   // (unused, kept zeroed)
constexpr size_t OFF_ACCS  = 38400;                   // [16]
constexpr size_t OFF_C0G   = 38416;                   // bzg [12][50][7000]
constexpr size_t OFF_BETA  = OFF_C0G  + 4200000;      // [600][7000] logits
constexpr size_t OFF_ALPHAT= OFF_BETA + 4200000;      // inp_f32 [384][400]
constexpr size_t OFF_INP   = OFF_ALPHAT + 180000;     // inp_bf ushort[384][416]
constexpr size_t OFF_X0    = OFF_INP  + 153600;       // [384][1600]
constexpr size_t OFF_OUT0  = OFF_X0   + 614400;       // hs0 [384][400]
constexpr size_t OFF_X1    = OFF_OUT0 + 153600;       // cst1|albf|r2bf region
constexpr size_t OFF_OUT1  = OFF_X1   + 614400;       // hs1 [384][400]
constexpr size_t OFF_CST   = OFF_OUT1 + 153600;       // cst0 [32][400]
constexpr size_t OFF_MUH   = OFF_CST  + 12800;        // [384][100]
constexpr size_t OFF_THETA = OFF_MUH  + 38400;        // [12][32][50]
constexpr size_t OFF_LTH   = OFF_THETA+ 19200;        // bsum0|bsum1|mlb|rs
constexpr size_t OFF_MUW4  = OFF_LTH  + 19200;        // [50][400]
constexpr size_t OFF_LSW4  = OFF_MUW4 + 20000;        // [50][400]
constexpr size_t OFF_RS    = OFF_LTH  + 3300;         // rowsum [2][600]
// overlay in bzg region (dead before pass1): block-packed LSTM weights
constexpr size_t OFF_W0P   = OFF_C0G;                 // f32 [200][400][8]
constexpr size_t OFF_W1P   = OFF_C0G + 640000;        // f32 [200][400][8]
constexpr size_t OFF_WI1P  = OFF_C0G + 1280000;       // f32 [200][400][8]
constexpr size_t OFF_NBBF  = OFF_C0G + 1920000;       // ushort[384][7040]
constexpr size_t OFF_R1BF  = OFF_C0G + 3271680;       // ushort[5000][320]
// overlay in beta region (dead before beta GEMMs):
constexpr size_t OFF_QWBF  = OFF_BETA;                // ushort[400][7040]
constexpr size_t OFF_W0BF  = OFF_BETA + 1408000;      // ushort[1600][416]
// overlay in X1 region (X1 eliminated):
constexpr size_t OFF_CST1  = OFF_X1;                  // f32 [32][400]
constexpr size_t OFF_ALBF  = OFF_X1 + 12800;          // ushort[600][320]
constexpr size_t OFF_R2BF  = OFF_X1 + 108800;         // ushort[2000][320]

// ---------------- helpers ----------------
__device__ __forceinline__ float wsum64(float x){
  #pragma unroll
  for (int o = 32; o; o >>= 1) x += __shfl_down(x, o);
  return x;
}
__device__ __forceinline__ float u01(unsigned int x){
  x ^= x >> 16; x *= 0x7feb352dU;
  x ^= x >> 15; x *= 0x846ca68bU;
  x ^= x >> 16;
  return ((float)x + 0.5f) * (1.0f/4294967296.0f);
}
__device__ __forceinline__ unsigned short f2bf(float x){
  unsigned int u = __float_as_uint(x);
  u += 0x7FFFu + ((u >> 16) & 1u);
  return (unsigned short)(u >> 16);
}
__device__ __forceinline__ ushort4 f4bf(float4 v){
  ushort4 r;
  r.x = f2bf(v.x); r.y = f2bf(v.y); r.z = f2bf(v.z); r.w = f2bf(v.w);
  return r;
}

// ---------------- fused prep (vectorized) ----------------
__global__ void prep_misc(float* __restrict__ ws,
    const float* __restrict__ muW, const float* __restrict__ lsW,
    const float* __restrict__ qmu,
    const float* __restrict__ bi0, const float* __restrict__ bh0,
    const float* __restrict__ bi1, const float* __restrict__ bh1,
    const float* __restrict__ mb,  const float* __restrict__ lb,
    const float* __restrict__ qb,
    const float* __restrict__ whh0, const float* __restrict__ whh1,
    const float* __restrict__ wih1,
    const float* __restrict__ nbows, const float* __restrict__ qmap_w,
    const float* __restrict__ wih0,
    const float* __restrict__ rho1w, const float* __restrict__ rho2w)
{
  float* zbase = ws + OFF_C1G1;
  float* muW4  = ws + OFF_MUW4;
  float* lsW4  = ws + OFF_LSW4;
  unsigned short* albf = (unsigned short*)(ws + OFF_ALBF);
  float* bsum0 = ws + OFF_LTH;
  float* bsum1 = ws + OFF_LTH + 1600;
  float* mlb   = ws + OFF_LTH + 3200;
  float* rs    = ws + OFF_RS;
  unsigned int* inbz = (unsigned int*)(ws + OFF_INP);
  float* inpf  = ws + OFF_ALPHAT;
  float* w0P   = ws + OFF_W0P;
  float* w1P   = ws + OFF_W1P;
  float* wi1P  = ws + OFF_WI1P;
  unsigned short* nbbf = (unsigned short*)(ws + OFF_NBBF);
  unsigned short* qwbf = (unsigned short*)(ws + OFF_QWBF);
  unsigned short* w0bf = (unsigned short*)(ws + OFF_W0BF);
  unsigned short* r1bf = (unsigned short*)(ws + OFF_R1BF);
  unsigned short* r2bf = (unsigned short*)(ws + OFF_R2BF);
  const float4 z4 = {0.f, 0.f, 0.f, 0.f};

  for (long long un = blockIdx.x*blockDim.x + threadIdx.x; un < 2713337LL;
       un += (long long)gridDim.x*blockDim.x){
    if (un < 9604){
      int j = (int)un * 4;
      if (j + 3 < 38416) *(float4*)&zbase[j] = z4;
      else { for (int q = 0; q < 4 && j+q < 38416; ++q) zbase[j+q] = 0.f; }
    }
    else if (un < 14604){
      int j = (int)(un - 9604) * 4;
      int k = j / 400, c = j % 400;
      const float* s = &muW[k*450 + c];
      float4 v = {s[0], s[1], s[2], s[3]};
      *(float4*)&muW4[j] = v;
    }
    else if (un < 19604){
      int j = (int)(un - 14604) * 4;
      int k = j / 400, c = j % 400;
      const float* s = &lsW[k*450 + c];
      float4 v = {s[0], s[1], s[2], s[3]};
      *(float4*)&lsW4[j] = v;
    }
    else if (un < 67604){
      int j = (int)(un - 19604) * 4;
      int m = j / 320, r = j % 320;
      int t = m / 50, k = m % 50;
      ushort4 o = {0,0,0,0};
      if (r < 300) o = f4bf(*(const float4*)&qmu[((size_t)k*12 + t)*300 + r]);
      *(ushort4*)&albf[j] = o;
    }
    else if (un < 68004){
      int j = (int)(un - 67604) * 4;
      float4 a = *(const float4*)&bi0[j], b = *(const float4*)&bh0[j];
      float4 v = {a.x+b.x, a.y+b.y, a.z+b.z, a.w+b.w};
      *(float4*)&bsum0[j] = v;
    }
    else if (un < 68404){
      int j = (int)(un - 68004) * 4;
      float4 a = *(const float4*)&bi1[j], b = *(const float4*)&bh1[j];
      float4 v = {a.x+b.x, a.y+b.y, a.z+b.z, a.w+b.w};
      *(float4*)&bsum1[j] = v;
    }
    else if (un < 68429){
      int j = (int)(un - 68404) * 4;
      #pragma unroll
      for (int q = 0; q < 4; ++q){
        int jj = j + q;
        mlb[jj] = (jj < 50) ? mb[jj] : lb[jj-50];
      }
    }
    else if (un < 68729){
      int j = (int)(un - 68429) * 4;
      *(float4*)&rs[j] = z4;
    }
    else if (un < 88697){
      int j = (int)(un - 68729) * 4;
      *(uint4*)&inbz[j] = make_uint4(0u,0u,0u,0u);
    }
    else if (un < 568697){
      long long rel = un - 88697;
      int half = (int)(rel / 160000);
      int j = (int)(rel % 160000) * 4;
      int ub = j / 3200, rem = j % 3200;
      int r = rem / 8, c = rem % 8;
      int ul = c >> 2;
      int u = ub*2 + ul;
      const float* src = (half == 0) ? whh0 : (half == 1) ? whh1 : wih1;
      float* dst = (half == 0) ? w0P : (half == 1) ? w1P : wi1P;
      float4 v = { src[((size_t)(0*400 + u))*400 + r],
                   src[((size_t)(1*400 + u))*400 + r],
                   src[((size_t)(2*400 + u))*400 + r],
                   src[((size_t)(3*400 + u))*400 + r] };
      *(float4*)&dst[j] = v;
    }
    else if (un < 1244537){
      int j = (int)(un - 568697) * 4;
      int row = j / 7040, v = j % 7040;
      ushort4 o = {0,0,0,0};
      if (v < 7000) o = f4bf(*(const float4*)&nbows[(size_t)row*7000 + v]);
      *(ushort4*)&nbbf[j] = o;
    }
    else if (un < 1948537){
      int j = (int)(un - 1244537) * 4;
      int row = j / 7040, v = j % 7040;
      ushort4 o = {0,0,0,0};
      if (v < 7000) o = f4bf(*(const float4*)&qmap_w[(size_t)row*7000 + v]);
      *(ushort4*)&qwbf[j] = o;
    }
    else if (un < 2114937){
      int j = (int)(un - 1948537) * 4;
      int row = j / 416, r = j % 416;
      ushort4 o = {0,0,0,0};
      if (r < 400) o = f4bf(*(const float4*)&wih0[(size_t)row*400 + r]);
      *(ushort4*)&w0bf[j] = o;
    }
    else if (un < 2514937){
      int j = (int)(un - 2114937) * 4;
      int row = j / 320, r = j % 320;
      ushort4 o = {0,0,0,0};
      if (r < 300) o = f4bf(*(const float4*)&rho1w[(size_t)row*300 + r]);
      *(ushort4*)&r1bf[j] = o;
    }
    else if (un < 2674937){
      int j = (int)(un - 2514937) * 4;
      int row = j / 320, r = j % 320;
      ushort4 o = {0,0,0,0};
      if (r < 300) o = f4bf(*(const float4*)&rho2w[(size_t)row*300 + r]);
      *(ushort4*)&r2bf[j] = o;
    }
    else {
      int j = (int)(un - 2674937) * 4;
      int c = j % 400;
      *(float4*)&inpf[j] = *(const float4*)&qb[c];
    }
  }
}

// ---------------- MFMA bf16 GEMM ----------------
__global__ __launch_bounds__(256) void gemm_bf16(
    const unsigned short* __restrict__ A, int lda,
    const unsigned short* __restrict__ B, int ldb,
    float* __restrict__ Cf, unsigned short* __restrict__ Cbf,
    float* __restrict__ Cacc, int ldc,
    int M, int N, int Kp, int kchunk,
    const float* __restrict__ bias, float* __restrict__ rowsum)
{
  __shared__ unsigned short As[64][40];
  __shared__ unsigned short Bs[64][40];
  __shared__ float sexp[64];
  const int tid = threadIdx.x;
  const int m0 = blockIdx.y * 64, n0 = blockIdx.x * 64;
  const int kbeg = blockIdx.z * kchunk;
  const int kend = min(Kp, kbeg + kchunk);
  const int wave = tid >> 6, lane = tid & 63;
  const int wm = (wave >> 1) * 32, wn = (wave & 1) * 32;
  const int ra = tid >> 2, ck = (tid & 3) << 3;
  const int fr = lane & 15, fo = (lane >> 4) << 3;
  if (rowsum && tid < 64) sexp[tid] = 0.f;

  f32x4 acc00 = {0.f,0.f,0.f,0.f}, acc01 = {0.f,0.f,0.f,0.f};
  f32x4 acc10 = {0.f,0.f,0.f,0.f}, acc11 = {0.f,0.f,0.f,0.f};
  int4 pa, pb;
  {
    int rA = m0 + ra, rB = n0 + ra;
    pa = (rA < M) ? *(const int4*)&A[(size_t)rA*lda + kbeg + ck] : make_int4(0,0,0,0);
    pb = (rB < N) ? *(const int4*)&B[(size_t)rB*ldb + kbeg + ck] : make_int4(0,0,0,0);
  }
  for (int k0 = kbeg; k0 < kend; k0 += 32){
    *(int4*)&As[ra][ck] = pa;
    *(int4*)&Bs[ra][ck] = pb;
    __syncthreads();
    if (k0 + 32 < kend){
      int rA = m0 + ra, rB = n0 + ra;
      pa = (rA < M) ? *(const int4*)&A[(size_t)rA*lda + k0 + 32 + ck] : make_int4(0,0,0,0);
      pb = (rB < N) ? *(const int4*)&B[(size_t)rB*ldb + k0 + 32 + ck] : make_int4(0,0,0,0);
    }
    short8v a0 = *(const short8v*)&As[wm      + fr][fo];
    short8v a1 = *(const short8v*)&As[wm + 16 + fr][fo];
    short8v b0 = *(const short8v*)&Bs[wn      + fr][fo];
    short8v b1 = *(const short8v*)&Bs[wn + 16 + fr][fo];
    acc00 = __builtin_amdgcn_mfma_f32_16x16x32_bf16(a0, b0, acc00, 0, 0, 0);
    acc01 = __builtin_amdgcn_mfma_f32_16x16x32_bf16(a0, b1, acc01, 0, 0, 0);
    acc10 = __builtin_amdgcn_mfma_f32_16x16x32_bf16(a1, b0, acc10, 0, 0, 0);
    acc11 = __builtin_amdgcn_mfma_f32_16x16x32_bf16(a1, b1, acc11, 0, 0, 0);
    __syncthreads();
  }
  const int rbase = (lane >> 4) << 2;
  auto epi = [&](f32x4 ac0, f32x4 ac1, int mi){
    #pragma unroll
    for (int reg = 0; reg < 4; ++reg){
      const int lr = wm + mi*16 + rbase + reg;
      const int gr = m0 + lr;
      float ex = 0.f;
      {
        int gc = n0 + wn + fr;
        if (gr < M && gc < N){
          if (Cacc) atomicAdd(&Cacc[(size_t)gr*ldc + gc], ac0[reg]);
          else {
            float val = ac0[reg] + (bias ? bias[gc] : 0.f);
            if (Cbf) Cbf[(size_t)gr*ldc + gc] = f2bf(val);
            else     Cf [(size_t)gr*ldc + gc] = val;
            if (rowsum) ex += __expf(val);
          }
        }
      }
      {
        int gc = n0 + wn + 16 + fr;
        if (gr < M && gc < N){
          if (Cacc) atomicAdd(&Cacc[(size_t)gr*ldc + gc], ac1[reg]);
          else {
            float val = ac1[reg] + (bias ? bias[gc] : 0.f);
            if (Cbf) Cbf[(size_t)gr*ldc + gc] = f2bf(val);
            else     Cf [(size_t)gr*ldc + gc] = val;
            if (rowsum) ex += __expf(val);
          }
        }
      }
      if (rowsum){
        ex += __shfl_xor(ex, 1); ex += __shfl_xor(ex, 2);
        ex += __shfl_xor(ex, 4); ex += __shfl_xor(ex, 8);
        if (fr == 0 && gr < M) atomicAdd(&sexp[lr], ex);
      }
    }
  };
  epi(acc00, acc01, 0);
  epi(acc10, acc11, 1);
  if (rowsum){
    __syncthreads();
    if (tid < 64 && m0 + tid < M) atomicAdd(&rowsum[m0 + tid], sexp[tid]);
  }
}

// ---------------- convert inp_f32 -> bf16 (vectorized) ----------------
__global__ void cvt_inp(const float* __restrict__ inpf, unsigned short* __restrict__ inpbf){
  int un = blockIdx.x*blockDim.x + threadIdx.x;
  if (un < 38400){
    int j = un * 4;
    int r = j / 400, c = j % 400;
    ushort4 o = f4bf(*(const float4*)&inpf[j]);
    *(ushort4*)&inpbf[r*416 + c] = o;
  }
}

// ---------------- f32 GEMM (kept for tiny muH2) ----------------
__device__ __forceinline__ float4 g4(const float* __restrict__ base, int row, int nrows,
                                     int ld, int k, int kend){
  float4 v; v.x = v.y = v.z = v.w = 0.f;
  if (row < nrows){
    const float* q = base + (size_t)row*ld + k;
    if (k + 3 < kend) v = *(const float4*)q;
  }
  return v;
}
__global__ __launch_bounds__(256) void gemm_f32(
    const float* __restrict__ A, int lda,
    const float* __restrict__ B, int ldb,
    float* __restrict__ C, int ldc,
    int M, int N, int K,
    const float* __restrict__ bias)
{
  __shared__ __align__(16) float As[16][68];
  __shared__ __align__(16) float Bs[16][68];
  const int tid = threadIdx.x;
  const int m0 = blockIdx.y * 64, n0 = blockIdx.x * 64;
  const int lm  = tid >> 2;
  const int lkq = (tid & 3) << 2;
  const int ty = tid >> 4, tx = tid & 15;
  float acc[4][4];
  #pragma unroll
  for (int i=0;i<4;++i)
    #pragma unroll
    for (int j=0;j<4;++j) acc[i][j] = 0.f;
  for (int k0 = 0; k0 < K; k0 += 16){
    float4 av = g4(A, m0+lm, M, lda, k0+lkq, K);
    float4 bv = g4(B, n0+lm, N, ldb, k0+lkq, K);
    As[lkq+0][lm]=av.x; As[lkq+1][lm]=av.y; As[lkq+2][lm]=av.z; As[lkq+3][lm]=av.w;
    Bs[lkq+0][lm]=bv.x; Bs[lkq+1][lm]=bv.y; Bs[lkq+2][lm]=bv.z; Bs[lkq+3][lm]=bv.w;
    __syncthreads();
    #pragma unroll
    for (int kk = 0; kk < 16; ++kk){
      const float4 a = *(const float4*)&As[kk][ty<<2];
      const float4 b = *(const float4*)&Bs[kk][tx<<2];
      float ar[4] = {a.x,a.y,a.z,a.w};
      float br[4] = {b.x,b.y,b.z,b.w};
      #pragma unroll
      for (int i=0;i<4;++i)
        #pragma unroll
        for (int j=0;j<4;++j) acc[i][j] = fmaf(ar[i], br[j], acc[i][j]);
    }
    __syncthreads();
  }
  const int om = m0 + (ty<<2), on = n0 + (tx<<2);
  #pragma unroll
  for (int i=0;i<4;++i)
    #pragma unroll
    for (int j=0;j<4;++j)
      if (om+i < M && on+j < N)
        C[(size_t)(om+i)*ldc + (on+j)] = acc[i][j] + (bias ? bias[on+j] : 0.f);
}

// ---------------- pipelined LSTM v2: LDS-staged packed weights ----------------
__global__ __launch_bounds__(256) void lstm_pipe(
    const float* __restrict__ X0,    const float* __restrict__ w0P,
    const float* __restrict__ wi1P,  const float* __restrict__ w1P,
    const float* __restrict__ bsum1,
    float* __restrict__ hs0, float* __restrict__ hs1,
    float* __restrict__ cst0, float* __restrict__ cst1, int step)
{
  __shared__ __align__(16) float4 hq4[100*32];
  __shared__ __align__(16) float4 wq4[400*2];
  __shared__ __align__(16) float4 red4[4][32][2];
  const int tid = threadIdx.x;
  const int rh = tid >> 6;
  const int b  = (tid & 63) >> 1;
  const int ul = tid & 1;
  const int rq0 = rh * 25;

  if (blockIdx.x < 200){
    const int t = step;
    if (t >= 12) return;
    const int ub = blockIdx.x;
    const int U0 = ub * 2;
    if (t > 0){
      for (int i = tid; i < 3200; i += 256){
        int bb = i & 31, rq = i >> 5;
        hq4[rq*32 + bb] = *(const float4*)&hs0[((size_t)(bb*12 + (t-1)))*400 + rq*4];
      }
      for (int i = tid; i < 800; i += 256)
        wq4[i] = *(const float4*)&w0P[(size_t)ub*3200 + i*4];
      __syncthreads();
      float4 acc = {0.f,0.f,0.f,0.f};
      #pragma unroll 5
      for (int rq = rq0; rq < rq0 + 25; ++rq){
        float4 h4 = hq4[rq*32 + b];
        float hr[4] = {h4.x, h4.y, h4.z, h4.w};
        #pragma unroll
        for (int dr = 0; dr < 4; ++dr){
          float4 w4 = wq4[(rq*4 + dr)*2 + ul];
          acc.x = fmaf(hr[dr], w4.x, acc.x);
          acc.y = fmaf(hr[dr], w4.y, acc.y);
          acc.z = fmaf(hr[dr], w4.z, acc.z);
          acc.w = fmaf(hr[dr], w4.w, acc.w);
        }
      }
      red4[rh][b][ul] = acc;
    }
    __syncthreads();
    if (tid < 64){
      const int bb = tid >> 1, uu = U0 + (tid & 1);
      float4 a = {0.f,0.f,0.f,0.f};
      if (t > 0){
        #pragma unroll
        for (int w = 0; w < 4; ++w){
          float4 r = red4[w][bb][tid & 1];
          a.x += r.x; a.y += r.y; a.z += r.z; a.w += r.w;
        }
      }
      const size_t xrow = ((size_t)bb*12 + t)*1600;
      float gi = a.x + X0[xrow          + uu];
      float gf = a.y + X0[xrow +  400   + uu];
      float gg = a.z + X0[xrow +  800   + uu];
      float go = a.w + X0[xrow + 1200   + uu];
      float ii = 1.f/(1.f + expf(-gi));
      float ff = 1.f/(1.f + expf(-gf));
      float tg = tanhf(gg);
      float oo = 1.f/(1.f + expf(-go));
      float c = (t == 0) ? 0.f : cst0[bb*400 + uu];
      c = ff*c + ii*tg;
      cst0[bb*400 + uu] = c;
      hs0[((size_t)bb*12 + t)*400 + uu] = oo * tanhf(c);
    }
  } else {
    const int t = step - 1;
    if (t < 0) return;
    const int ub = blockIdx.x - 200;
    const int U0 = ub * 2;
    float4 acc = {0.f,0.f,0.f,0.f};
    for (int i = tid; i < 3200; i += 256){
      int bb = i & 31, rq = i >> 5;
      hq4[rq*32 + bb] = *(const float4*)&hs0[((size_t)(bb*12 + t))*400 + rq*4];
    }
    for (int i = tid; i < 800; i += 256)
      wq4[i] = *(const float4*)&wi1P[(size_t)ub*3200 + i*4];
    __syncthreads();
    {
      #pragma unroll 5
      for (int rq = rq0; rq < rq0 + 25; ++rq){
        float4 h4 = hq4[rq*32 + b];
        float hr[4] = {h4.x, h4.y, h4.z, h4.w};
        #pragma unroll
        for (int dr = 0; dr < 4; ++dr){
          float4 w4 = wq4[(rq*4 + dr)*2 + ul];
          acc.x = fmaf(hr[dr], w4.x, acc.x);
          acc.y = fmaf(hr[dr], w4.y, acc.y);
          acc.z = fmaf(hr[dr], w4.z, acc.z);
          acc.w = fmaf(hr[dr], w4.w, acc.w);
        }
      }
    }
    __syncthreads();
    if (t > 0){
      for (int i = tid; i < 3200; i += 256){
        int bb = i & 31, rq = i >> 5;
        hq4[rq*32 + bb] = *(const float4*)&hs1[((size_t)(bb*12 + (t-1)))*400 + rq*4];
      }
      for (int i = tid; i < 800; i += 256)
        wq4[i] = *(const float4*)&w1P[(size_t)ub*3200 + i*4];
    }
    __syncthreads();
    if (t > 0){
      #pragma unroll 5
      for (int rq = rq0; rq < rq0 + 25; ++rq){
        float4 h4 = hq4[rq*32 + b];
        float hr[4] = {h4.x, h4.y, h4.z, h4.w};
        #pragma unroll
        for (int dr = 0; dr < 4; ++dr){
          float4 w4 = wq4[(rq*4 + dr)*2 + ul];
          acc.x = fmaf(hr[dr], w4.x, acc.x);
          acc.y = fmaf(hr[dr], w4.y, acc.y);
          acc.z = fmaf(hr[dr], w4.z, acc.z);
          acc.w = fmaf(hr[dr], w4.w, acc.w);
        }
      }
    }
    red4[rh][b][ul] = acc;
    __syncthreads();
    if (tid < 64){
      const int bb = tid >> 1, uu = U0 + (tid & 1);
      float4 a = {0.f,0.f,0.f,0.f};
      #pragma unroll
      for (int w = 0; w < 4; ++w){
        float4 r = red4[w][bb][tid & 1];
        a.x += r.x; a.y += r.y; a.z += r.z; a.w += r.w;
      }
      float gi = a.x + bsum1[        uu];
      float gf = a.y + bsum1[ 400 + uu];
      float gg = a.z + bsum1[ 800 + uu];
      float go = a.w + bsum1[1200 + uu];
      float ii = 1.f/(1.f + expf(-gi));
      float ff = 1.f/(1.f + expf(-gf));
      float tg = tanhf(gg);
      float oo = 1.f/(1.f + expf(-go));
      float c = (t == 0) ? 0.f : cst1[bb*400 + uu];
      c = ff*c + ii*tg;
      cst1[bb*400 + uu] = c;
      hs1[((size_t)bb*12 + t)*400 + uu] = oo * tanhf(c);
    }
  }
}

// ---------------- theta head: one block per batch row b ----------------
__global__ __launch_bounds__(64) void theta_par(
    const float* __restrict__ muH2,
    const float* __restrict__ muW, const float* __restrict__ lsW,
    float* __restrict__ theta, float* __restrict__ accs)
{
  __shared__ float wm[50][51], wl[50][51];
  __shared__ float zs[12][50];
  const int tid = threadIdx.x;
  const int b = blockIdx.x;
  for (int i = tid; i < 2500; i += 64){
    int k = i / 50, j = i % 50;
    wm[k][j] = muW[k*450 + 400 + j];
    wl[k][j] = lsW[k*450 + 400 + j];
  }
  __syncthreads();
  const float dd = expf(LOG_DELTA) + 1e-6f;
  float kacc = 0.f;
  for (int t = 0; t < 12; ++t){
    float kpart = 0.f;
    if (tid < 50){
      int k = tid;
      float m = muH2[((size_t)b*12 + t)*100 + k];
      float l = muH2[((size_t)b*12 + t)*100 + 50 + k];
      float zp = 0.f;
      if (t > 0){
        zp = zs[t-1][k];
        float sm = 0.f, sl = 0.f;
        #pragma unroll 5
        for (int j = 0; j < 50; ++j){
          float z = zs[t-1][j];
          sm = fmaf(z, wm[k][j], sm);
          sl = fmaf(z, wl[k][j], sl);
        }
        m += sm; l += sl;
      }
      zs[t][k] = m;
      float denom = (t > 0) ? dd : (1.f + 1e-6f);
      float pls = (t > 0) ? LOG_DELTA : 0.f;
      float d = m - zp;
      kpart = (expf(l) + d*d)/denom - 1.f + pls - l;
    }
    kpart = wsum64(kpart);
    if (tid == 0) kacc += 0.5f * kpart / 32.f;
    __syncthreads();
  }
  if (tid < 12){
    int t = tid;
    float m = -3.0e38f;
    for (int k = 0; k < 50; ++k) m = fmaxf(m, zs[t][k]);
    float S = 0.f;
    for (int k = 0; k < 50; ++k) S += expf(zs[t][k] - m);
    float inv = 1.f/S;
    for (int k = 0; k < 50; ++k)
      theta[((size_t)t*32 + b)*50 + k] = expf(zs[t][k] - m) * inv;
  }
  if (tid == 0) atomicAdd(&accs[6], kacc);
}

// ---------------- kld_alpha ----------------
__global__ void kld_alpha_k(const float* __restrict__ qmu, const float* __restrict__ qls,
                            float* __restrict__ accs){
  const int t = blockIdx.x / 50, k = blockIdx.x % 50;
  const size_t base  = ((size_t)k*12 + t)*300;
  const size_t pbase = ((size_t)k*12 + (t-1))*300;
  const float dd  = (t > 0) ? (expf(LOG_DELTA) + 1e-6f) : (1.f + 1e-6f);
  const float pls = (t > 0) ? LOG_DELTA : 0.f;
  float s = 0.f;
  for (int r = threadIdx.x; r < 300; r += 64){
    float qm = qmu[base + r], ql = qls[base + r];
    float pm = (t > 0) ? qmu[pbase + r] : 0.f;
    float d = qm - pm;
    s += (expf(ql) + d*d)/dd - 1.f + pls - ql;
  }
  s = wsum64(s);
  if (threadIdx.x == 0) atomicAdd(&accs[7], 0.5f * s / 50.f);
}

// ---------------- pass1 v8: quad-pair v-mapping (bank-conflict-free S1),
// packed c0, u32-combined c1 atomics ----------------
__global__ __launch_bounds__(256) void pass1(
    const float* __restrict__ blog, const float* __restrict__ rs,
    const float* __restrict__ theta,
    float* __restrict__ bzg,
    unsigned int* __restrict__ c1u,
    float* __restrict__ accs)
{
  const int t = blockIdx.y;
  const int v0 = blockIdx.x * 64;
  __shared__ float th[32][50];
  __shared__ __align__(16) float be[50][64];
  __shared__ unsigned int c0p[64][13];
  __shared__ unsigned int c1p[2][32][25];
  __shared__ float rlog[2][50];
  __shared__ float kred[4];
  const int tid = threadIdx.x;

  if (tid < 100){
    int p = tid / 50, k = tid % 50;
    rlog[p][k] = __logf(rs[p*600 + t*50 + k]);
  }
  float lg[13];
  #pragma unroll
  for (int j = 0; j < 13; ++j){
    int i = tid + j*256;
    lg[j] = -40.f;
    if (i < 3200){
      int k = i >> 6, vl = i & 63, v = v0 + vl;
      if (v < 7000) lg[j] = blog[((size_t)t*50 + k)*7000 + v];
    }
  }
  #pragma unroll
  for (int j = 0; j < 7; ++j){
    int i = tid + j*256;
    if (i < 1600) th[i/50][i%50] = theta[(size_t)t*1600 + i];
  }
  for (int i = tid; i < 832; i += 256) ((unsigned int*)c0p)[i] = 0u;
  #pragma unroll
  for (int j = 0; j < 7; ++j){
    int i = tid + j*256;
    if (i < 1600) ((unsigned int*)c1p)[i] = 0u;
  }
  if (tid < 4) kred[tid] = 0.f;
  __syncthreads();
  #pragma unroll
  for (int j = 0; j < 13; ++j){
    int i = tid + j*256;
    if (i < 3200){
      int k = i >> 6, vl = i & 63, v = v0 + vl;
      int p = (v >= 5000);
      be[k][vl] = __expf(lg[j] - rlog[p][k]);
    }
  }
  __syncthreads();

  const int b = tid >> 3, sub = tid & 7;
  // two quads per thread: off = sub*4 + {0..3} and 32 + sub*4 + {0..3}
  // -> each wave's 8 b128 addresses span banks 0..31 exactly (conflict-free)
  int off[8];
  #pragma unroll
  for (int i = 0; i < 8; ++i) off[i] = ((i >> 2) ? 32 : 0) + sub*4 + (i & 3);

  float sx[8], mx[8];
  #pragma unroll
  for (int i = 0; i < 8; ++i){ sx[i] = 0.f; mx[i] = 0.f; }
  for (int k = 0; k < 50; ++k){
    float tk = th[b][k];
    float4 q0 = *(const float4*)&be[k][sub*4];
    float4 q1 = *(const float4*)&be[k][32 + sub*4];
    float bv[8] = {q0.x,q0.y,q0.z,q0.w,q1.x,q1.y,q1.z,q1.w};
    #pragma unroll
    for (int i = 0; i < 8; ++i){
      float x = tk * bv[i];
      sx[i] += x;
      mx[i] = fmaxf(mx[i], x);
    }
  }
  float inv[8], lS1[8], bnd[8];
  #pragma unroll
  for (int i = 0; i < 8; ++i){
    inv[i] = 1.f / (50.f + sx[i]);
    lS1[i] = LOG50 + sx[i] * 0.02f;
    bnd[i] = (1.f + mx[i]) * inv[i];
  }

  int ks[8]; float xs[8];
  unsigned fmask = 0;
  const int sbase = (t*32 + b)*7000 + v0;
  #pragma unroll
  for (int i = 0; i < 8; ++i){
    ks[i] = 0; xs[i] = 0.f;
    if (v0 + off[i] >= 7000) fmask |= 1u << i;
  }
  int round = 0;
  while (true){
    const unsigned roff = (unsigned)round * 0x9E3779B9u;
    #pragma unroll
    for (int i = 0; i < 8; ++i){
      if (!((fmask >> i) & 1u)){
        const unsigned bse = (unsigned)(sbase + off[i]) * 2u;
        float u1 = u01(bse + roff);
        float u2 = u01(bse + 1u + roff);
        int kp = min((int)(u1 * 50.f), 49);
        float x  = th[b][kp] * be[kp][off[i]];
        float pi = (1.f + x) * inv[i];
        float y  = pi - bnd[i];
        float ap = 1.f + y + 0.5f*y*y;
        if (u2 <= ap || round >= 7){
          ks[i] = kp; xs[i] = x; fmask |= 1u << i;
        }
      }
    }
    ++round;
    if (__all(fmask == 255u)) break;
  }

  float kA1 = 0.f, kB1 = 0.f, kA2 = 0.f, kB2 = 0.f;
  #pragma unroll
  for (int i = 0; i < 8; ++i){
    const int vl = off[i], v = v0 + vl;
    if (v < 7000){
      float pis  = (1.f + xs[i]) * inv[i];
      float lpis = xs[i] - lS1[i];
      float lt   = __logf(th[b][ks[i]]);
      if (v >= 5000){ kA2 += lt; kB2 += pis*lpis; }
      else          { kA1 += lt; kB1 += pis*lpis; }
      atomicAdd(&c0p[vl][ks[i] >> 2], 1u << (8*(ks[i] & 3)));
      atomicAdd(&c1p[(v >= 5000) ? 1 : 0][b][ks[i] >> 1],
                (ks[i] & 1) ? 65536u : 1u);
    }
  }
  kA1 = wsum64(kA1); kB1 = wsum64(kB1); kA2 = wsum64(kA2); kB2 = wsum64(kB2);
  if ((tid & 63) == 0){
    atomicAdd(&kred[0], kA1); atomicAdd(&kred[1], kB1);
    atomicAdd(&kred[2], kA2); atomicAdd(&kred[3], kB2);
  }
  __syncthreads();
  #pragma unroll
  for (int j = 0; j < 13; ++j){
    int i = tid + j*256;
    if (i < 3200){
      int k = i >> 6, vl = i & 63, v = v0 + vl;
      if (v < 7000){
        float cnt = (float)((c0p[vl][k >> 2] >> (8*(k & 3))) & 0xFFu);
        bzg[(size_t)t*350000 + (size_t)k*7000 + v] = be[k][vl] * cnt * (1.f/32.f);
      }
    }
  }
  // combined u32 c1 atomics: lo 16 bits = part1, hi 16 bits = part2
  for (int i = tid; i < 1600; i += 256){
    int b2 = i / 50, k2 = i % 50;
    unsigned w1 = c1p[0][b2][k2 >> 1];
    unsigned w2 = c1p[1][b2][k2 >> 1];
    unsigned cnt1 = (k2 & 1) ? (w1 >> 16) : (w1 & 0xFFFFu);
    unsigned cnt2 = (k2 & 1) ? (w2 >> 16) : (w2 & 0xFFFFu);
    unsigned comb = cnt1 | (cnt2 << 16);
    if (comb) atomicAdd(&c1u[(size_t)t*1600 + i], comb);
  }
  if (tid < 4) atomicAdd(&accs[tid], kred[tid]);
}

// ---------------- pass2: log-likelihood (quad-pair v-mapping) ----------------
__global__ __launch_bounds__(256) void pass2(
    const float* __restrict__ bzg, const float* __restrict__ theta,
    const unsigned int* __restrict__ c1u,
    const float* __restrict__ bows, float* __restrict__ accs)
{
  const int t = blockIdx.y, v0 = blockIdx.x * 64;
  __shared__ float tz[2][32][50];
  __shared__ __align__(16) float bzs[50][64];
  __shared__ float sr[2];
  const int tid = threadIdx.x;
  if (tid < 2) sr[tid] = 0.f;
  for (int i = tid; i < 1600; i += 256){
    int b = i / 50, k = i % 50;
    float th_ = theta[(size_t)t*1600 + i];
    unsigned cw = c1u[(size_t)t*1600 + i];
    tz[0][b][k] = th_ * (float)(cw & 0xFFFFu) * (1.f/5000.f);
    tz[1][b][k] = th_ * (float)(cw >> 16)     * (1.f/2000.f);
  }
  for (int i = tid; i < 3200; i += 256){
    int k = i >> 6, vl = i & 63, v = v0 + vl;
    bzs[k][vl] = (v < 7000) ? bzg[(size_t)t*350000 + (size_t)k*7000 + v] : 0.f;
  }
  __syncthreads();

  const int b = tid >> 3, sub = tid & 7;
  int off[8];
  #pragma unroll
  for (int i = 0; i < 8; ++i) off[i] = ((i >> 2) ? 32 : 0) + sub*4 + (i & 3);
  int part[8];
  #pragma unroll
  for (int i = 0; i < 8; ++i) part[i] = (v0 + off[i] >= 5000);
  float dot[8];
  #pragma unroll
  for (int i = 0; i < 8; ++i) dot[i] = 0.f;
  for (int k = 0; k < 50; ++k){
    float t0 = tz[0][b][k], t1 = tz[1][b][k];
    float4 q0 = *(const float4*)&bzs[k][sub*4];
    float4 q1 = *(const float4*)&bzs[k][32 + sub*4];
    float bv[8] = {q0.x,q0.y,q0.z,q0.w,q1.x,q1.y,q1.z,q1.w};
    #pragma unroll
    for (int i = 0; i < 8; ++i)
      dot[i] = fmaf(part[i] ? t1 : t0, bv[i], dot[i]);
  }
  float w8[8];
  const size_t brow = ((size_t)b*12 + t)*7000;
  if (v0 + 63 < 7000){
    float4 wa = *(const float4*)&bows[brow + v0 + sub*4];
    float4 wb = *(const float4*)&bows[brow + v0 + 32 + sub*4];
    w8[0]=wa.x; w8[1]=wa.y; w8[2]=wa.z; w8[3]=wa.w;
    w8[4]=wb.x; w8[5]=wb.y; w8[6]=wb.z; w8[7]=wb.w;
  } else {
    #pragma unroll
    for (int i = 0; i < 8; ++i)
      w8[i] = (v0 + off[i] < 7000) ? bows[brow + v0 + off[i]] : 0.f;
  }
  float s1 = 0.f, s2 = 0.f;
  #pragma unroll
  for (int i = 0; i < 8; ++i){
    const int v = v0 + off[i];
    if (v < 7000){
      const float l = __logf(dot[i]) * w8[i];
      if (part[i]) s2 += l; else s1 += l;
    }
  }
  s1 = wsum64(s1); s2 = wsum64(s2);
  if ((tid & 63) == 0){ atomicAdd(&sr[0], s1); atomicAdd(&sr[1], s2); }
  __syncthreads();
  if (tid < 2) atomicAdd(&accs[4 + tid], sr[tid]);
}

// ---------------- finalize ----------------
__global__ void finalize_k(const float* __restrict__ accs, float* __restrict__ out){
  if (threadIdx.x == 0 && blockIdx.x == 0){
    out[0] = -(accs[4] + accs[5]) * (1.f/32.f);
    out[1] = accs[6];
    out[2] = -accs[0]/(32.f*5000.f) - accs[1]/32.f;
    out[3] = -accs[2]/(32.f*2000.f) - accs[3]/32.f;
    out[4] = accs[7];
  }
}

// ---------------- host launcher ----------------
extern "C" void kernel_launch(void* const* d_in, const int* in_sizes, int n_in,
                              void* d_out, int out_size, void* d_ws, size_t ws_size,
                              hipStream_t stream)
{
  const float* bows   = (const float*)d_in[0];
  const float* nbows  = (const float*)d_in[1];
  const float* qmap_w = (const float*)d_in[2];
  const float* qmap_b = (const float*)d_in[3];
  const float* wih0   = (const float*)d_in[4];
  const float* whh0   = (const float*)d_in[5];
  const float* bih0   = (const float*)d_in[6];
  const float* bhh0   = (const float*)d_in[7];
  const float* wih1   = (const float*)d_in[8];
  const float* whh1   = (const float*)d_in[9];
  const float* bih1   = (const float*)d_in[10];
  const float* bhh1   = (const float*)d_in[11];
  const float* muW    = (const float*)d_in[12];
  const float* muB    = (const float*)d_in[13];
  const float* lsW    = (const float*)d_in[14];
  const float* lsB    = (const float*)d_in[15];
  const float* qmu    = (const float*)d_in[16];
  const float* qlsa   = (const float*)d_in[17];
  const float* rho1w  = (const float*)d_in[18];
  const float* rho1b  = (const float*)d_in[19];
  const float* rho2w  = (const float*)d_in[20];
  const float* rho2b  = (const float*)d_in[21];

  float* ws  = (float*)d_ws;
  float* out = (float*)d_out;

  unsigned int* c1u = (unsigned int*)(ws + OFF_C1G1);
  float* accs  = ws + OFF_ACCS;
  float* bzg   = ws + OFF_C0G;
  float* beta  = ws + OFF_BETA;
  float* inpf  = ws + OFF_ALPHAT;
  float* X0    = ws + OFF_X0;
  float* hs0   = ws + OFF_OUT0;
  float* hs1   = ws + OFF_OUT1;
  float* cst0  = ws + OFF_CST;
  float* cst1  = ws + OFF_CST1;
  float* muH2  = ws + OFF_MUH;
  float* theta = ws + OFF_THETA;
  float* muW4  = ws + OFF_MUW4;
  float* bsum0 = ws + OFF_LTH;
  float* bsum1 = ws + OFF_LTH + 1600;
  float* mlb   = ws + OFF_LTH + 3200;
  float* rs    = ws + OFF_RS;
  unsigned short* nbbf  = (unsigned short*)(ws + OFF_NBBF);
  unsigned short* qwbf  = (unsigned short*)(ws + OFF_QWBF);
  unsigned short* inpbf = (unsigned short*)(ws + OFF_INP);
  unsigned short* w0bf  = (unsigned short*)(ws + OFF_W0BF);
  unsigned short* albf  = (unsigned short*)(ws + OFF_ALBF);
  unsigned short* r1bf  = (unsigned short*)(ws + OFF_R1BF);
  unsigned short* r2bf  = (unsigned short*)(ws + OFF_R2BF);
  float* w0P  = ws + OFF_W0P;
  float* w1P  = ws + OFF_W1P;
  float* wi1P = ws + OFF_WI1P;

  prep_misc<<<2048, 256, 0, stream>>>(ws, muW, lsW, qmu, bih0, bhh0, bih1, bhh1,
                                      muB, lsB, qmap_b, whh0, whh1, wih1,
                                      nbows, qmap_w, wih0, rho1w, rho2w);
  kld_alpha_k<<<600, 64, 0, stream>>>(qmu, qlsa, accs);

  // inp_f32 += nbows_bf @ qmap_w_bf^T  (split-K x10; bias pre-init'd in prep)
  gemm_bf16<<<dim3(7,6,10), 256, 0, stream>>>(nbbf, 7040, qwbf, 7040,
                                              nullptr, nullptr, inpf, 400,
                                              384, 400, 7040, 704, nullptr, nullptr);
  cvt_inp<<<150, 256, 0, stream>>>(inpf, inpbf);

  // X0 = inp_bf @ wih0^T + (bih0+bhh0)     M=384 N=1600 Kp=416
  gemm_bf16<<<dim3(25,6,1), 256, 0, stream>>>(inpbf, 416, w0bf, 416,
                                              X0, nullptr, nullptr, 1600,
                                              384, 1600, 416, 416, bsum0, nullptr);
  // pipelined double-layer LSTM: 13 launches
  for (int i = 0; i < 13; ++i)
    lstm_pipe<<<400, 256, 0, stream>>>(X0, w0P, wi1P, w1P, bsum1,
                                       hs0, hs1, cst0, cst1, i);

  // muH2 = hs1 @ [muW4;lsW4]^T + [muB;lsB]
  gemm_f32<<<dim3(2,6), 256, 0, stream>>>(hs1, 400, muW4, 400, muH2, 100,
                                          384, 100, 400, mlb);
  theta_par<<<32, 64, 0, stream>>>(muH2, muW, lsW, theta, accs);

  // beta logits via MFMA + fused row sum(exp)
  gemm_bf16<<<dim3(79,10,1), 256, 0, stream>>>(albf, 320, r1bf, 320,
                                               beta, nullptr, nullptr, 7000,
                                               600, 5000, 320, 320, rho1b, rs);
  gemm_bf16<<<dim3(32,10,1), 256, 0, stream>>>(albf, 320, r2bf, 320,
                                               beta + 5000, nullptr, nullptr, 7000,
                                               600, 2000, 320, 320, rho2b, rs + 600);

  pass1<<<dim3(110,12), 256, 0, stream>>>(beta, rs, theta, bzg, c1u, accs);
  pass2<<<dim3(110,12), 256, 0, stream>>>(bzg, theta, c1u, bows, accs);

  finalize_k<<<1, 64, 0, stream>>>(accs, out);
}